// Round 1
// baseline (946.551 us; speedup 1.0000x reference)
//
#include <hip/hip_runtime.h>
#include <math.h>

#define N_NODES 150000
#define N_EDGES 1200000
#define C 64
#define ACT 6
#define B_ROWS 25000   // N/ACT
#define GLOB 256
#define GOUT 10
#define H 32

// ---------------- degree ----------------
__global__ void degree_kernel(const int* __restrict__ dst, float* __restrict__ deg, int E) {
    int e = blockIdx.x * blockDim.x + threadIdx.x;
    if (e < E) atomicAdd(&deg[dst[e]], 1.0f);
}

__global__ void dinv_kernel(float* __restrict__ deg, int n) {
    int i = blockIdx.x * blockDim.x + threadIdx.x;
    if (i < n) deg[i] = rsqrtf(deg[i] + 1.0f);   // in-place: deg -> dinv
}

// ---------------- h = state @ convW^T ----------------
__global__ void conv_gemm(const float* __restrict__ x, const float* __restrict__ W,
                          float* __restrict__ h, int nrows) {
    __shared__ float Wt[64 * 65];     // transposed, padded
    __shared__ float sx[4][64];
    for (int idx = threadIdx.x; idx < 4096; idx += 256) {
        int j = idx >> 6, k = idx & 63;
        Wt[k * 65 + j] = W[idx];
    }
    __syncthreads();
    int r = threadIdx.x >> 6, c = threadIdx.x & 63;
    int ngroups = (nrows + 3) >> 2;
    for (int g = blockIdx.x; g < ngroups; g += gridDim.x) {
        int row = g * 4 + r;
        sx[r][c] = (row < nrows) ? x[row * 64 + c] : 0.f;
        __syncthreads();
        float acc = 0.f;
        #pragma unroll
        for (int k = 0; k < 64; ++k) acc += sx[r][k] * Wt[k * 65 + c];
        if (row < nrows) h[row * 64 + c] = acc;
        __syncthreads();
    }
}

// ---------------- edge scatter ----------------
__global__ void scatter_kernel(const int* __restrict__ src, const int* __restrict__ dst,
                               const float* __restrict__ h, const float* __restrict__ dinv,
                               float* __restrict__ agg, int E) {
    int idx = blockIdx.x * blockDim.x + threadIdx.x;   // E*64 = 76.8M < 2^31
    if (idx >= E * 64) return;
    int e = idx >> 6;
    int c = idx & 63;
    int s = src[e], d = dst[e];
    float norm = dinv[s] * dinv[d];
    atomicAdd(&agg[d * 64 + c], h[s * 64 + c] * norm);
}

// ---------------- self-loop + bias + relu + residual ----------------
__global__ void selfloop_kernel(float* __restrict__ xbuf, const float* __restrict__ h,
                                const float* __restrict__ state, const float* __restrict__ dinv,
                                const float* __restrict__ convb, int total) {
    int idx = blockIdx.x * blockDim.x + threadIdx.x;
    if (idx >= total) return;
    int node = idx >> 6, c = idx & 63;
    float di = dinv[node];
    float v = xbuf[idx] + h[idx] * di * di + convb[c];
    v = (v > 0.f) ? v : 0.f;
    xbuf[idx] = v + state[idx];
}

// ---------------- global branch: [B,384]@[384,256] -> leaky -> @[256,10] -> leaky ----------------
#define TB 8
__global__ void global_branch(const float* __restrict__ state,
                              const float* __restrict__ gW1, const float* __restrict__ gb1,
                              const float* __restrict__ gW2, const float* __restrict__ gb2,
                              float* __restrict__ xg, int B) {
    __shared__ float sx[TB][384];
    __shared__ float sy[TB][256];
    int b0 = blockIdx.x * TB;
    for (int idx = threadIdx.x; idx < TB * 384; idx += 256) {
        int r = idx / 384, k = idx - r * 384;
        int b = b0 + r;
        sx[r][k] = (b < B) ? state[(long long)b * 384 + k] : 0.f;
    }
    __syncthreads();
    int j = threadIdx.x;   // output column 0..255
    float acc[TB];
    float bj = gb1[j];
    #pragma unroll
    for (int r = 0; r < TB; ++r) acc[r] = bj;
    const float* wrow = gW1 + j * 384;
    for (int k = 0; k < 384; ++k) {
        float w = wrow[k];
        #pragma unroll
        for (int r = 0; r < TB; ++r) acc[r] += sx[r][k] * w;
    }
    #pragma unroll
    for (int r = 0; r < TB; ++r) {
        float v = acc[r];
        sy[r][j] = (v > 0.f) ? v : 0.01f * v;
    }
    __syncthreads();
    if (threadIdx.x < TB * GOUT) {
        int r = threadIdx.x / GOUT, o = threadIdx.x - r * GOUT;
        int b = b0 + r;
        if (b < B) {
            float a = gb2[o];
            const float* w2 = gW2 + o * 256;
            for (int k = 0; k < 256; ++k) a += sy[r][k] * w2[k];
            xg[b * GOUT + o] = (a > 0.f) ? a : 0.01f * a;
        }
    }
}

// ---------------- final MLP per node + softplus + |conc| reduction ----------------
__global__ void mlp_kernel(const float* __restrict__ x, const float* __restrict__ xg,
                           const float* __restrict__ l1W, const float* __restrict__ l1b,
                           const float* __restrict__ l2W, const float* __restrict__ l2b,
                           const float* __restrict__ l3W, const float* __restrict__ l3b,
                           float* __restrict__ out, float* __restrict__ reg_out, int n) {
    __shared__ float s_l1W[32 * 74];
    __shared__ float s_l2W[32 * 32];
    __shared__ float s_l1b[32], s_l2b[32], s_l3W[32];
    __shared__ float s_l3b;
    for (int i = threadIdx.x; i < 32 * 74; i += 256) s_l1W[i] = l1W[i];
    for (int i = threadIdx.x; i < 32 * 32; i += 256) s_l2W[i] = l2W[i];
    if (threadIdx.x < 32) {
        s_l1b[threadIdx.x] = l1b[threadIdx.x];
        s_l2b[threadIdx.x] = l2b[threadIdx.x];
        s_l3W[threadIdx.x] = l3W[threadIdx.x];
    }
    if (threadIdx.x == 0) s_l3b = l3b[0];
    __syncthreads();

    int node = blockIdx.x * blockDim.x + threadIdx.x;
    float conc = 0.f;
    if (node < n) {
        float xin[64];
        #pragma unroll
        for (int k = 0; k < 64; ++k) xin[k] = x[(long long)node * 64 + k];
        int b = node / 6;
        float xgv[10];
        #pragma unroll
        for (int k = 0; k < 10; ++k) xgv[k] = xg[b * 10 + k];
        float y1[32];
        for (int hh = 0; hh < 32; ++hh) {
            float a = s_l1b[hh];
            const float* w = &s_l1W[hh * 74];
            #pragma unroll
            for (int k = 0; k < 64; ++k) a += w[k] * xin[k];
            #pragma unroll
            for (int k = 0; k < 10; ++k) a += w[64 + k] * xgv[k];
            y1[hh] = (a > 0.f) ? a : 0.01f * a;
        }
        float y2[32];
        for (int hh = 0; hh < 32; ++hh) {
            float a = s_l2b[hh];
            const float* w = &s_l2W[hh * 32];
            #pragma unroll
            for (int k = 0; k < 32; ++k) a += w[k] * y1[k];
            y2[hh] = (a > 0.f) ? a : 0.01f * a;
        }
        float a = s_l3b;
        #pragma unroll
        for (int k = 0; k < 32; ++k) a += s_l3W[k] * y2[k];
        conc = (a > 20.f) ? a : log1pf(expf(a));
        out[node] = conc;
    }
    // block reduction of |conc| for regularize
    float v = fabsf(conc);
    for (int off = 32; off > 0; off >>= 1) v += __shfl_down(v, off, 64);
    __shared__ float wsum[4];
    if ((threadIdx.x & 63) == 0) wsum[threadIdx.x >> 6] = v;
    __syncthreads();
    if (threadIdx.x == 0) {
        float s = wsum[0] + wsum[1] + wsum[2] + wsum[3];
        atomicAdd(reg_out, s * (1.0f / (float)N_NODES));
    }
}

// ---------------- per-group normalize ----------------
__global__ void normalize_kernel(float* __restrict__ out, int B) {
    int b = blockIdx.x * blockDim.x + threadIdx.x;
    if (b >= B) return;
    float v[ACT];
    float s = 0.f;
    #pragma unroll
    for (int i = 0; i < ACT; ++i) { v[i] = out[b * ACT + i]; s += v[i]; }
    s += 1e-20f;
    #pragma unroll
    for (int i = 0; i < ACT; ++i) out[b * ACT + i] = v[i] / s;
}

extern "C" void kernel_launch(void* const* d_in, const int* in_sizes, int n_in,
                              void* d_out, int out_size, void* d_ws, size_t ws_size,
                              hipStream_t stream) {
    const float* state = (const float*)d_in[0];
    const int*   ei    = (const int*)d_in[1];
    const float* convW = (const float*)d_in[2];
    const float* convb = (const float*)d_in[3];
    const float* gW1   = (const float*)d_in[4];
    const float* gb1   = (const float*)d_in[5];
    const float* gW2   = (const float*)d_in[6];
    const float* gb2   = (const float*)d_in[7];
    const float* l1W   = (const float*)d_in[8];
    const float* l1b   = (const float*)d_in[9];
    const float* l2W   = (const float*)d_in[10];
    const float* l2b   = (const float*)d_in[11];
    const float* l3W   = (const float*)d_in[12];
    const float* l3b   = (const float*)d_in[13];

    const int n = N_NODES, E = N_EDGES, B = B_ROWS;
    const int* src = ei;
    const int* dst = ei + E;

    float* ws   = (float*)d_ws;
    float* deg  = ws;                       // [N] -> becomes dinv
    float* h    = ws + 150016;              // [N*64]
    float* agg  = h + (size_t)n * 64;       // [N*64] -> becomes x after selfloop
    float* xg   = h;                        // reuse h region after h is dead (K6 runs after K5)

    float* out    = (float*)d_out;          // [150000] action (conc first), + [1] regularize
    float* regptr = out + n;

    hipMemsetAsync(deg, 0, n * sizeof(float), stream);
    hipMemsetAsync(agg, 0, (size_t)n * 64 * sizeof(float), stream);
    hipMemsetAsync(regptr, 0, sizeof(float), stream);

    degree_kernel<<<(E + 255) / 256, 256, 0, stream>>>(dst, deg, E);
    dinv_kernel<<<(n + 255) / 256, 256, 0, stream>>>(deg, n);
    conv_gemm<<<1024, 256, 0, stream>>>(state, convW, h, n);
    scatter_kernel<<<(E * 64) / 256, 256, 0, stream>>>(src, dst, h, deg, agg, E);
    selfloop_kernel<<<(n * 64) / 256, 256, 0, stream>>>(agg, h, state, deg, convb, n * 64);
    global_branch<<<(B + TB - 1) / TB, 256, 0, stream>>>(state, gW1, gb1, gW2, gb2, xg, B);
    mlp_kernel<<<(n + 255) / 256, 256, 0, stream>>>(agg, xg, l1W, l1b, l2W, l2b, l3W, l3b,
                                                    out, regptr, n);
    normalize_kernel<<<(B + 255) / 256, 256, 0, stream>>>(out, B);
}

// Round 2
// 837.963 us; speedup vs baseline: 1.1296x; 1.1296x over previous
//
#include <hip/hip_runtime.h>
#include <math.h>

#define N_NODES 150000
#define N_EDGES 1200000
#define C 64
#define ACT 6
#define B_ROWS 25000   // N/ACT
#define GLOB 256
#define GOUT 10
#define H 32

#define NPAD 150016            // N rounded up (alignment)
#define SCAN_CHUNK 1024
#define NSCAN 147              // ceil(150000/1024)

// ---------------- degree histogram (int) ----------------
__global__ void degree_kernel(const int* __restrict__ dst, int* __restrict__ counts, int E) {
    int e = blockIdx.x * blockDim.x + threadIdx.x;
    if (e < E) atomicAdd(&counts[dst[e]], 1);
}

// ---------------- prefix scan (3 kernels) ----------------
__global__ void scan_block(const int* __restrict__ counts, int* __restrict__ rowptr,
                           int* __restrict__ bsum, int n) {
    __shared__ int lds[256];
    int base = blockIdx.x * SCAN_CHUNK;
    int t = threadIdx.x;
    int v[4]; int s = 0;
    #pragma unroll
    for (int i = 0; i < 4; ++i) {
        int idx = base + t * 4 + i;
        v[i] = (idx < n) ? counts[idx] : 0;
        s += v[i];
    }
    lds[t] = s; __syncthreads();
    for (int off = 1; off < 256; off <<= 1) {
        int x = (t >= off) ? lds[t - off] : 0;
        __syncthreads();
        lds[t] += x;
        __syncthreads();
    }
    int excl = lds[t] - s;
    if (t == 255) bsum[blockIdx.x] = lds[255];
    int run = excl;
    #pragma unroll
    for (int i = 0; i < 4; ++i) {
        int idx = base + t * 4 + i;
        if (idx < n) rowptr[idx] = run;
        run += v[i];
    }
}

__global__ void scan_sums(int* __restrict__ bsum, int nb) {
    __shared__ int lds[256];
    int t = threadIdx.x;
    int v = (t < nb) ? bsum[t] : 0;
    lds[t] = v; __syncthreads();
    for (int off = 1; off < 256; off <<= 1) {
        int x = (t >= off) ? lds[t - off] : 0;
        __syncthreads();
        lds[t] += x;
        __syncthreads();
    }
    if (t < nb) bsum[t] = lds[t] - v;   // exclusive
}

__global__ void scan_add(int* __restrict__ rowptr, const int* __restrict__ bsum,
                         const int* __restrict__ counts, float* __restrict__ dinv,
                         int n, int E) {
    int i = blockIdx.x * blockDim.x + threadIdx.x;
    if (i < n) {
        rowptr[i] += bsum[i >> 10];
        dinv[i] = rsqrtf((float)counts[i] + 1.0f);
    }
    if (i == n) rowptr[n] = E;
}

// ---------------- CSR fill ----------------
__global__ void fill_csr(const int* __restrict__ src, const int* __restrict__ dst,
                         const int* __restrict__ rowptr, int* __restrict__ cursor,
                         int* __restrict__ csr, int E) {
    int e = blockIdx.x * blockDim.x + threadIdx.x;
    if (e >= E) return;
    int d = dst[e];
    int pos = rowptr[d] + atomicAdd(&cursor[d], 1);
    csr[pos] = src[e];
}

// ---------------- h = state @ convW^T ----------------
__global__ void conv_gemm(const float* __restrict__ x, const float* __restrict__ W,
                          float* __restrict__ h, int nrows) {
    __shared__ float Wt[64 * 65];     // transposed, padded
    __shared__ float sx[4][64];
    for (int idx = threadIdx.x; idx < 4096; idx += 256) {
        int j = idx >> 6, k = idx & 63;
        Wt[k * 65 + j] = W[idx];
    }
    __syncthreads();
    int r = threadIdx.x >> 6, c = threadIdx.x & 63;
    int ngroups = (nrows + 3) >> 2;
    for (int g = blockIdx.x; g < ngroups; g += gridDim.x) {
        int row = g * 4 + r;
        sx[r][c] = (row < nrows) ? x[row * 64 + c] : 0.f;
        __syncthreads();
        float acc = 0.f;
        #pragma unroll
        for (int k = 0; k < 64; ++k) acc += sx[r][k] * Wt[k * 65 + c];
        if (row < nrows) h[row * 64 + c] = acc;
        __syncthreads();
    }
}

// ---------------- gather (CSR) + self-loop + bias + relu + residual ----------------
__global__ void gather_fused(const int* __restrict__ rowptr, const int* __restrict__ csr,
                             const float* __restrict__ h, const float* __restrict__ dinv,
                             const float* __restrict__ convb, const float* __restrict__ state,
                             float* __restrict__ x, int n) {
    int node = blockIdx.x * 4 + (threadIdx.x >> 6);
    if (node >= n) return;
    int lane = threadIdx.x & 63;
    int beg = rowptr[node], end = rowptr[node + 1];
    float dd = dinv[node];
    float acc = 0.f;
    for (int e = beg; e < end; ++e) {
        int s = csr[e];                      // wave-uniform load (broadcast)
        acc += dinv[s] * h[(size_t)s * 64 + lane];
    }
    size_t off = (size_t)node * 64 + lane;
    float v = dd * acc + h[off] * dd * dd + convb[lane];
    v = (v > 0.f) ? v : 0.f;
    x[off] = v + state[off];
}

// ---------------- global branch: [B,384]@[384,256] -> leaky -> @[256,10] -> leaky ----------------
#define TB 8
__global__ void global_branch(const float* __restrict__ state,
                              const float* __restrict__ gW1, const float* __restrict__ gb1,
                              const float* __restrict__ gW2, const float* __restrict__ gb2,
                              float* __restrict__ xg, int B) {
    __shared__ float sx[TB][384];
    __shared__ float sy[TB][256];
    int b0 = blockIdx.x * TB;
    for (int idx = threadIdx.x; idx < TB * 384; idx += 256) {
        int r = idx / 384, k = idx - r * 384;
        int b = b0 + r;
        sx[r][k] = (b < B) ? state[(long long)b * 384 + k] : 0.f;
    }
    __syncthreads();
    int j = threadIdx.x;
    float acc[TB];
    float bj = gb1[j];
    #pragma unroll
    for (int r = 0; r < TB; ++r) acc[r] = bj;
    const float* wrow = gW1 + j * 384;
    for (int k = 0; k < 384; ++k) {
        float w = wrow[k];
        #pragma unroll
        for (int r = 0; r < TB; ++r) acc[r] += sx[r][k] * w;
    }
    #pragma unroll
    for (int r = 0; r < TB; ++r) {
        float v = acc[r];
        sy[r][j] = (v > 0.f) ? v : 0.01f * v;
    }
    __syncthreads();
    if (threadIdx.x < TB * GOUT) {
        int r = threadIdx.x / GOUT, o = threadIdx.x - r * GOUT;
        int b = b0 + r;
        if (b < B) {
            float a = gb2[o];
            const float* w2 = gW2 + o * 256;
            for (int k = 0; k < 256; ++k) a += sy[r][k] * w2[k];
            xg[b * GOUT + o] = (a > 0.f) ? a : 0.01f * a;
        }
    }
}

// ---------------- final MLP + softplus + normalize + |conc| reduction ----------------
// block = 256 threads; first 252 handle nodes (42 whole groups of 6)
#define MLP_NODES 252
__global__ void mlp_kernel(const float* __restrict__ x, const float* __restrict__ xg,
                           const float* __restrict__ l1W, const float* __restrict__ l1b,
                           const float* __restrict__ l2W, const float* __restrict__ l2b,
                           const float* __restrict__ l3W, const float* __restrict__ l3b,
                           float* __restrict__ out, float* __restrict__ reg_out, int n) {
    __shared__ float s_l1W[32 * 74];
    __shared__ float s_l2W[32 * 32];
    __shared__ float s_l1b[32], s_l2b[32], s_l3W[32];
    __shared__ float s_l3b;
    __shared__ float s_conc[MLP_NODES];
    for (int i = threadIdx.x; i < 32 * 74; i += 256) s_l1W[i] = l1W[i];
    for (int i = threadIdx.x; i < 32 * 32; i += 256) s_l2W[i] = l2W[i];
    if (threadIdx.x < 32) {
        s_l1b[threadIdx.x] = l1b[threadIdx.x];
        s_l2b[threadIdx.x] = l2b[threadIdx.x];
        s_l3W[threadIdx.x] = l3W[threadIdx.x];
    }
    if (threadIdx.x == 0) s_l3b = l3b[0];
    __syncthreads();

    int local = threadIdx.x;
    int node = blockIdx.x * MLP_NODES + local;
    bool active = (local < MLP_NODES) && (node < n);
    float conc = 0.f;
    if (active) {
        float xin[64];
        #pragma unroll
        for (int k = 0; k < 64; ++k) xin[k] = x[(long long)node * 64 + k];
        int b = node / 6;
        float xgv[10];
        #pragma unroll
        for (int k = 0; k < 10; ++k) xgv[k] = xg[b * 10 + k];
        float y1[32];
        for (int hh = 0; hh < 32; ++hh) {
            float a = s_l1b[hh];
            const float* w = &s_l1W[hh * 74];
            #pragma unroll
            for (int k = 0; k < 64; ++k) a += w[k] * xin[k];
            #pragma unroll
            for (int k = 0; k < 10; ++k) a += w[64 + k] * xgv[k];
            y1[hh] = (a > 0.f) ? a : 0.01f * a;
        }
        float y2[32];
        for (int hh = 0; hh < 32; ++hh) {
            float a = s_l2b[hh];
            const float* w = &s_l2W[hh * 32];
            #pragma unroll
            for (int k = 0; k < 32; ++k) a += w[k] * y1[k];
            y2[hh] = (a > 0.f) ? a : 0.01f * a;
        }
        float a = s_l3b;
        #pragma unroll
        for (int k = 0; k < 32; ++k) a += s_l3W[k] * y2[k];
        conc = (a > 20.f) ? a : log1pf(expf(a));
        s_conc[local] = conc;
    } else if (local < MLP_NODES) {
        s_conc[local] = 0.f;
    }

    // regularize: block reduction of |conc|
    float v = fabsf(conc);
    for (int off = 32; off > 0; off >>= 1) v += __shfl_down(v, off, 64);
    __shared__ float wsum[4];
    if ((threadIdx.x & 63) == 0) wsum[threadIdx.x >> 6] = v;
    __syncthreads();
    if (threadIdx.x == 0) {
        float s = wsum[0] + wsum[1] + wsum[2] + wsum[3];
        atomicAdd(reg_out, s * (1.0f / (float)N_NODES));
    }

    // normalize within group of 6 (groups never straddle blocks: 252 % 6 == 0)
    if (active) {
        int g0 = (local / 6) * 6;
        float s = 0.f;
        #pragma unroll
        for (int i = 0; i < 6; ++i) s += s_conc[g0 + i];
        out[node] = conc / (s + 1e-20f);
    }
}

extern "C" void kernel_launch(void* const* d_in, const int* in_sizes, int n_in,
                              void* d_out, int out_size, void* d_ws, size_t ws_size,
                              hipStream_t stream) {
    const float* state = (const float*)d_in[0];
    const int*   ei    = (const int*)d_in[1];
    const float* convW = (const float*)d_in[2];
    const float* convb = (const float*)d_in[3];
    const float* gW1   = (const float*)d_in[4];
    const float* gb1   = (const float*)d_in[5];
    const float* gW2   = (const float*)d_in[6];
    const float* gb2   = (const float*)d_in[7];
    const float* l1W   = (const float*)d_in[8];
    const float* l1b   = (const float*)d_in[9];
    const float* l2W   = (const float*)d_in[10];
    const float* l2b   = (const float*)d_in[11];
    const float* l3W   = (const float*)d_in[12];
    const float* l3b   = (const float*)d_in[13];

    const int n = N_NODES, E = N_EDGES, B = B_ROWS;
    const int* src = ei;
    const int* dst = ei + E;

    // ---- workspace layout ----
    char* w = (char*)d_ws;
    int*   counts = (int*)w;                 w += NPAD * 4;
    int*   cursor = (int*)w;                 w += NPAD * 4;
    int*   rowptr = (int*)w;                 w += NPAD * 4;   // N+1 fits
    int*   bsum   = (int*)w;                 w += 256 * 4;
    float* dinv   = (float*)w;               w += NPAD * 4;
    int*   csr    = (int*)w;                 w += (size_t)E * 4;
    float* h      = (float*)w;               w += (size_t)n * 64 * 4;
    float* x      = (float*)w;               /* w += n*64*4 */
    float* xg     = h;                       // reuse h region after gather is done

    float* out    = (float*)d_out;           // [150000] action + [1] regularize
    float* regptr = out + n;

    hipMemsetAsync(counts, 0, NPAD * 4, stream);
    hipMemsetAsync(cursor, 0, NPAD * 4, stream);
    hipMemsetAsync(regptr, 0, 4, stream);

    degree_kernel<<<(E + 255) / 256, 256, 0, stream>>>(dst, counts, E);
    scan_block<<<NSCAN, 256, 0, stream>>>(counts, rowptr, bsum, n);
    scan_sums<<<1, 256, 0, stream>>>(bsum, NSCAN);
    scan_add<<<(n + 256) / 256, 256, 0, stream>>>(rowptr, bsum, counts, dinv, n, E);
    fill_csr<<<(E + 255) / 256, 256, 0, stream>>>(src, dst, rowptr, cursor, csr, E);
    conv_gemm<<<1024, 256, 0, stream>>>(state, convW, h, n);
    gather_fused<<<(n + 3) / 4, 256, 0, stream>>>(rowptr, csr, h, dinv, convb, state, x, n);
    global_branch<<<(B + TB - 1) / TB, 256, 0, stream>>>(state, gW1, gb1, gW2, gb2, xg, B);
    mlp_kernel<<<(n + MLP_NODES - 1) / MLP_NODES, 256, 0, stream>>>(
        x, xg, l1W, l1b, l2W, l2b, l3W, l3b, out, regptr, n);
}

// Round 3
// 738.173 us; speedup vs baseline: 1.2823x; 1.1352x over previous
//
#include <hip/hip_runtime.h>
#include <math.h>

#define N_NODES 150000
#define N_EDGES 1200000
#define C 64
#define ACT 6
#define B_ROWS 25000   // N/ACT
#define GLOB 256
#define GOUT 10
#define H 32

#define NPAD 150016            // N rounded up (alignment)
#define SCAN_CHUNK 1024
#define NSCAN 147              // ceil(150000/1024)

// ---------------- degree histogram (int) ----------------
__global__ void degree_kernel(const int* __restrict__ dst, int* __restrict__ counts, int E) {
    int e = blockIdx.x * blockDim.x + threadIdx.x;
    if (e < E) atomicAdd(&counts[dst[e]], 1);
}

// ---------------- prefix scan (3 kernels) ----------------
__global__ void scan_block(const int* __restrict__ counts, int* __restrict__ rowptr,
                           int* __restrict__ bsum, int n) {
    __shared__ int lds[256];
    int base = blockIdx.x * SCAN_CHUNK;
    int t = threadIdx.x;
    int v[4]; int s = 0;
    #pragma unroll
    for (int i = 0; i < 4; ++i) {
        int idx = base + t * 4 + i;
        v[i] = (idx < n) ? counts[idx] : 0;
        s += v[i];
    }
    lds[t] = s; __syncthreads();
    for (int off = 1; off < 256; off <<= 1) {
        int x = (t >= off) ? lds[t - off] : 0;
        __syncthreads();
        lds[t] += x;
        __syncthreads();
    }
    int excl = lds[t] - s;
    if (t == 255) bsum[blockIdx.x] = lds[255];
    int run = excl;
    #pragma unroll
    for (int i = 0; i < 4; ++i) {
        int idx = base + t * 4 + i;
        if (idx < n) rowptr[idx] = run;
        run += v[i];
    }
}

__global__ void scan_sums(int* __restrict__ bsum, int nb) {
    __shared__ int lds[256];
    int t = threadIdx.x;
    int v = (t < nb) ? bsum[t] : 0;
    lds[t] = v; __syncthreads();
    for (int off = 1; off < 256; off <<= 1) {
        int x = (t >= off) ? lds[t - off] : 0;
        __syncthreads();
        lds[t] += x;
        __syncthreads();
    }
    if (t < nb) bsum[t] = lds[t] - v;   // exclusive
}

__global__ void scan_add(int* __restrict__ rowptr, const int* __restrict__ bsum,
                         const int* __restrict__ counts, float* __restrict__ dinv,
                         int n, int E) {
    int i = blockIdx.x * blockDim.x + threadIdx.x;
    if (i < n) {
        rowptr[i] += bsum[i >> 10];
        dinv[i] = rsqrtf((float)counts[i] + 1.0f);
    }
    if (i == n) rowptr[n] = E;
}

// ---------------- CSR fill ----------------
__global__ void fill_csr(const int* __restrict__ src, const int* __restrict__ dst,
                         const int* __restrict__ rowptr, int* __restrict__ cursor,
                         int* __restrict__ csr, int E) {
    int e = blockIdx.x * blockDim.x + threadIdx.x;
    if (e >= E) return;
    int d = dst[e];
    int pos = rowptr[d] + atomicAdd(&cursor[d], 1);
    csr[pos] = src[e];
}

// ---------------- h = state @ convW^T ----------------
__global__ void conv_gemm(const float* __restrict__ x, const float* __restrict__ W,
                          float* __restrict__ h, int nrows) {
    __shared__ float Wt[64 * 65];     // transposed, padded
    __shared__ float sx[4][64];
    for (int idx = threadIdx.x; idx < 4096; idx += 256) {
        int j = idx >> 6, k = idx & 63;
        Wt[k * 65 + j] = W[idx];
    }
    __syncthreads();
    int r = threadIdx.x >> 6, c = threadIdx.x & 63;
    int ngroups = (nrows + 3) >> 2;
    for (int g = blockIdx.x; g < ngroups; g += gridDim.x) {
        int row = g * 4 + r;
        sx[r][c] = (row < nrows) ? x[row * 64 + c] : 0.f;
        __syncthreads();
        float acc = 0.f;
        #pragma unroll
        for (int k = 0; k < 64; ++k) acc += sx[r][k] * Wt[k * 65 + c];
        if (row < nrows) h[row * 64 + c] = acc;
        __syncthreads();
    }
}

// ---------------- gather (CSR) + self-loop + bias + relu + residual ----------------
__global__ void gather_fused(const int* __restrict__ rowptr, const int* __restrict__ csr,
                             const float* __restrict__ h, const float* __restrict__ dinv,
                             const float* __restrict__ convb, const float* __restrict__ state,
                             float* __restrict__ x, int n) {
    int node = blockIdx.x * 4 + (threadIdx.x >> 6);
    if (node >= n) return;
    int lane = threadIdx.x & 63;
    int beg = rowptr[node], end = rowptr[node + 1];
    float dd = dinv[node];
    float acc = 0.f;
    for (int e = beg; e < end; ++e) {
        int s = csr[e];                      // wave-uniform load (broadcast)
        acc += dinv[s] * h[(size_t)s * 64 + lane];
    }
    size_t off = (size_t)node * 64 + lane;
    float v = dd * acc + h[off] * dd * dd + convb[lane];
    v = (v > 0.f) ? v : 0.f;
    x[off] = v + state[off];
}

// ---------------- global branch layer 1: y1 = leaky(state[B,384] @ gW1^T + gb1), [B,256] ----------------
// Register-blocked fp32 GEMM: block tile 128(M) x 64(N), thread tile 8x4, KC=16.
#define G1_SA 132   // aT row stride (128 + 4)
#define G1_SB 68    // bT row stride (64 + 4)
__global__ __launch_bounds__(256) void global_gemm1(
        const float* __restrict__ A,     // state as [25000][384]
        const float* __restrict__ Wg,    // gW1 [256][384]
        const float* __restrict__ bias,  // gb1 [256]
        float* __restrict__ y1, int M) {
    __shared__ float aT[16 * G1_SA];
    __shared__ float bT[16 * G1_SB];

    int t = threadIdx.x;
    int mb = blockIdx.x >> 2;            // 196 row-blocks
    int nb = blockIdx.x & 3;             // 4 col-blocks of 64
    int row0 = mb * 128;
    int col0 = nb * 64;

    // staging maps
    int arow = t >> 1;                   // 0..127
    int akseg = (t & 1) * 8;             // 0 or 8
    int brow = t >> 2;                   // 0..63 (col within tile)
    int bkseg = (t & 3) * 4;             // 0,4,8,12

    int ty = t >> 4, tx = t & 15;
    int r0 = ty * 8, c0 = tx * 4;

    float acc[8][4];
    #pragma unroll
    for (int r = 0; r < 8; ++r)
        #pragma unroll
        for (int c = 0; c < 4; ++c) acc[r][c] = 0.f;

    const int arowg = row0 + arow;
    const bool avalid = arowg < M;

    for (int chunk = 0; chunk < 24; ++chunk) {
        int kk0 = chunk * 16;
        __syncthreads();
        // stage A: rows row0..+127, k kk0..+15, transposed into aT[k][row]
        {
            float4 v0 = make_float4(0.f, 0.f, 0.f, 0.f), v1 = v0;
            if (avalid) {
                const float* p = A + (size_t)arowg * 384 + kk0 + akseg;
                v0 = *(const float4*)p;
                v1 = *(const float4*)(p + 4);
            }
            aT[(akseg + 0) * G1_SA + arow] = v0.x;
            aT[(akseg + 1) * G1_SA + arow] = v0.y;
            aT[(akseg + 2) * G1_SA + arow] = v0.z;
            aT[(akseg + 3) * G1_SA + arow] = v0.w;
            aT[(akseg + 4) * G1_SA + arow] = v1.x;
            aT[(akseg + 5) * G1_SA + arow] = v1.y;
            aT[(akseg + 6) * G1_SA + arow] = v1.z;
            aT[(akseg + 7) * G1_SA + arow] = v1.w;
        }
        // stage B: cols col0..+63, k kk0..+15, transposed into bT[k][col]
        {
            const float* p = Wg + (size_t)(col0 + brow) * 384 + kk0 + bkseg;
            float4 v = *(const float4*)p;
            bT[(bkseg + 0) * G1_SB + brow] = v.x;
            bT[(bkseg + 1) * G1_SB + brow] = v.y;
            bT[(bkseg + 2) * G1_SB + brow] = v.z;
            bT[(bkseg + 3) * G1_SB + brow] = v.w;
        }
        __syncthreads();

        #pragma unroll
        for (int kk = 0; kk < 16; ++kk) {
            float4 a0 = *(const float4*)&aT[kk * G1_SA + r0];
            float4 a1 = *(const float4*)&aT[kk * G1_SA + r0 + 4];
            float4 bb = *(const float4*)&bT[kk * G1_SB + c0];
            float av[8] = {a0.x, a0.y, a0.z, a0.w, a1.x, a1.y, a1.z, a1.w};
            float bv[4] = {bb.x, bb.y, bb.z, bb.w};
            #pragma unroll
            for (int r = 0; r < 8; ++r)
                #pragma unroll
                for (int c = 0; c < 4; ++c) acc[r][c] += av[r] * bv[c];
        }
    }

    // epilogue: bias + leaky, store float4 per row
    float bv[4];
    #pragma unroll
    for (int c = 0; c < 4; ++c) bv[c] = bias[col0 + c0 + c];
    #pragma unroll
    for (int r = 0; r < 8; ++r) {
        int row = row0 + r0 + r;
        if (row < M) {
            float4 o;
            float v0 = acc[r][0] + bv[0];
            float v1 = acc[r][1] + bv[1];
            float v2 = acc[r][2] + bv[2];
            float v3 = acc[r][3] + bv[3];
            o.x = (v0 > 0.f) ? v0 : 0.01f * v0;
            o.y = (v1 > 0.f) ? v1 : 0.01f * v1;
            o.z = (v2 > 0.f) ? v2 : 0.01f * v2;
            o.w = (v3 > 0.f) ? v3 : 0.01f * v3;
            *(float4*)&y1[(size_t)row * 256 + col0 + c0] = o;
        }
    }
}

// ---------------- global branch layer 2: xg = leaky(y1 @ gW2^T + gb2), [B,10] ----------------
// one wave per b-row; lanes partition k=256; shuffle-reduce per output
__global__ void global_gemm2(const float* __restrict__ y1, const float* __restrict__ W2,
                             const float* __restrict__ b2, float* __restrict__ xg, int B) {
    int wave = (blockIdx.x * blockDim.x + threadIdx.x) >> 6;
    int lane = threadIdx.x & 63;
    if (wave >= B) return;
    const float* yr = y1 + (size_t)wave * 256;
    float yv[4];
    #pragma unroll
    for (int j = 0; j < 4; ++j) yv[j] = yr[lane + 64 * j];
    float res[10];
    #pragma unroll
    for (int o = 0; o < 10; ++o) {
        const float* w = W2 + o * 256;
        float p = 0.f;
        #pragma unroll
        for (int j = 0; j < 4; ++j) p += yv[j] * w[lane + 64 * j];
        #pragma unroll
        for (int off = 32; off > 0; off >>= 1) p += __shfl_down(p, off, 64);
        res[o] = p;
    }
    if (lane == 0) {
        #pragma unroll
        for (int o = 0; o < 10; ++o) {
            float v = res[o] + b2[o];
            xg[wave * 10 + o] = (v > 0.f) ? v : 0.01f * v;
        }
    }
}

// ---------------- final MLP + softplus + normalize + |conc| reduction ----------------
#define MLP_NODES 252
__global__ void mlp_kernel(const float* __restrict__ x, const float* __restrict__ xg,
                           const float* __restrict__ l1W, const float* __restrict__ l1b,
                           const float* __restrict__ l2W, const float* __restrict__ l2b,
                           const float* __restrict__ l3W, const float* __restrict__ l3b,
                           float* __restrict__ out, float* __restrict__ reg_out, int n) {
    __shared__ float s_l1W[32 * 74];
    __shared__ float s_l2W[32 * 32];
    __shared__ float s_l1b[32], s_l2b[32], s_l3W[32];
    __shared__ float s_l3b;
    __shared__ float s_conc[MLP_NODES];
    for (int i = threadIdx.x; i < 32 * 74; i += 256) s_l1W[i] = l1W[i];
    for (int i = threadIdx.x; i < 32 * 32; i += 256) s_l2W[i] = l2W[i];
    if (threadIdx.x < 32) {
        s_l1b[threadIdx.x] = l1b[threadIdx.x];
        s_l2b[threadIdx.x] = l2b[threadIdx.x];
        s_l3W[threadIdx.x] = l3W[threadIdx.x];
    }
    if (threadIdx.x == 0) s_l3b = l3b[0];
    __syncthreads();

    int local = threadIdx.x;
    int node = blockIdx.x * MLP_NODES + local;
    bool active = (local < MLP_NODES) && (node < n);
    float conc = 0.f;
    if (active) {
        float xin[64];
        #pragma unroll
        for (int k = 0; k < 64; ++k) xin[k] = x[(long long)node * 64 + k];
        int b = node / 6;
        float xgv[10];
        #pragma unroll
        for (int k = 0; k < 10; ++k) xgv[k] = xg[b * 10 + k];
        float y1[32];
        for (int hh = 0; hh < 32; ++hh) {
            float a = s_l1b[hh];
            const float* w = &s_l1W[hh * 74];
            #pragma unroll
            for (int k = 0; k < 64; ++k) a += w[k] * xin[k];
            #pragma unroll
            for (int k = 0; k < 10; ++k) a += w[64 + k] * xgv[k];
            y1[hh] = (a > 0.f) ? a : 0.01f * a;
        }
        float y2[32];
        for (int hh = 0; hh < 32; ++hh) {
            float a = s_l2b[hh];
            const float* w = &s_l2W[hh * 32];
            #pragma unroll
            for (int k = 0; k < 32; ++k) a += w[k] * y1[k];
            y2[hh] = (a > 0.f) ? a : 0.01f * a;
        }
        float a = s_l3b;
        #pragma unroll
        for (int k = 0; k < 32; ++k) a += s_l3W[k] * y2[k];
        conc = (a > 20.f) ? a : log1pf(expf(a));
        s_conc[local] = conc;
    } else if (local < MLP_NODES) {
        s_conc[local] = 0.f;
    }

    float v = fabsf(conc);
    for (int off = 32; off > 0; off >>= 1) v += __shfl_down(v, off, 64);
    __shared__ float wsum[4];
    if ((threadIdx.x & 63) == 0) wsum[threadIdx.x >> 6] = v;
    __syncthreads();
    if (threadIdx.x == 0) {
        float s = wsum[0] + wsum[1] + wsum[2] + wsum[3];
        atomicAdd(reg_out, s * (1.0f / (float)N_NODES));
    }

    if (active) {
        int g0 = (local / 6) * 6;
        float s = 0.f;
        #pragma unroll
        for (int i = 0; i < 6; ++i) s += s_conc[g0 + i];
        out[node] = conc / (s + 1e-20f);
    }
}

extern "C" void kernel_launch(void* const* d_in, const int* in_sizes, int n_in,
                              void* d_out, int out_size, void* d_ws, size_t ws_size,
                              hipStream_t stream) {
    const float* state = (const float*)d_in[0];
    const int*   ei    = (const int*)d_in[1];
    const float* convW = (const float*)d_in[2];
    const float* convb = (const float*)d_in[3];
    const float* gW1   = (const float*)d_in[4];
    const float* gb1   = (const float*)d_in[5];
    const float* gW2   = (const float*)d_in[6];
    const float* gb2   = (const float*)d_in[7];
    const float* l1W   = (const float*)d_in[8];
    const float* l1b   = (const float*)d_in[9];
    const float* l2W   = (const float*)d_in[10];
    const float* l2b   = (const float*)d_in[11];
    const float* l3W   = (const float*)d_in[12];
    const float* l3b   = (const float*)d_in[13];

    const int n = N_NODES, E = N_EDGES, B = B_ROWS;
    const int* src = ei;
    const int* dst = ei + E;

    // ---- workspace layout ----
    char* w = (char*)d_ws;
    int*   counts = (int*)w;                 w += NPAD * 4;
    int*   cursor = (int*)w;                 w += NPAD * 4;
    int*   rowptr = (int*)w;                 w += NPAD * 4;   // N+1 fits
    int*   bsum   = (int*)w;                 w += 256 * 4;
    float* dinv   = (float*)w;               w += NPAD * 4;
    int*   csr    = (int*)w;                 w += (size_t)E * 4;
    float* h      = (float*)w;               w += (size_t)n * 64 * 4;
    float* x      = (float*)w;               /* w += n*64*4 */
    float* y1     = h;                       // reuse h region after gather (6.4M floats)
    float* xg     = h + 6400000;             // [B*10] after y1 within h region

    float* out    = (float*)d_out;           // [150000] action + [1] regularize
    float* regptr = out + n;

    hipMemsetAsync(counts, 0, NPAD * 4, stream);
    hipMemsetAsync(cursor, 0, NPAD * 4, stream);
    hipMemsetAsync(regptr, 0, 4, stream);

    degree_kernel<<<(E + 255) / 256, 256, 0, stream>>>(dst, counts, E);
    scan_block<<<NSCAN, 256, 0, stream>>>(counts, rowptr, bsum, n);
    scan_sums<<<1, 256, 0, stream>>>(bsum, NSCAN);
    scan_add<<<(n + 256) / 256, 256, 0, stream>>>(rowptr, bsum, counts, dinv, n, E);
    fill_csr<<<(E + 255) / 256, 256, 0, stream>>>(src, dst, rowptr, cursor, csr, E);
    conv_gemm<<<1024, 256, 0, stream>>>(state, convW, h, n);
    gather_fused<<<(n + 3) / 4, 256, 0, stream>>>(rowptr, csr, h, dinv, convb, state, x, n);
    // global branch (after gather: y1/xg alias h)
    global_gemm1<<<196 * 4, 256, 0, stream>>>(state, gW1, gb1, y1, B);
    global_gemm2<<<(B * 64 + 255) / 256, 256, 0, stream>>>(y1, gW2, gb2, xg, B);
    mlp_kernel<<<(n + MLP_NODES - 1) / MLP_NODES, 256, 0, stream>>>(
        x, xg, l1W, l1b, l2W, l2b, l3W, l3b, out, regptr, n);
}

// Round 4
// 578.513 us; speedup vs baseline: 1.6362x; 1.2760x over previous
//
#include <hip/hip_runtime.h>
#include <math.h>

#define N_NODES 150000
#define N_EDGES 1200000
#define C 64
#define ACT 6
#define B_ROWS 25000   // N/ACT
#define GLOB 256
#define GOUT 10
#define H 32

#define NPAD 150016            // N rounded up (alignment)
#define SCAN_CHUNK 1024
#define NSCAN 147              // ceil(150000/1024)

// ---------------- degree histogram (int) ----------------
__global__ void degree_kernel(const int* __restrict__ dst, int* __restrict__ counts, int E) {
    int e = blockIdx.x * blockDim.x + threadIdx.x;
    if (e < E) atomicAdd(&counts[dst[e]], 1);
}

// ---------------- prefix scan (3 kernels) ----------------
__global__ void scan_block(const int* __restrict__ counts, int* __restrict__ rowptr,
                           int* __restrict__ bsum, int n) {
    __shared__ int lds[256];
    int base = blockIdx.x * SCAN_CHUNK;
    int t = threadIdx.x;
    int v[4]; int s = 0;
    #pragma unroll
    for (int i = 0; i < 4; ++i) {
        int idx = base + t * 4 + i;
        v[i] = (idx < n) ? counts[idx] : 0;
        s += v[i];
    }
    lds[t] = s; __syncthreads();
    for (int off = 1; off < 256; off <<= 1) {
        int x = (t >= off) ? lds[t - off] : 0;
        __syncthreads();
        lds[t] += x;
        __syncthreads();
    }
    int excl = lds[t] - s;
    if (t == 255) bsum[blockIdx.x] = lds[255];
    int run = excl;
    #pragma unroll
    for (int i = 0; i < 4; ++i) {
        int idx = base + t * 4 + i;
        if (idx < n) rowptr[idx] = run;
        run += v[i];
    }
}

__global__ void scan_sums(int* __restrict__ bsum, int nb) {
    __shared__ int lds[256];
    int t = threadIdx.x;
    int v = (t < nb) ? bsum[t] : 0;
    lds[t] = v; __syncthreads();
    for (int off = 1; off < 256; off <<= 1) {
        int x = (t >= off) ? lds[t - off] : 0;
        __syncthreads();
        lds[t] += x;
        __syncthreads();
    }
    if (t < nb) bsum[t] = lds[t] - v;   // exclusive
}

__global__ void scan_add(int* __restrict__ rowptr, const int* __restrict__ bsum,
                         const int* __restrict__ counts, float* __restrict__ dinv,
                         int n, int E) {
    int i = blockIdx.x * blockDim.x + threadIdx.x;
    if (i < n) {
        rowptr[i] += bsum[i >> 10];
        dinv[i] = rsqrtf((float)counts[i] + 1.0f);
    }
    if (i == n) rowptr[n] = E;
}

// ---------------- CSR fill ----------------
__global__ void fill_csr(const int* __restrict__ src, const int* __restrict__ dst,
                         const int* __restrict__ rowptr, int* __restrict__ cursor,
                         int* __restrict__ csr, int E) {
    int e = blockIdx.x * blockDim.x + threadIdx.x;
    if (e >= E) return;
    int d = dst[e];
    int pos = rowptr[d] + atomicAdd(&cursor[d], 1);
    csr[pos] = src[e];
}

// ---------------- h = state @ convW^T ----------------
__global__ void conv_gemm(const float* __restrict__ x, const float* __restrict__ W,
                          float* __restrict__ h, int nrows) {
    __shared__ float Wt[64 * 65];     // transposed, padded
    __shared__ float sx[4][64];
    for (int idx = threadIdx.x; idx < 4096; idx += 256) {
        int j = idx >> 6, k = idx & 63;
        Wt[k * 65 + j] = W[idx];
    }
    __syncthreads();
    int r = threadIdx.x >> 6, c = threadIdx.x & 63;
    int ngroups = (nrows + 3) >> 2;
    for (int g = blockIdx.x; g < ngroups; g += gridDim.x) {
        int row = g * 4 + r;
        sx[r][c] = (row < nrows) ? x[row * 64 + c] : 0.f;
        __syncthreads();
        float acc = 0.f;
        #pragma unroll
        for (int k = 0; k < 64; ++k) acc += sx[r][k] * Wt[k * 65 + c];
        if (row < nrows) h[row * 64 + c] = acc;
        __syncthreads();
    }
}

// ---------------- gather (CSR) + self-loop + bias + relu + residual ----------------
__global__ void gather_fused(const int* __restrict__ rowptr, const int* __restrict__ csr,
                             const float* __restrict__ h, const float* __restrict__ dinv,
                             const float* __restrict__ convb, const float* __restrict__ state,
                             float* __restrict__ x, int n) {
    int node = blockIdx.x * 4 + (threadIdx.x >> 6);
    if (node >= n) return;
    int lane = threadIdx.x & 63;
    int beg = rowptr[node], end = rowptr[node + 1];
    float dd = dinv[node];
    float acc = 0.f;
    for (int e = beg; e < end; ++e) {
        int s = csr[e];                      // wave-uniform load (broadcast)
        acc += dinv[s] * h[(size_t)s * 64 + lane];
    }
    size_t off = (size_t)node * 64 + lane;
    float v = dd * acc + h[off] * dd * dd + convb[lane];
    v = (v > 0.f) ? v : 0.f;
    x[off] = v + state[off];
}

// ---------------- global branch layer 1: y1 = leaky(state[B,384] @ gW1^T + gb1), [B,256] ----------------
#define G1_SA 132   // aT row stride (128 + 4)
#define G1_SB 68    // bT row stride (64 + 4)
__global__ __launch_bounds__(256) void global_gemm1(
        const float* __restrict__ A,     // state as [25000][384]
        const float* __restrict__ Wg,    // gW1 [256][384]
        const float* __restrict__ bias,  // gb1 [256]
        float* __restrict__ y1, int M) {
    __shared__ float aT[16 * G1_SA];
    __shared__ float bT[16 * G1_SB];

    int t = threadIdx.x;
    int mb = blockIdx.x >> 2;
    int nb = blockIdx.x & 3;
    int row0 = mb * 128;
    int col0 = nb * 64;

    int arow = t >> 1;
    int akseg = (t & 1) * 8;
    int brow = t >> 2;
    int bkseg = (t & 3) * 4;

    int ty = t >> 4, tx = t & 15;
    int r0 = ty * 8, c0 = tx * 4;

    float acc[8][4];
    #pragma unroll
    for (int r = 0; r < 8; ++r)
        #pragma unroll
        for (int c = 0; c < 4; ++c) acc[r][c] = 0.f;

    const int arowg = row0 + arow;
    const bool avalid = arowg < M;

    for (int chunk = 0; chunk < 24; ++chunk) {
        int kk0 = chunk * 16;
        __syncthreads();
        {
            float4 v0 = make_float4(0.f, 0.f, 0.f, 0.f), v1 = v0;
            if (avalid) {
                const float* p = A + (size_t)arowg * 384 + kk0 + akseg;
                v0 = *(const float4*)p;
                v1 = *(const float4*)(p + 4);
            }
            aT[(akseg + 0) * G1_SA + arow] = v0.x;
            aT[(akseg + 1) * G1_SA + arow] = v0.y;
            aT[(akseg + 2) * G1_SA + arow] = v0.z;
            aT[(akseg + 3) * G1_SA + arow] = v0.w;
            aT[(akseg + 4) * G1_SA + arow] = v1.x;
            aT[(akseg + 5) * G1_SA + arow] = v1.y;
            aT[(akseg + 6) * G1_SA + arow] = v1.z;
            aT[(akseg + 7) * G1_SA + arow] = v1.w;
        }
        {
            const float* p = Wg + (size_t)(col0 + brow) * 384 + kk0 + bkseg;
            float4 v = *(const float4*)p;
            bT[(bkseg + 0) * G1_SB + brow] = v.x;
            bT[(bkseg + 1) * G1_SB + brow] = v.y;
            bT[(bkseg + 2) * G1_SB + brow] = v.z;
            bT[(bkseg + 3) * G1_SB + brow] = v.w;
        }
        __syncthreads();

        #pragma unroll
        for (int kk = 0; kk < 16; ++kk) {
            float4 a0 = *(const float4*)&aT[kk * G1_SA + r0];
            float4 a1 = *(const float4*)&aT[kk * G1_SA + r0 + 4];
            float4 bb = *(const float4*)&bT[kk * G1_SB + c0];
            float av[8] = {a0.x, a0.y, a0.z, a0.w, a1.x, a1.y, a1.z, a1.w};
            float bv[4] = {bb.x, bb.y, bb.z, bb.w};
            #pragma unroll
            for (int r = 0; r < 8; ++r)
                #pragma unroll
                for (int c = 0; c < 4; ++c) acc[r][c] += av[r] * bv[c];
        }
    }

    float bv[4];
    #pragma unroll
    for (int c = 0; c < 4; ++c) bv[c] = bias[col0 + c0 + c];
    #pragma unroll
    for (int r = 0; r < 8; ++r) {
        int row = row0 + r0 + r;
        if (row < M) {
            float4 o;
            float v0 = acc[r][0] + bv[0];
            float v1 = acc[r][1] + bv[1];
            float v2 = acc[r][2] + bv[2];
            float v3 = acc[r][3] + bv[3];
            o.x = (v0 > 0.f) ? v0 : 0.01f * v0;
            o.y = (v1 > 0.f) ? v1 : 0.01f * v1;
            o.z = (v2 > 0.f) ? v2 : 0.01f * v2;
            o.w = (v3 > 0.f) ? v3 : 0.01f * v3;
            *(float4*)&y1[(size_t)row * 256 + col0 + c0] = o;
        }
    }
}

// ---------------- global branch layer 2 ----------------
__global__ void global_gemm2(const float* __restrict__ y1, const float* __restrict__ W2,
                             const float* __restrict__ b2, float* __restrict__ xg, int B) {
    int wave = (blockIdx.x * blockDim.x + threadIdx.x) >> 6;
    int lane = threadIdx.x & 63;
    if (wave >= B) return;
    const float* yr = y1 + (size_t)wave * 256;
    float yv[4];
    #pragma unroll
    for (int j = 0; j < 4; ++j) yv[j] = yr[lane + 64 * j];
    float res[10];
    #pragma unroll
    for (int o = 0; o < 10; ++o) {
        const float* w = W2 + o * 256;
        float p = 0.f;
        #pragma unroll
        for (int j = 0; j < 4; ++j) p += yv[j] * w[lane + 64 * j];
        #pragma unroll
        for (int off = 32; off > 0; off >>= 1) p += __shfl_down(p, off, 64);
        res[o] = p;
    }
    if (lane == 0) {
        #pragma unroll
        for (int o = 0; o < 10; ++o) {
            float v = res[o] + b2[o];
            xg[wave * 10 + o] = (v > 0.f) ? v : 0.01f * v;
        }
    }
}

// ---------------- final MLP + softplus + normalize + |conc| reduction ----------------
// Spill-free rewrite: stream x as float4 chunks into y1 accumulators; weights
// via wave-uniform loads (scalar path, K$) — no divergent CF before loads.
#define MLP_NODES 252
__global__ __launch_bounds__(256, 3) void mlp_kernel(
                           const float* __restrict__ x, const float* __restrict__ xg,
                           const float* __restrict__ l1W, const float* __restrict__ l1b,
                           const float* __restrict__ l2W, const float* __restrict__ l2b,
                           const float* __restrict__ l3W, const float* __restrict__ l3b,
                           float* __restrict__ out, float* __restrict__ reg_out, int n) {
    __shared__ float s_conc[MLP_NODES];
    __shared__ float wsum[4];

    int local = threadIdx.x;
    int node = blockIdx.x * MLP_NODES + local;
    bool active = (local < MLP_NODES) && (node < n);
    int nodec = (node < n) ? node : (n - 1);     // clamp: keep CF uniform

    const float4* xrow = (const float4*)(x + (size_t)nodec * 64);
    int b = nodec / 6;

    // layer 1: y1 = leaky(l1W[:, :64] @ xrow + l1W[:, 64:] @ xg + l1b)
    float y1[32];
    #pragma unroll
    for (int hh = 0; hh < 32; ++hh) y1[hh] = l1b[hh];
    for (int kk = 0; kk < 16; ++kk) {
        float4 xv = xrow[kk];
        #pragma unroll
        for (int hh = 0; hh < 32; ++hh) {
            const float* w = l1W + hh * 74 + kk * 4;   // wave-uniform -> s_load
            y1[hh] += w[0] * xv.x + w[1] * xv.y + w[2] * xv.z + w[3] * xv.w;
        }
    }
    float xgv[10];
    #pragma unroll
    for (int j = 0; j < 10; ++j) xgv[j] = xg[b * 10 + j];
    #pragma unroll
    for (int hh = 0; hh < 32; ++hh) {
        const float* w = l1W + hh * 74 + 64;
        float a = y1[hh];
        #pragma unroll
        for (int j = 0; j < 10; ++j) a += w[j] * xgv[j];
        y1[hh] = (a > 0.f) ? a : 0.01f * a;
    }

    // layer 2
    float y2[32];
    for (int hh = 0; hh < 32; ++hh) {
        const float* w = l2W + hh * 32;
        float a = l2b[hh];
        #pragma unroll
        for (int k = 0; k < 32; ++k) a += w[k] * y1[k];
        y2[hh] = (a > 0.f) ? a : 0.01f * a;
    }

    // layer 3 + softplus
    float a3 = l3b[0];
    #pragma unroll
    for (int k = 0; k < 32; ++k) a3 += l3W[k] * y2[k];
    float conc = (a3 > 20.f) ? a3 : log1pf(expf(a3));
    if (!active) conc = 0.f;
    if (local < MLP_NODES) s_conc[local] = conc;

    // regularize: block reduction of |conc|
    float v = fabsf(conc);
    #pragma unroll
    for (int off = 32; off > 0; off >>= 1) v += __shfl_down(v, off, 64);
    if ((threadIdx.x & 63) == 0) wsum[threadIdx.x >> 6] = v;
    __syncthreads();
    if (threadIdx.x == 0) {
        float s = wsum[0] + wsum[1] + wsum[2] + wsum[3];
        atomicAdd(reg_out, s * (1.0f / (float)N_NODES));
    }

    // normalize within group of 6 (252 % 6 == 0: groups never straddle blocks)
    if (active) {
        int g0 = (local / 6) * 6;
        float s = 0.f;
        #pragma unroll
        for (int i = 0; i < 6; ++i) s += s_conc[g0 + i];
        out[node] = conc / (s + 1e-20f);
    }
}

extern "C" void kernel_launch(void* const* d_in, const int* in_sizes, int n_in,
                              void* d_out, int out_size, void* d_ws, size_t ws_size,
                              hipStream_t stream) {
    const float* state = (const float*)d_in[0];
    const int*   ei    = (const int*)d_in[1];
    const float* convW = (const float*)d_in[2];
    const float* convb = (const float*)d_in[3];
    const float* gW1   = (const float*)d_in[4];
    const float* gb1   = (const float*)d_in[5];
    const float* gW2   = (const float*)d_in[6];
    const float* gb2   = (const float*)d_in[7];
    const float* l1W   = (const float*)d_in[8];
    const float* l1b   = (const float*)d_in[9];
    const float* l2W   = (const float*)d_in[10];
    const float* l2b   = (const float*)d_in[11];
    const float* l3W   = (const float*)d_in[12];
    const float* l3b   = (const float*)d_in[13];

    const int n = N_NODES, E = N_EDGES, B = B_ROWS;
    const int* src = ei;
    const int* dst = ei + E;

    // ---- workspace layout ----
    char* w = (char*)d_ws;
    int*   counts = (int*)w;                 w += NPAD * 4;
    int*   cursor = (int*)w;                 w += NPAD * 4;
    int*   rowptr = (int*)w;                 w += NPAD * 4;
    int*   bsum   = (int*)w;                 w += 256 * 4;
    float* dinv   = (float*)w;               w += NPAD * 4;
    int*   csr    = (int*)w;                 w += (size_t)E * 4;
    float* h      = (float*)w;               w += (size_t)n * 64 * 4;
    float* x      = (float*)w;
    float* y1     = h;
    float* xg     = h + 6400000;

    float* out    = (float*)d_out;
    float* regptr = out + n;

    hipMemsetAsync(counts, 0, NPAD * 4, stream);
    hipMemsetAsync(cursor, 0, NPAD * 4, stream);
    hipMemsetAsync(regptr, 0, 4, stream);

    degree_kernel<<<(E + 255) / 256, 256, 0, stream>>>(dst, counts, E);
    scan_block<<<NSCAN, 256, 0, stream>>>(counts, rowptr, bsum, n);
    scan_sums<<<1, 256, 0, stream>>>(bsum, NSCAN);
    scan_add<<<(n + 256) / 256, 256, 0, stream>>>(rowptr, bsum, counts, dinv, n, E);
    fill_csr<<<(E + 255) / 256, 256, 0, stream>>>(src, dst, rowptr, cursor, csr, E);
    conv_gemm<<<1024, 256, 0, stream>>>(state, convW, h, n);
    gather_fused<<<(n + 3) / 4, 256, 0, stream>>>(rowptr, csr, h, dinv, convb, state, x, n);
    global_gemm1<<<196 * 4, 256, 0, stream>>>(state, gW1, gb1, y1, B);
    global_gemm2<<<(B * 64 + 255) / 256, 256, 0, stream>>>(y1, gW2, gb2, xg, B);
    mlp_kernel<<<(n + MLP_NODES - 1) / MLP_NODES, 256, 0, stream>>>(
        x, xg, l1W, l1b, l2W, l2b, l3W, l3b, out, regptr, n);
}

// Round 5
// 529.526 us; speedup vs baseline: 1.7875x; 1.0925x over previous
//
#include <hip/hip_runtime.h>
#include <math.h>

#define N_NODES 150000
#define N_EDGES 1200000
#define C 64
#define ACT 6
#define B_ROWS 25000   // N/ACT
#define GLOB 256
#define GOUT 10
#define H 32

#define NPAD 150016            // N rounded up (alignment)
#define SCAN_CHUNK 1024
#define NSCAN 147              // ceil(150000/1024)

// ---- bf16 helpers ----
__device__ __forceinline__ unsigned short f2bf(float f) {
    unsigned int u = __builtin_bit_cast(unsigned int, f);
    unsigned int r = (u + 0x7fffu + ((u >> 16) & 1u)) >> 16;   // RTNE
    return (unsigned short)r;
}
__device__ __forceinline__ float bflo(unsigned int u) {
    return __builtin_bit_cast(float, u << 16);
}
__device__ __forceinline__ float bfhi(unsigned int u) {
    return __builtin_bit_cast(float, u & 0xffff0000u);
}

// ---------------- degree histogram (int) ----------------
__global__ void degree_kernel(const int* __restrict__ dst, int* __restrict__ counts, int E) {
    int e = blockIdx.x * blockDim.x + threadIdx.x;
    if (e < E) atomicAdd(&counts[dst[e]], 1);
}

// ---------------- prefix scan (3 kernels) ----------------
__global__ void scan_block(const int* __restrict__ counts, int* __restrict__ rowptr,
                           int* __restrict__ bsum, int n) {
    __shared__ int lds[256];
    int base = blockIdx.x * SCAN_CHUNK;
    int t = threadIdx.x;
    int v[4]; int s = 0;
    #pragma unroll
    for (int i = 0; i < 4; ++i) {
        int idx = base + t * 4 + i;
        v[i] = (idx < n) ? counts[idx] : 0;
        s += v[i];
    }
    lds[t] = s; __syncthreads();
    for (int off = 1; off < 256; off <<= 1) {
        int x = (t >= off) ? lds[t - off] : 0;
        __syncthreads();
        lds[t] += x;
        __syncthreads();
    }
    int excl = lds[t] - s;
    if (t == 255) bsum[blockIdx.x] = lds[255];
    int run = excl;
    #pragma unroll
    for (int i = 0; i < 4; ++i) {
        int idx = base + t * 4 + i;
        if (idx < n) rowptr[idx] = run;
        run += v[i];
    }
}

__global__ void scan_sums(int* __restrict__ bsum, int nb) {
    __shared__ int lds[256];
    int t = threadIdx.x;
    int v = (t < nb) ? bsum[t] : 0;
    lds[t] = v; __syncthreads();
    for (int off = 1; off < 256; off <<= 1) {
        int x = (t >= off) ? lds[t - off] : 0;
        __syncthreads();
        lds[t] += x;
        __syncthreads();
    }
    if (t < nb) bsum[t] = lds[t] - v;   // exclusive
}

__global__ void scan_add(int* __restrict__ rowptr, const int* __restrict__ bsum,
                         const int* __restrict__ counts, float* __restrict__ dinv,
                         int n, int E) {
    int i = blockIdx.x * blockDim.x + threadIdx.x;
    if (i < n) {
        rowptr[i] += bsum[i >> 10];
        dinv[i] = rsqrtf((float)counts[i] + 1.0f);
    }
    if (i == n) rowptr[n] = E;
}

// ---------------- CSR fill ----------------
__global__ void fill_csr(const int* __restrict__ src, const int* __restrict__ dst,
                         const int* __restrict__ rowptr, int* __restrict__ cursor,
                         int* __restrict__ csr, int E) {
    int e = blockIdx.x * blockDim.x + threadIdx.x;
    if (e >= E) return;
    int d = dst[e];
    int pos = rowptr[d] + atomicAdd(&cursor[d], 1);
    csr[pos] = src[e];
}

// ---------------- hs = bf16( (state @ convW^T) * dinv[row] ) ----------------
__global__ void conv_gemm(const float* __restrict__ x, const float* __restrict__ W,
                          const float* __restrict__ dinv,
                          unsigned short* __restrict__ hb, int nrows) {
    __shared__ float Wt[64 * 65];     // transposed, padded
    __shared__ float sx[4][64];
    for (int idx = threadIdx.x; idx < 4096; idx += 256) {
        int j = idx >> 6, k = idx & 63;
        Wt[k * 65 + j] = W[idx];
    }
    __syncthreads();
    int r = threadIdx.x >> 6, c = threadIdx.x & 63;
    int ngroups = (nrows + 3) >> 2;
    for (int g = blockIdx.x; g < ngroups; g += gridDim.x) {
        int row = g * 4 + r;
        sx[r][c] = (row < nrows) ? x[row * 64 + c] : 0.f;
        __syncthreads();
        float acc = 0.f;
        #pragma unroll
        for (int k = 0; k < 64; ++k) acc += sx[r][k] * Wt[k * 65 + c];
        if (row < nrows) hb[(size_t)row * 64 + c] = f2bf(acc * dinv[row]);
        __syncthreads();
    }
}

// ---------------- gather (CSR, bf16 rows, 2 edges/iter) + self-loop + relu + residual ----------------
__global__ void gather_fused(const int* __restrict__ rowptr, const int* __restrict__ csr,
                             const unsigned short* __restrict__ hb, const float* __restrict__ dinv,
                             const float* __restrict__ convb, const float* __restrict__ state,
                             float* __restrict__ x, int n) {
    int node = blockIdx.x * 4 + (threadIdx.x >> 6);
    if (node >= n) return;
    int lane  = threadIdx.x & 63;
    int half  = lane >> 5;       // which edge parity this half-wave handles
    int hlane = lane & 31;       // channel-pair index (2 channels per lane)
    int beg = rowptr[node], end = rowptr[node + 1];
    float dd = dinv[node];
    float acc0 = 0.f, acc1 = 0.f;
    for (int e = beg + half; e < end; e += 2) {
        int s = csr[e];          // uniform within half-wave -> broadcast
        unsigned int u = *(const unsigned int*)(hb + (size_t)s * 64 + 2 * hlane);
        acc0 += bflo(u);
        acc1 += bfhi(u);
    }
    // combine the two half-waves
    acc0 += __shfl_down(acc0, 32, 64);
    acc1 += __shfl_down(acc1, 32, 64);
    if (half == 0) {
        unsigned int us = *(const unsigned int*)(hb + (size_t)node * 64 + 2 * hlane);
        float2 cb = *(const float2*)(convb + 2 * hlane);
        float2 st = *(const float2*)(state + (size_t)node * 64 + 2 * hlane);
        float v0 = dd * (acc0 + bflo(us)) + cb.x;
        float v1 = dd * (acc1 + bfhi(us)) + cb.y;
        v0 = (v0 > 0.f) ? v0 : 0.f;
        v1 = (v1 > 0.f) ? v1 : 0.f;
        float2 o = make_float2(v0 + st.x, v1 + st.y);
        *(float2*)(x + (size_t)node * 64 + 2 * hlane) = o;
    }
}

// ---------------- global branch layer 1: y1 = leaky(state[B,384] @ gW1^T + gb1), [B,256] ----------------
#define G1_SA 132   // aT row stride (128 + 4)
#define G1_SB 68    // bT row stride (64 + 4)
__global__ __launch_bounds__(256) void global_gemm1(
        const float* __restrict__ A,     // state as [25000][384]
        const float* __restrict__ Wg,    // gW1 [256][384]
        const float* __restrict__ bias,  // gb1 [256]
        float* __restrict__ y1, int M) {
    __shared__ float aT[16 * G1_SA];
    __shared__ float bT[16 * G1_SB];

    int t = threadIdx.x;
    int mb = blockIdx.x >> 2;
    int nb = blockIdx.x & 3;
    int row0 = mb * 128;
    int col0 = nb * 64;

    int arow = t >> 1;
    int akseg = (t & 1) * 8;
    int brow = t >> 2;
    int bkseg = (t & 3) * 4;

    int ty = t >> 4, tx = t & 15;
    int r0 = ty * 8, c0 = tx * 4;

    float acc[8][4];
    #pragma unroll
    for (int r = 0; r < 8; ++r)
        #pragma unroll
        for (int c = 0; c < 4; ++c) acc[r][c] = 0.f;

    const int arowg = row0 + arow;
    const bool avalid = arowg < M;

    for (int chunk = 0; chunk < 24; ++chunk) {
        int kk0 = chunk * 16;
        __syncthreads();
        {
            float4 v0 = make_float4(0.f, 0.f, 0.f, 0.f), v1 = v0;
            if (avalid) {
                const float* p = A + (size_t)arowg * 384 + kk0 + akseg;
                v0 = *(const float4*)p;
                v1 = *(const float4*)(p + 4);
            }
            aT[(akseg + 0) * G1_SA + arow] = v0.x;
            aT[(akseg + 1) * G1_SA + arow] = v0.y;
            aT[(akseg + 2) * G1_SA + arow] = v0.z;
            aT[(akseg + 3) * G1_SA + arow] = v0.w;
            aT[(akseg + 4) * G1_SA + arow] = v1.x;
            aT[(akseg + 5) * G1_SA + arow] = v1.y;
            aT[(akseg + 6) * G1_SA + arow] = v1.z;
            aT[(akseg + 7) * G1_SA + arow] = v1.w;
        }
        {
            const float* p = Wg + (size_t)(col0 + brow) * 384 + kk0 + bkseg;
            float4 v = *(const float4*)p;
            bT[(bkseg + 0) * G1_SB + brow] = v.x;
            bT[(bkseg + 1) * G1_SB + brow] = v.y;
            bT[(bkseg + 2) * G1_SB + brow] = v.z;
            bT[(bkseg + 3) * G1_SB + brow] = v.w;
        }
        __syncthreads();

        #pragma unroll
        for (int kk = 0; kk < 16; ++kk) {
            float4 a0 = *(const float4*)&aT[kk * G1_SA + r0];
            float4 a1 = *(const float4*)&aT[kk * G1_SA + r0 + 4];
            float4 bb = *(const float4*)&bT[kk * G1_SB + c0];
            float av[8] = {a0.x, a0.y, a0.z, a0.w, a1.x, a1.y, a1.z, a1.w};
            float bv[4] = {bb.x, bb.y, bb.z, bb.w};
            #pragma unroll
            for (int r = 0; r < 8; ++r)
                #pragma unroll
                for (int c = 0; c < 4; ++c) acc[r][c] += av[r] * bv[c];
        }
    }

    float bv[4];
    #pragma unroll
    for (int c = 0; c < 4; ++c) bv[c] = bias[col0 + c0 + c];
    #pragma unroll
    for (int r = 0; r < 8; ++r) {
        int row = row0 + r0 + r;
        if (row < M) {
            float4 o;
            float v0 = acc[r][0] + bv[0];
            float v1 = acc[r][1] + bv[1];
            float v2 = acc[r][2] + bv[2];
            float v3 = acc[r][3] + bv[3];
            o.x = (v0 > 0.f) ? v0 : 0.01f * v0;
            o.y = (v1 > 0.f) ? v1 : 0.01f * v1;
            o.z = (v2 > 0.f) ? v2 : 0.01f * v2;
            o.w = (v3 > 0.f) ? v3 : 0.01f * v3;
            *(float4*)&y1[(size_t)row * 256 + col0 + c0] = o;
        }
    }
}

// ---------------- global branch layer 2 ----------------
__global__ void global_gemm2(const float* __restrict__ y1, const float* __restrict__ W2,
                             const float* __restrict__ b2, float* __restrict__ xg, int B) {
    int wave = (blockIdx.x * blockDim.x + threadIdx.x) >> 6;
    int lane = threadIdx.x & 63;
    if (wave >= B) return;
    const float* yr = y1 + (size_t)wave * 256;
    float yv[4];
    #pragma unroll
    for (int j = 0; j < 4; ++j) yv[j] = yr[lane + 64 * j];
    float res[10];
    #pragma unroll
    for (int o = 0; o < 10; ++o) {
        const float* w = W2 + o * 256;
        float p = 0.f;
        #pragma unroll
        for (int j = 0; j < 4; ++j) p += yv[j] * w[lane + 64 * j];
        #pragma unroll
        for (int off = 32; off > 0; off >>= 1) p += __shfl_down(p, off, 64);
        res[o] = p;
    }
    if (lane == 0) {
        #pragma unroll
        for (int o = 0; o < 10; ++o) {
            float v = res[o] + b2[o];
            xg[wave * 10 + o] = (v > 0.f) ? v : 0.01f * v;
        }
    }
}

// ---------------- final MLP + softplus + normalize + |conc| reduction ----------------
#define MLP_NODES 252
__global__ __launch_bounds__(256, 3) void mlp_kernel(
                           const float* __restrict__ x, const float* __restrict__ xg,
                           const float* __restrict__ l1W, const float* __restrict__ l1b,
                           const float* __restrict__ l2W, const float* __restrict__ l2b,
                           const float* __restrict__ l3W, const float* __restrict__ l3b,
                           float* __restrict__ out, float* __restrict__ reg_out, int n) {
    __shared__ float s_conc[MLP_NODES];
    __shared__ float wsum[4];

    int local = threadIdx.x;
    int node = blockIdx.x * MLP_NODES + local;
    bool active = (local < MLP_NODES) && (node < n);
    int nodec = (node < n) ? node : (n - 1);     // clamp: keep CF uniform

    const float4* xrow = (const float4*)(x + (size_t)nodec * 64);
    int b = nodec / 6;

    float y1[32];
    #pragma unroll
    for (int hh = 0; hh < 32; ++hh) y1[hh] = l1b[hh];
    for (int kk = 0; kk < 16; ++kk) {
        float4 xv = xrow[kk];
        #pragma unroll
        for (int hh = 0; hh < 32; ++hh) {
            const float* w = l1W + hh * 74 + kk * 4;   // wave-uniform -> s_load
            y1[hh] += w[0] * xv.x + w[1] * xv.y + w[2] * xv.z + w[3] * xv.w;
        }
    }
    float xgv[10];
    #pragma unroll
    for (int j = 0; j < 10; ++j) xgv[j] = xg[b * 10 + j];
    #pragma unroll
    for (int hh = 0; hh < 32; ++hh) {
        const float* w = l1W + hh * 74 + 64;
        float a = y1[hh];
        #pragma unroll
        for (int j = 0; j < 10; ++j) a += w[j] * xgv[j];
        y1[hh] = (a > 0.f) ? a : 0.01f * a;
    }

    float y2[32];
    for (int hh = 0; hh < 32; ++hh) {
        const float* w = l2W + hh * 32;
        float a = l2b[hh];
        #pragma unroll
        for (int k = 0; k < 32; ++k) a += w[k] * y1[k];
        y2[hh] = (a > 0.f) ? a : 0.01f * a;
    }

    float a3 = l3b[0];
    #pragma unroll
    for (int k = 0; k < 32; ++k) a3 += l3W[k] * y2[k];
    float conc = (a3 > 20.f) ? a3 : log1pf(expf(a3));
    if (!active) conc = 0.f;
    if (local < MLP_NODES) s_conc[local] = conc;

    float v = fabsf(conc);
    #pragma unroll
    for (int off = 32; off > 0; off >>= 1) v += __shfl_down(v, off, 64);
    if ((threadIdx.x & 63) == 0) wsum[threadIdx.x >> 6] = v;
    __syncthreads();
    if (threadIdx.x == 0) {
        float s = wsum[0] + wsum[1] + wsum[2] + wsum[3];
        atomicAdd(reg_out, s * (1.0f / (float)N_NODES));
    }

    if (active) {
        int g0 = (local / 6) * 6;
        float s = 0.f;
        #pragma unroll
        for (int i = 0; i < 6; ++i) s += s_conc[g0 + i];
        out[node] = conc / (s + 1e-20f);
    }
}

extern "C" void kernel_launch(void* const* d_in, const int* in_sizes, int n_in,
                              void* d_out, int out_size, void* d_ws, size_t ws_size,
                              hipStream_t stream) {
    const float* state = (const float*)d_in[0];
    const int*   ei    = (const int*)d_in[1];
    const float* convW = (const float*)d_in[2];
    const float* convb = (const float*)d_in[3];
    const float* gW1   = (const float*)d_in[4];
    const float* gb1   = (const float*)d_in[5];
    const float* gW2   = (const float*)d_in[6];
    const float* gb2   = (const float*)d_in[7];
    const float* l1W   = (const float*)d_in[8];
    const float* l1b   = (const float*)d_in[9];
    const float* l2W   = (const float*)d_in[10];
    const float* l2b   = (const float*)d_in[11];
    const float* l3W   = (const float*)d_in[12];
    const float* l3b   = (const float*)d_in[13];

    const int n = N_NODES, E = N_EDGES, B = B_ROWS;
    const int* src = ei;
    const int* dst = ei + E;

    // ---- workspace layout ----
    char* w = (char*)d_ws;
    int*   counts = (int*)w;                 w += NPAD * 4;
    int*   cursor = (int*)w;                 w += NPAD * 4;
    int*   rowptr = (int*)w;                 w += NPAD * 4;
    int*   bsum   = (int*)w;                 w += 256 * 4;
    float* dinv   = (float*)w;               w += NPAD * 4;
    int*   csr    = (int*)w;                 w += (size_t)E * 4;
    float* hregion= (float*)w;               w += (size_t)n * 64 * 4;
    float* x      = (float*)w;
    unsigned short* hb = (unsigned short*)hregion;  // bf16 hs, 19.2 MB
    float* y1     = hregion;                 // reuse after gather (gemm1 runs later)
    float* xg     = hregion + 6400000;

    float* out    = (float*)d_out;
    float* regptr = out + n;

    hipMemsetAsync(counts, 0, NPAD * 4, stream);
    hipMemsetAsync(cursor, 0, NPAD * 4, stream);
    hipMemsetAsync(regptr, 0, 4, stream);

    degree_kernel<<<(E + 255) / 256, 256, 0, stream>>>(dst, counts, E);
    scan_block<<<NSCAN, 256, 0, stream>>>(counts, rowptr, bsum, n);
    scan_sums<<<1, 256, 0, stream>>>(bsum, NSCAN);
    scan_add<<<(n + 256) / 256, 256, 0, stream>>>(rowptr, bsum, counts, dinv, n, E);
    fill_csr<<<(E + 255) / 256, 256, 0, stream>>>(src, dst, rowptr, cursor, csr, E);
    conv_gemm<<<1024, 256, 0, stream>>>(state, convW, dinv, hb, n);
    gather_fused<<<(n + 3) / 4, 256, 0, stream>>>(rowptr, csr, hb, dinv, convb, state, x, n);
    global_gemm1<<<196 * 4, 256, 0, stream>>>(state, gW1, gb1, y1, B);
    global_gemm2<<<(B * 64 + 255) / 256, 256, 0, stream>>>(y1, gW2, gb2, xg, B);
    mlp_kernel<<<(n + MLP_NODES - 1) / MLP_NODES, 256, 0, stream>>>(
        x, xg, l1W, l1b, l2W, l2b, l3W, l3b, out, regptr, n);
}

// Round 6
// 513.671 us; speedup vs baseline: 1.8427x; 1.0309x over previous
//
#include <hip/hip_runtime.h>
#include <math.h>

#define N_NODES 150000
#define N_EDGES 1200000
#define C 64
#define ACT 6
#define B_ROWS 25000   // N/ACT
#define GLOB 256
#define GOUT 10
#define H 32

#define NPAD 150016            // N rounded up (alignment)
#define SCAN_CHUNK 1024
#define NSCAN 147              // ceil(150000/1024)

typedef short bf16x8 __attribute__((ext_vector_type(8)));
typedef float f32x4v __attribute__((ext_vector_type(4)));

// ---- bf16 helpers ----
__device__ __forceinline__ unsigned short f2bf(float f) {
    unsigned int u = __builtin_bit_cast(unsigned int, f);
    unsigned int r = (u + 0x7fffu + ((u >> 16) & 1u)) >> 16;   // RTNE
    return (unsigned short)r;
}
__device__ __forceinline__ float bflo(unsigned int u) {
    return __builtin_bit_cast(float, u << 16);
}
__device__ __forceinline__ float bfhi(unsigned int u) {
    return __builtin_bit_cast(float, u & 0xffff0000u);
}
__device__ __forceinline__ float bf1(unsigned short us) {
    return __builtin_bit_cast(float, ((unsigned int)us) << 16);
}

// ---------------- degree histogram (int) ----------------
__global__ void degree_kernel(const int* __restrict__ dst, int* __restrict__ counts, int E) {
    int e = blockIdx.x * blockDim.x + threadIdx.x;
    if (e < E) atomicAdd(&counts[dst[e]], 1);
}

// ---------------- prefix scan (3 kernels) ----------------
__global__ void scan_block(const int* __restrict__ counts, int* __restrict__ rowptr,
                           int* __restrict__ bsum, int n) {
    __shared__ int lds[256];
    int base = blockIdx.x * SCAN_CHUNK;
    int t = threadIdx.x;
    int v[4]; int s = 0;
    #pragma unroll
    for (int i = 0; i < 4; ++i) {
        int idx = base + t * 4 + i;
        v[i] = (idx < n) ? counts[idx] : 0;
        s += v[i];
    }
    lds[t] = s; __syncthreads();
    for (int off = 1; off < 256; off <<= 1) {
        int x = (t >= off) ? lds[t - off] : 0;
        __syncthreads();
        lds[t] += x;
        __syncthreads();
    }
    int excl = lds[t] - s;
    if (t == 255) bsum[blockIdx.x] = lds[255];
    int run = excl;
    #pragma unroll
    for (int i = 0; i < 4; ++i) {
        int idx = base + t * 4 + i;
        if (idx < n) rowptr[idx] = run;
        run += v[i];
    }
}

__global__ void scan_sums(int* __restrict__ bsum, int nb) {
    __shared__ int lds[256];
    int t = threadIdx.x;
    int v = (t < nb) ? bsum[t] : 0;
    lds[t] = v; __syncthreads();
    for (int off = 1; off < 256; off <<= 1) {
        int x = (t >= off) ? lds[t - off] : 0;
        __syncthreads();
        lds[t] += x;
        __syncthreads();
    }
    if (t < nb) bsum[t] = lds[t] - v;   // exclusive
}

__global__ void scan_add(int* __restrict__ rowptr, const int* __restrict__ bsum,
                         const int* __restrict__ counts, float* __restrict__ dinv,
                         int n, int E) {
    int i = blockIdx.x * blockDim.x + threadIdx.x;
    if (i < n) {
        rowptr[i] += bsum[i >> 10];
        dinv[i] = rsqrtf((float)counts[i] + 1.0f);
    }
    if (i == n) rowptr[n] = E;
}

// ---------------- CSR fill ----------------
__global__ void fill_csr(const int* __restrict__ src, const int* __restrict__ dst,
                         const int* __restrict__ rowptr, int* __restrict__ cursor,
                         int* __restrict__ csr, int E) {
    int e = blockIdx.x * blockDim.x + threadIdx.x;
    if (e >= E) return;
    int d = dst[e];
    int pos = rowptr[d] + atomicAdd(&cursor[d], 1);
    csr[pos] = src[e];
}

// ---------------- hs = bf16((state @ convW^T) * dinv) ; sb = bf16(state) ----------------
__global__ void conv_gemm(const float* __restrict__ x, const float* __restrict__ W,
                          const float* __restrict__ dinv,
                          unsigned short* __restrict__ hb,
                          unsigned short* __restrict__ sb, int nrows) {
    __shared__ float Wt[64 * 65];     // transposed, padded
    __shared__ float sx[4][64];
    for (int idx = threadIdx.x; idx < 4096; idx += 256) {
        int j = idx >> 6, k = idx & 63;
        Wt[k * 65 + j] = W[idx];
    }
    __syncthreads();
    int r = threadIdx.x >> 6, c = threadIdx.x & 63;
    int ngroups = (nrows + 3) >> 2;
    for (int g = blockIdx.x; g < ngroups; g += gridDim.x) {
        int row = g * 4 + r;
        float xv = (row < nrows) ? x[row * 64 + c] : 0.f;
        sx[r][c] = xv;
        __syncthreads();
        float acc = 0.f;
        #pragma unroll
        for (int k = 0; k < 64; ++k) acc += sx[r][k] * Wt[k * 65 + c];
        if (row < nrows) {
            hb[(size_t)row * 64 + c] = f2bf(acc * dinv[row]);
            sb[(size_t)row * 64 + c] = f2bf(xv);
        }
        __syncthreads();
    }
}

// ---------------- gather (CSR, bf16 rows, 2 edges/iter) + self-loop + relu + residual ----------------
__global__ void gather_fused(const int* __restrict__ rowptr, const int* __restrict__ csr,
                             const unsigned short* __restrict__ hb, const float* __restrict__ dinv,
                             const float* __restrict__ convb, const float* __restrict__ state,
                             float* __restrict__ x, int n) {
    int node = blockIdx.x * 4 + (threadIdx.x >> 6);
    if (node >= n) return;
    int lane  = threadIdx.x & 63;
    int half  = lane >> 5;
    int hlane = lane & 31;
    int beg = rowptr[node], end = rowptr[node + 1];
    float dd = dinv[node];
    float acc0 = 0.f, acc1 = 0.f;
    for (int e = beg + half; e < end; e += 2) {
        int s = csr[e];
        unsigned int u = *(const unsigned int*)(hb + (size_t)s * 64 + 2 * hlane);
        acc0 += bflo(u);
        acc1 += bfhi(u);
    }
    acc0 += __shfl_down(acc0, 32, 64);
    acc1 += __shfl_down(acc1, 32, 64);
    if (half == 0) {
        unsigned int us = *(const unsigned int*)(hb + (size_t)node * 64 + 2 * hlane);
        float2 cb = *(const float2*)(convb + 2 * hlane);
        float2 st = *(const float2*)(state + (size_t)node * 64 + 2 * hlane);
        float v0 = dd * (acc0 + bflo(us)) + cb.x;
        float v1 = dd * (acc1 + bfhi(us)) + cb.y;
        v0 = (v0 > 0.f) ? v0 : 0.f;
        v1 = (v1 > 0.f) ? v1 : 0.f;
        float2 o = make_float2(v0 + st.x, v1 + st.y);
        *(float2*)(x + (size_t)node * 64 + 2 * hlane) = o;
    }
}

// ---------------- cast gW1 -> bf16 ----------------
__global__ void cast_w1(const float* __restrict__ W, unsigned short* __restrict__ Wb, int total) {
    int i = blockIdx.x * blockDim.x + threadIdx.x;
    if (i < total) Wb[i] = f2bf(W[i]);
}

// ---------------- global branch layer 1 (MFMA bf16, LDS-free): y1b = bf16(leaky(A@W1^T+b1)) ----------------
// wave = 16 rows x 128 cols (8 tiles of 16x16), K=384 in 12 steps of 32.
// A frag: A[m=lane&15][k=quad*8+j]; B frag: W[n=lane&15][k=quad*8+j]; D: n=lane&15, m=quad*4+r.
__global__ __launch_bounds__(256) void global_gemm1_mfma(
        const unsigned short* __restrict__ Ab,   // [25000][384] bf16
        const unsigned short* __restrict__ Wb,   // [256][384] bf16
        const float* __restrict__ bias,          // gb1
        unsigned short* __restrict__ y1b, int M) {
    int wave = threadIdx.x >> 6;
    int lane = threadIdx.x & 63;
    int quad = lane >> 4;
    int lm   = lane & 15;
    int mtile = blockIdx.x >> 1;
    int nhalf = blockIdx.x & 1;
    int row0 = mtile * 64 + wave * 16;
    int col0 = nhalf * 128;

    int arow = row0 + lm;
    if (arow >= M) arow = M - 1;             // clamp; stores predicated
    const unsigned short* ap = Ab + (size_t)arow * 384 + quad * 8;
    const unsigned short* bp = Wb + (size_t)(col0 + lm) * 384 + quad * 8;

    f32x4v acc[8];
    #pragma unroll
    for (int t = 0; t < 8; ++t) acc[t] = (f32x4v){0.f, 0.f, 0.f, 0.f};

    #pragma unroll
    for (int ks = 0; ks < 12; ++ks) {
        bf16x8 af = *(const bf16x8*)(ap + ks * 32);
        #pragma unroll
        for (int t = 0; t < 8; ++t) {
            bf16x8 bfr = *(const bf16x8*)(bp + (size_t)t * 16 * 384 + ks * 32);
            acc[t] = __builtin_amdgcn_mfma_f32_16x16x32_bf16(af, bfr, acc[t], 0, 0, 0);
        }
    }

    #pragma unroll
    for (int t = 0; t < 8; ++t) {
        int n = col0 + t * 16 + lm;
        float bv = bias[n];
        #pragma unroll
        for (int r = 0; r < 4; ++r) {
            int m = row0 + quad * 4 + r;
            if (m < M) {
                float v = acc[t][r] + bv;
                v = (v > 0.f) ? v : 0.01f * v;
                y1b[(size_t)m * 256 + n] = f2bf(v);
            }
        }
    }
}

// ---------------- global branch layer 2 (bf16 y1) ----------------
__global__ void global_gemm2(const unsigned short* __restrict__ y1b, const float* __restrict__ W2,
                             const float* __restrict__ b2, float* __restrict__ xg, int B) {
    int wave = (blockIdx.x * blockDim.x + threadIdx.x) >> 6;
    int lane = threadIdx.x & 63;
    if (wave >= B) return;
    const unsigned short* yr = y1b + (size_t)wave * 256;
    float yv[4];
    #pragma unroll
    for (int j = 0; j < 4; ++j) yv[j] = bf1(yr[lane + 64 * j]);
    float res[10];
    #pragma unroll
    for (int o = 0; o < 10; ++o) {
        const float* w = W2 + o * 256;
        float p = 0.f;
        #pragma unroll
        for (int j = 0; j < 4; ++j) p += yv[j] * w[lane + 64 * j];
        #pragma unroll
        for (int off = 32; off > 0; off >>= 1) p += __shfl_down(p, off, 64);
        res[o] = p;
    }
    if (lane == 0) {
        #pragma unroll
        for (int o = 0; o < 10; ++o) {
            float v = res[o] + b2[o];
            xg[wave * 10 + o] = (v > 0.f) ? v : 0.01f * v;
        }
    }
}

// ---------------- final MLP + softplus + normalize + |conc| reduction ----------------
#define MLP_NODES 252
__global__ __launch_bounds__(256, 3) void mlp_kernel(
                           const float* __restrict__ x, const float* __restrict__ xg,
                           const float* __restrict__ l1W, const float* __restrict__ l1b,
                           const float* __restrict__ l2W, const float* __restrict__ l2b,
                           const float* __restrict__ l3W, const float* __restrict__ l3b,
                           float* __restrict__ out, float* __restrict__ reg_out, int n) {
    __shared__ float s_conc[MLP_NODES];
    __shared__ float wsum[4];

    int local = threadIdx.x;
    int node = blockIdx.x * MLP_NODES + local;
    bool active = (local < MLP_NODES) && (node < n);
    int nodec = (node < n) ? node : (n - 1);     // clamp: keep CF uniform

    const float4* xrow = (const float4*)(x + (size_t)nodec * 64);
    int b = nodec / 6;

    float y1[32];
    #pragma unroll
    for (int hh = 0; hh < 32; ++hh) y1[hh] = l1b[hh];
    for (int kk = 0; kk < 16; ++kk) {
        float4 xv = xrow[kk];
        #pragma unroll
        for (int hh = 0; hh < 32; ++hh) {
            const float* w = l1W + hh * 74 + kk * 4;   // wave-uniform -> s_load
            y1[hh] += w[0] * xv.x + w[1] * xv.y + w[2] * xv.z + w[3] * xv.w;
        }
    }
    float xgv[10];
    #pragma unroll
    for (int j = 0; j < 10; ++j) xgv[j] = xg[b * 10 + j];
    #pragma unroll
    for (int hh = 0; hh < 32; ++hh) {
        const float* w = l1W + hh * 74 + 64;
        float a = y1[hh];
        #pragma unroll
        for (int j = 0; j < 10; ++j) a += w[j] * xgv[j];
        y1[hh] = (a > 0.f) ? a : 0.01f * a;
    }

    float y2[32];
    for (int hh = 0; hh < 32; ++hh) {
        const float* w = l2W + hh * 32;
        float a = l2b[hh];
        #pragma unroll
        for (int k = 0; k < 32; ++k) a += w[k] * y1[k];
        y2[hh] = (a > 0.f) ? a : 0.01f * a;
    }

    float a3 = l3b[0];
    #pragma unroll
    for (int k = 0; k < 32; ++k) a3 += l3W[k] * y2[k];
    float conc = (a3 > 20.f) ? a3 : log1pf(expf(a3));
    if (!active) conc = 0.f;
    if (local < MLP_NODES) s_conc[local] = conc;

    float v = fabsf(conc);
    #pragma unroll
    for (int off = 32; off > 0; off >>= 1) v += __shfl_down(v, off, 64);
    if ((threadIdx.x & 63) == 0) wsum[threadIdx.x >> 6] = v;
    __syncthreads();
    if (threadIdx.x == 0) {
        float s = wsum[0] + wsum[1] + wsum[2] + wsum[3];
        atomicAdd(reg_out, s * (1.0f / (float)N_NODES));
    }

    if (active) {
        int g0 = (local / 6) * 6;
        float s = 0.f;
        #pragma unroll
        for (int i = 0; i < 6; ++i) s += s_conc[g0 + i];
        out[node] = conc / (s + 1e-20f);
    }
}

extern "C" void kernel_launch(void* const* d_in, const int* in_sizes, int n_in,
                              void* d_out, int out_size, void* d_ws, size_t ws_size,
                              hipStream_t stream) {
    const float* state = (const float*)d_in[0];
    const int*   ei    = (const int*)d_in[1];
    const float* convW = (const float*)d_in[2];
    const float* convb = (const float*)d_in[3];
    const float* gW1   = (const float*)d_in[4];
    const float* gb1   = (const float*)d_in[5];
    const float* gW2   = (const float*)d_in[6];
    const float* gb2   = (const float*)d_in[7];
    const float* l1W   = (const float*)d_in[8];
    const float* l1b   = (const float*)d_in[9];
    const float* l2W   = (const float*)d_in[10];
    const float* l2b   = (const float*)d_in[11];
    const float* l3W   = (const float*)d_in[12];
    const float* l3b   = (const float*)d_in[13];

    const int n = N_NODES, E = N_EDGES, B = B_ROWS;
    const int* src = ei;
    const int* dst = ei + E;

    // ---- workspace layout ----
    char* w = (char*)d_ws;
    int*   counts = (int*)w;                 w += NPAD * 4;
    int*   cursor = (int*)w;                 w += NPAD * 4;
    int*   rowptr = (int*)w;                 w += NPAD * 4;
    int*   bsum   = (int*)w;                 w += 256 * 4;
    float* dinv   = (float*)w;               w += NPAD * 4;
    int*   csr    = (int*)w;                 w += (size_t)E * 4;
    float* hregion= (float*)w;               w += (size_t)n * 64 * 4;   // 38.4 MB
    float* x      = (float*)w;               w += (size_t)n * 64 * 4;   // 38.4 MB
    unsigned short* w1b = (unsigned short*)w; /* 196 KB */
    // hregion sublayout (phases):
    //   phase 1 (conv/gather):  hb  = hregion[0 .. 19.2MB)   bf16 h*dinv
    //                           sb  = hregion[19.2 .. 38.4MB) bf16 state
    //   phase 2 (gemm1/gemm2):  y1b = hregion[0 .. 12.8MB)    bf16 y1 (hb dead)
    //                           xg  = hregion[12.8 .. 13.8MB) fp32   (sb still live for gemm1)
    unsigned short* hb  = (unsigned short*)hregion;
    unsigned short* sb  = (unsigned short*)(hregion + 4800000);
    unsigned short* y1b = (unsigned short*)hregion;
    float*          xg  = hregion + 3200000;

    float* out    = (float*)d_out;
    float* regptr = out + n;

    hipMemsetAsync(counts, 0, NPAD * 4, stream);
    hipMemsetAsync(cursor, 0, NPAD * 4, stream);
    hipMemsetAsync(regptr, 0, 4, stream);

    degree_kernel<<<(E + 255) / 256, 256, 0, stream>>>(dst, counts, E);
    scan_block<<<NSCAN, 256, 0, stream>>>(counts, rowptr, bsum, n);
    scan_sums<<<1, 256, 0, stream>>>(bsum, NSCAN);
    scan_add<<<(n + 256) / 256, 256, 0, stream>>>(rowptr, bsum, counts, dinv, n, E);
    fill_csr<<<(E + 255) / 256, 256, 0, stream>>>(src, dst, rowptr, cursor, csr, E);
    cast_w1<<<(GLOB * 384 + 1023) / 1024, 1024, 0, stream>>>(gW1, w1b, GLOB * 384);
    conv_gemm<<<1024, 256, 0, stream>>>(state, convW, dinv, hb, sb, n);
    gather_fused<<<(n + 3) / 4, 256, 0, stream>>>(rowptr, csr, hb, dinv, convb, state, x, n);
    global_gemm1_mfma<<<391 * 2, 256, 0, stream>>>(sb, w1b, gb1, y1b, B);
    global_gemm2<<<(B * 64 + 255) / 256, 256, 0, stream>>>(y1b, gW2, gb2, xg, B);
    mlp_kernel<<<(n + MLP_NODES - 1) / MLP_NODES, 256, 0, stream>>>(
        x, xg, l1W, l1b, l2W, l2b, l3W, l3b, out, regptr, n);
}

// Round 7
// 493.543 us; speedup vs baseline: 1.9179x; 1.0408x over previous
//
#include <hip/hip_runtime.h>
#include <math.h>

#define N_NODES 150000
#define N_EDGES 1200000
#define C 64
#define ACT 6
#define B_ROWS 25000   // N/ACT
#define GLOB 256
#define GOUT 10
#define H 32

#define NPAD 150016            // N rounded up (alignment)
#define SCAN_CHUNK 1024
#define NSCAN 147              // ceil(150000/1024)

typedef short bf16x8 __attribute__((ext_vector_type(8)));
typedef float f32x4v __attribute__((ext_vector_type(4)));

// ---- bf16 helpers ----
__device__ __forceinline__ unsigned short f2bf(float f) {
    unsigned int u = __builtin_bit_cast(unsigned int, f);
    unsigned int r = (u + 0x7fffu + ((u >> 16) & 1u)) >> 16;   // RTNE
    return (unsigned short)r;
}
__device__ __forceinline__ float bflo(unsigned int u) {
    return __builtin_bit_cast(float, u << 16);
}
__device__ __forceinline__ float bfhi(unsigned int u) {
    return __builtin_bit_cast(float, u & 0xffff0000u);
}
__device__ __forceinline__ float bf1(unsigned short us) {
    return __builtin_bit_cast(float, ((unsigned int)us) << 16);
}

// ---------------- degree histogram (int) ----------------
__global__ void degree_kernel(const int* __restrict__ dst, int* __restrict__ counts, int E) {
    int e = blockIdx.x * blockDim.x + threadIdx.x;
    if (e < E) atomicAdd(&counts[dst[e]], 1);
}

// ---------------- prefix scan (3 kernels) ----------------
__global__ void scan_block(const int* __restrict__ counts, int* __restrict__ rowptr,
                           int* __restrict__ bsum, int n) {
    __shared__ int lds[256];
    int base = blockIdx.x * SCAN_CHUNK;
    int t = threadIdx.x;
    int v[4]; int s = 0;
    #pragma unroll
    for (int i = 0; i < 4; ++i) {
        int idx = base + t * 4 + i;
        v[i] = (idx < n) ? counts[idx] : 0;
        s += v[i];
    }
    lds[t] = s; __syncthreads();
    for (int off = 1; off < 256; off <<= 1) {
        int x = (t >= off) ? lds[t - off] : 0;
        __syncthreads();
        lds[t] += x;
        __syncthreads();
    }
    int excl = lds[t] - s;
    if (t == 255) bsum[blockIdx.x] = lds[255];
    int run = excl;
    #pragma unroll
    for (int i = 0; i < 4; ++i) {
        int idx = base + t * 4 + i;
        if (idx < n) rowptr[idx] = run;
        run += v[i];
    }
}

__global__ void scan_sums(int* __restrict__ bsum, int nb) {
    __shared__ int lds[256];
    int t = threadIdx.x;
    int v = (t < nb) ? bsum[t] : 0;
    lds[t] = v; __syncthreads();
    for (int off = 1; off < 256; off <<= 1) {
        int x = (t >= off) ? lds[t - off] : 0;
        __syncthreads();
        lds[t] += x;
        __syncthreads();
    }
    if (t < nb) bsum[t] = lds[t] - v;   // exclusive
}

__global__ void scan_add(int* __restrict__ rowptr, const int* __restrict__ bsum,
                         const int* __restrict__ counts, float* __restrict__ dinv,
                         int n, int E) {
    int i = blockIdx.x * blockDim.x + threadIdx.x;
    if (i < n) {
        rowptr[i] += bsum[i >> 10];
        dinv[i] = rsqrtf((float)counts[i] + 1.0f);
    }
    if (i == n) rowptr[n] = E;
}

// ---------------- CSR fill ----------------
__global__ void fill_csr(const int* __restrict__ src, const int* __restrict__ dst,
                         const int* __restrict__ rowptr, int* __restrict__ cursor,
                         int* __restrict__ csr, int E) {
    int e = blockIdx.x * blockDim.x + threadIdx.x;
    if (e >= E) return;
    int d = dst[e];
    int pos = rowptr[d] + atomicAdd(&cursor[d], 1);
    csr[pos] = src[e];
}

// ---------------- hs = bf16((state @ convW^T) * dinv) ; sb = bf16(state) ----------------
__global__ void conv_gemm(const float* __restrict__ x, const float* __restrict__ W,
                          const float* __restrict__ dinv,
                          unsigned short* __restrict__ hb,
                          unsigned short* __restrict__ sb, int nrows) {
    __shared__ float Wt[64 * 65];     // transposed, padded
    __shared__ float sx[4][64];
    for (int idx = threadIdx.x; idx < 4096; idx += 256) {
        int j = idx >> 6, k = idx & 63;
        Wt[k * 65 + j] = W[idx];
    }
    __syncthreads();
    int r = threadIdx.x >> 6, c = threadIdx.x & 63;
    int ngroups = (nrows + 3) >> 2;
    for (int g = blockIdx.x; g < ngroups; g += gridDim.x) {
        int row = g * 4 + r;
        float xv = (row < nrows) ? x[row * 64 + c] : 0.f;
        sx[r][c] = xv;
        __syncthreads();
        float acc = 0.f;
        #pragma unroll
        for (int k = 0; k < 64; ++k) acc += sx[r][k] * Wt[k * 65 + c];
        if (row < nrows) {
            hb[(size_t)row * 64 + c] = f2bf(acc * dinv[row]);
            sb[(size_t)row * 64 + c] = f2bf(xv);
        }
        __syncthreads();
    }
}

// ---------------- gather (CSR, bf16 rows): 8 edge-groups x 8 lanes, 8 rows in flight ----------------
__global__ void gather_fused(const int* __restrict__ rowptr, const int* __restrict__ csr,
                             const unsigned short* __restrict__ hb, const float* __restrict__ dinv,
                             const float* __restrict__ convb, const float* __restrict__ state,
                             float* __restrict__ x, int n) {
    int node = blockIdx.x * 4 + (threadIdx.x >> 6);
    if (node >= n) return;
    int lane = threadIdx.x & 63;
    int g = lane >> 3;        // edge group 0..7
    int l = lane & 7;         // channel octet (8 bf16 per lane)
    int beg = rowptr[node], end = rowptr[node + 1];
    float acc[8] = {0.f, 0.f, 0.f, 0.f, 0.f, 0.f, 0.f, 0.f};
    for (int e = beg + g; e < end; e += 8) {
        int s = csr[e];
        uint4 u = *(const uint4*)(hb + (size_t)s * 64 + l * 8);
        acc[0] += bflo(u.x); acc[1] += bfhi(u.x);
        acc[2] += bflo(u.y); acc[3] += bfhi(u.y);
        acc[4] += bflo(u.z); acc[5] += bfhi(u.z);
        acc[6] += bflo(u.w); acc[7] += bfhi(u.w);
    }
    // butterfly across the 8 groups: all lanes end with channel sums for octet l
    #pragma unroll
    for (int st = 8; st < 64; st <<= 1) {
        #pragma unroll
        for (int j = 0; j < 8; ++j) acc[j] += __shfl_xor(acc[j], st, 64);
    }
    if (g == 0) {
        float dd = dinv[node];
        uint4 us = *(const uint4*)(hb + (size_t)node * 64 + l * 8);
        float sf[8] = {bflo(us.x), bfhi(us.x), bflo(us.y), bfhi(us.y),
                       bflo(us.z), bfhi(us.z), bflo(us.w), bfhi(us.w)};
        float4 c0 = *(const float4*)(convb + l * 8);
        float4 c1 = *(const float4*)(convb + l * 8 + 4);
        float4 s0 = *(const float4*)(state + (size_t)node * 64 + l * 8);
        float4 s1 = *(const float4*)(state + (size_t)node * 64 + l * 8 + 4);
        float cb[8] = {c0.x, c0.y, c0.z, c0.w, c1.x, c1.y, c1.z, c1.w};
        float sv[8] = {s0.x, s0.y, s0.z, s0.w, s1.x, s1.y, s1.z, s1.w};
        float o[8];
        #pragma unroll
        for (int j = 0; j < 8; ++j) {
            float v = dd * (acc[j] + sf[j]) + cb[j];
            v = (v > 0.f) ? v : 0.f;
            o[j] = v + sv[j];
        }
        float* xp = x + (size_t)node * 64 + l * 8;
        *(float4*)xp       = make_float4(o[0], o[1], o[2], o[3]);
        *(float4*)(xp + 4) = make_float4(o[4], o[5], o[6], o[7]);
    }
}

// ---------------- cast gW1 -> bf16 ----------------
__global__ void cast_w1(const float* __restrict__ W, unsigned short* __restrict__ Wb, int total) {
    int i = blockIdx.x * blockDim.x + threadIdx.x;
    if (i < total) Wb[i] = f2bf(W[i]);
}

// ---------------- global branch layer 1 (MFMA bf16, LDS-free) ----------------
__global__ __launch_bounds__(256) void global_gemm1_mfma(
        const unsigned short* __restrict__ Ab,   // [25000][384] bf16
        const unsigned short* __restrict__ Wb,   // [256][384] bf16
        const float* __restrict__ bias,          // gb1
        unsigned short* __restrict__ y1b, int M) {
    int wave = threadIdx.x >> 6;
    int lane = threadIdx.x & 63;
    int quad = lane >> 4;
    int lm   = lane & 15;
    int mtile = blockIdx.x >> 1;
    int nhalf = blockIdx.x & 1;
    int row0 = mtile * 64 + wave * 16;
    int col0 = nhalf * 128;

    int arow = row0 + lm;
    if (arow >= M) arow = M - 1;             // clamp; stores predicated
    const unsigned short* ap = Ab + (size_t)arow * 384 + quad * 8;
    const unsigned short* bp = Wb + (size_t)(col0 + lm) * 384 + quad * 8;

    f32x4v acc[8];
    #pragma unroll
    for (int t = 0; t < 8; ++t) acc[t] = (f32x4v){0.f, 0.f, 0.f, 0.f};

    #pragma unroll
    for (int ks = 0; ks < 12; ++ks) {
        bf16x8 af = *(const bf16x8*)(ap + ks * 32);
        #pragma unroll
        for (int t = 0; t < 8; ++t) {
            bf16x8 bfr = *(const bf16x8*)(bp + (size_t)t * 16 * 384 + ks * 32);
            acc[t] = __builtin_amdgcn_mfma_f32_16x16x32_bf16(af, bfr, acc[t], 0, 0, 0);
        }
    }

    #pragma unroll
    for (int t = 0; t < 8; ++t) {
        int nn = col0 + t * 16 + lm;
        float bv = bias[nn];
        #pragma unroll
        for (int r = 0; r < 4; ++r) {
            int m = row0 + quad * 4 + r;
            if (m < M) {
                float v = acc[t][r] + bv;
                v = (v > 0.f) ? v : 0.01f * v;
                y1b[(size_t)m * 256 + nn] = f2bf(v);
            }
        }
    }
}

// ---------------- global branch layer 2 (bf16 y1) ----------------
__global__ void global_gemm2(const unsigned short* __restrict__ y1b, const float* __restrict__ W2,
                             const float* __restrict__ b2, float* __restrict__ xg, int B) {
    int wave = (blockIdx.x * blockDim.x + threadIdx.x) >> 6;
    int lane = threadIdx.x & 63;
    if (wave >= B) return;
    const unsigned short* yr = y1b + (size_t)wave * 256;
    float yv[4];
    #pragma unroll
    for (int j = 0; j < 4; ++j) yv[j] = bf1(yr[lane + 64 * j]);
    float res[10];
    #pragma unroll
    for (int o = 0; o < 10; ++o) {
        const float* w = W2 + o * 256;
        float p = 0.f;
        #pragma unroll
        for (int j = 0; j < 4; ++j) p += yv[j] * w[lane + 64 * j];
        #pragma unroll
        for (int off = 32; off > 0; off >>= 1) p += __shfl_down(p, off, 64);
        res[o] = p;
    }
    if (lane == 0) {
        #pragma unroll
        for (int o = 0; o < 10; ++o) {
            float v = res[o] + b2[o];
            xg[wave * 10 + o] = (v > 0.f) ? v : 0.01f * v;
        }
    }
}

// ---------------- final MLP + softplus + normalize + |conc| reduction ----------------
#define MLP_NODES 252
__global__ __launch_bounds__(256, 3) void mlp_kernel(
                           const float* __restrict__ x, const float* __restrict__ xg,
                           const float* __restrict__ l1W, const float* __restrict__ l1b,
                           const float* __restrict__ l2W, const float* __restrict__ l2b,
                           const float* __restrict__ l3W, const float* __restrict__ l3b,
                           float* __restrict__ out, float* __restrict__ reg_out, int n) {
    __shared__ float s_conc[MLP_NODES];
    __shared__ float wsum[4];

    int local = threadIdx.x;
    int node = blockIdx.x * MLP_NODES + local;
    bool active = (local < MLP_NODES) && (node < n);
    int nodec = (node < n) ? node : (n - 1);     // clamp: keep CF uniform

    const float4* xrow = (const float4*)(x + (size_t)nodec * 64);
    int b = nodec / 6;

    float y1[32];
    #pragma unroll
    for (int hh = 0; hh < 32; ++hh) y1[hh] = l1b[hh];
    for (int kk = 0; kk < 16; ++kk) {
        float4 xv = xrow[kk];
        #pragma unroll
        for (int hh = 0; hh < 32; ++hh) {
            const float* w = l1W + hh * 74 + kk * 4;   // wave-uniform -> s_load
            y1[hh] += w[0] * xv.x + w[1] * xv.y + w[2] * xv.z + w[3] * xv.w;
        }
    }
    float xgv[10];
    #pragma unroll
    for (int j = 0; j < 10; ++j) xgv[j] = xg[b * 10 + j];
    #pragma unroll
    for (int hh = 0; hh < 32; ++hh) {
        const float* w = l1W + hh * 74 + 64;
        float a = y1[hh];
        #pragma unroll
        for (int j = 0; j < 10; ++j) a += w[j] * xgv[j];
        y1[hh] = (a > 0.f) ? a : 0.01f * a;
    }

    float y2[32];
    for (int hh = 0; hh < 32; ++hh) {
        const float* w = l2W + hh * 32;
        float a = l2b[hh];
        #pragma unroll
        for (int k = 0; k < 32; ++k) a += w[k] * y1[k];
        y2[hh] = (a > 0.f) ? a : 0.01f * a;
    }

    float a3 = l3b[0];
    #pragma unroll
    for (int k = 0; k < 32; ++k) a3 += l3W[k] * y2[k];
    float conc = (a3 > 20.f) ? a3 : log1pf(expf(a3));
    if (!active) conc = 0.f;
    if (local < MLP_NODES) s_conc[local] = conc;

    float v = fabsf(conc);
    #pragma unroll
    for (int off = 32; off > 0; off >>= 1) v += __shfl_down(v, off, 64);
    if ((threadIdx.x & 63) == 0) wsum[threadIdx.x >> 6] = v;
    __syncthreads();
    if (threadIdx.x == 0) {
        float s = wsum[0] + wsum[1] + wsum[2] + wsum[3];
        atomicAdd(reg_out, s * (1.0f / (float)N_NODES));
    }

    if (active) {
        int g0 = (local / 6) * 6;
        float s = 0.f;
        #pragma unroll
        for (int i = 0; i < 6; ++i) s += s_conc[g0 + i];
        out[node] = conc / (s + 1e-20f);
    }
}

extern "C" void kernel_launch(void* const* d_in, const int* in_sizes, int n_in,
                              void* d_out, int out_size, void* d_ws, size_t ws_size,
                              hipStream_t stream) {
    const float* state = (const float*)d_in[0];
    const int*   ei    = (const int*)d_in[1];
    const float* convW = (const float*)d_in[2];
    const float* convb = (const float*)d_in[3];
    const float* gW1   = (const float*)d_in[4];
    const float* gb1   = (const float*)d_in[5];
    const float* gW2   = (const float*)d_in[6];
    const float* gb2   = (const float*)d_in[7];
    const float* l1W   = (const float*)d_in[8];
    const float* l1b   = (const float*)d_in[9];
    const float* l2W   = (const float*)d_in[10];
    const float* l2b   = (const float*)d_in[11];
    const float* l3W   = (const float*)d_in[12];
    const float* l3b   = (const float*)d_in[13];

    const int n = N_NODES, E = N_EDGES, B = B_ROWS;
    const int* src = ei;
    const int* dst = ei + E;

    // ---- workspace layout ----
    char* w = (char*)d_ws;
    int*   counts = (int*)w;                 w += NPAD * 4;
    int*   cursor = (int*)w;                 w += NPAD * 4;
    int*   rowptr = (int*)w;                 w += NPAD * 4;
    int*   bsum   = (int*)w;                 w += 256 * 4;
    float* dinv   = (float*)w;               w += NPAD * 4;
    int*   csr    = (int*)w;                 w += (size_t)E * 4;
    float* hregion= (float*)w;               w += (size_t)n * 64 * 4;   // 38.4 MB
    float* x      = (float*)w;               w += (size_t)n * 64 * 4;   // 38.4 MB
    unsigned short* w1b = (unsigned short*)w; /* 196 KB */
    unsigned short* hb  = (unsigned short*)hregion;
    unsigned short* sb  = (unsigned short*)(hregion + 4800000);
    unsigned short* y1b = (unsigned short*)hregion;
    float*          xg  = hregion + 3200000;

    float* out    = (float*)d_out;
    float* regptr = out + n;

    hipMemsetAsync(counts, 0, NPAD * 4, stream);
    hipMemsetAsync(cursor, 0, NPAD * 4, stream);
    hipMemsetAsync(regptr, 0, 4, stream);

    degree_kernel<<<(E + 255) / 256, 256, 0, stream>>>(dst, counts, E);
    scan_block<<<NSCAN, 256, 0, stream>>>(counts, rowptr, bsum, n);
    scan_sums<<<1, 256, 0, stream>>>(bsum, NSCAN);
    scan_add<<<(n + 256) / 256, 256, 0, stream>>>(rowptr, bsum, counts, dinv, n, E);
    fill_csr<<<(E + 255) / 256, 256, 0, stream>>>(src, dst, rowptr, cursor, csr, E);
    cast_w1<<<(GLOB * 384 + 1023) / 1024, 1024, 0, stream>>>(gW1, w1b, GLOB * 384);
    conv_gemm<<<1024, 256, 0, stream>>>(state, convW, dinv, hb, sb, n);
    gather_fused<<<(n + 3) / 4, 256, 0, stream>>>(rowptr, csr, hb, dinv, convb, state, x, n);
    global_gemm1_mfma<<<391 * 2, 256, 0, stream>>>(sb, w1b, gb1, y1b, B);
    global_gemm2<<<(B * 64 + 255) / 256, 256, 0, stream>>>(y1b, gW2, gb2, xg, B);
    mlp_kernel<<<(n + MLP_NODES - 1) / MLP_NODES, 256, 0, stream>>>(
        x, xg, l1W, l1b, l2W, l2b, l3W, l3b, out, regptr, n);
}

// Round 8
// 419.178 us; speedup vs baseline: 2.2581x; 1.1774x over previous
//
#include <hip/hip_runtime.h>
#include <math.h>

#define N_NODES 150000
#define N_EDGES 1200000
#define C 64
#define ACT 6
#define B_ROWS 25000   // N/ACT
#define GLOB 256
#define GOUT 10
#define H 32

#define NPAD 150016            // N rounded up (alignment)
#define SCAN_CHUNK 1024
#define NSCAN 147              // ceil(150000/1024)

typedef short bf16x8 __attribute__((ext_vector_type(8)));
typedef float f32x4v __attribute__((ext_vector_type(4)));

// ---- bf16 helpers ----
__device__ __forceinline__ unsigned short f2bf(float f) {
    unsigned int u = __builtin_bit_cast(unsigned int, f);
    unsigned int r = (u + 0x7fffu + ((u >> 16) & 1u)) >> 16;   // RTNE
    return (unsigned short)r;
}
__device__ __forceinline__ unsigned int pack2bf(float a, float b) {
    return (unsigned int)f2bf(a) | ((unsigned int)f2bf(b) << 16);
}
__device__ __forceinline__ float bflo(unsigned int u) {
    return __builtin_bit_cast(float, u << 16);
}
__device__ __forceinline__ float bfhi(unsigned int u) {
    return __builtin_bit_cast(float, u & 0xffff0000u);
}
__device__ __forceinline__ float bf1(unsigned short us) {
    return __builtin_bit_cast(float, ((unsigned int)us) << 16);
}

// ---------------- degree histogram + per-edge rank ----------------
__global__ void degree_kernel(const int* __restrict__ dst, int* __restrict__ counts,
                              int* __restrict__ rank, int E) {
    int e = blockIdx.x * blockDim.x + threadIdx.x;
    if (e < E) rank[e] = atomicAdd(&counts[dst[e]], 1);
}

// ---------------- prefix scan (3 kernels) ----------------
__global__ void scan_block(const int* __restrict__ counts, int* __restrict__ rowptr,
                           int* __restrict__ bsum, int n) {
    __shared__ int lds[256];
    int base = blockIdx.x * SCAN_CHUNK;
    int t = threadIdx.x;
    int v[4]; int s = 0;
    #pragma unroll
    for (int i = 0; i < 4; ++i) {
        int idx = base + t * 4 + i;
        v[i] = (idx < n) ? counts[idx] : 0;
        s += v[i];
    }
    lds[t] = s; __syncthreads();
    for (int off = 1; off < 256; off <<= 1) {
        int x = (t >= off) ? lds[t - off] : 0;
        __syncthreads();
        lds[t] += x;
        __syncthreads();
    }
    int excl = lds[t] - s;
    if (t == 255) bsum[blockIdx.x] = lds[255];
    int run = excl;
    #pragma unroll
    for (int i = 0; i < 4; ++i) {
        int idx = base + t * 4 + i;
        if (idx < n) rowptr[idx] = run;
        run += v[i];
    }
}

__global__ void scan_sums(int* __restrict__ bsum, int nb) {
    __shared__ int lds[256];
    int t = threadIdx.x;
    int v = (t < nb) ? bsum[t] : 0;
    lds[t] = v; __syncthreads();
    for (int off = 1; off < 256; off <<= 1) {
        int x = (t >= off) ? lds[t - off] : 0;
        __syncthreads();
        lds[t] += x;
        __syncthreads();
    }
    if (t < nb) bsum[t] = lds[t] - v;   // exclusive
}

__global__ void scan_add(int* __restrict__ rowptr, const int* __restrict__ bsum,
                         const int* __restrict__ counts, float* __restrict__ dinv,
                         int n, int E) {
    int i = blockIdx.x * blockDim.x + threadIdx.x;
    if (i < n) {
        rowptr[i] += bsum[i >> 10];
        dinv[i] = rsqrtf((float)counts[i] + 1.0f);
    }
    if (i == n) rowptr[n] = E;
}

// ---------------- CSR fill (atomic-free: rank precomputed) ----------------
__global__ void fill_csr(const int* __restrict__ src, const int* __restrict__ dst,
                         const int* __restrict__ rowptr, const int* __restrict__ rank,
                         int* __restrict__ csr, int E) {
    int e = blockIdx.x * blockDim.x + threadIdx.x;
    if (e >= E) return;
    int d = dst[e];
    csr[rowptr[d] + rank[e]] = src[e];
}

// ---------------- hs = bf16((state @ convW^T) * dinv) ; sb = bf16(state) ----------------
__global__ void conv_gemm(const float* __restrict__ x, const float* __restrict__ W,
                          const float* __restrict__ dinv,
                          unsigned short* __restrict__ hb,
                          unsigned short* __restrict__ sb, int nrows) {
    __shared__ float Wt[64 * 65];     // transposed, padded
    __shared__ float sx[4][64];
    for (int idx = threadIdx.x; idx < 4096; idx += 256) {
        int j = idx >> 6, k = idx & 63;
        Wt[k * 65 + j] = W[idx];
    }
    __syncthreads();
    int r = threadIdx.x >> 6, c = threadIdx.x & 63;
    int ngroups = (nrows + 3) >> 2;
    for (int g = blockIdx.x; g < ngroups; g += gridDim.x) {
        int row = g * 4 + r;
        float xv = (row < nrows) ? x[row * 64 + c] : 0.f;
        sx[r][c] = xv;
        __syncthreads();
        float acc = 0.f;
        #pragma unroll
        for (int k = 0; k < 64; ++k) acc += sx[r][k] * Wt[k * 65 + c];
        if (row < nrows) {
            hb[(size_t)row * 64 + c] = f2bf(acc * dinv[row]);
            sb[(size_t)row * 64 + c] = f2bf(xv);
        }
        __syncthreads();
    }
}

// ---------------- gather (CSR, bf16 rows): 8 edge-groups x 8 lanes -> bf16 x ----------------
__global__ void gather_fused(const int* __restrict__ rowptr, const int* __restrict__ csr,
                             const unsigned short* __restrict__ hb, const float* __restrict__ dinv,
                             const float* __restrict__ convb, const float* __restrict__ state,
                             unsigned short* __restrict__ xb, int n) {
    int node = blockIdx.x * 4 + (threadIdx.x >> 6);
    if (node >= n) return;
    int lane = threadIdx.x & 63;
    int g = lane >> 3;        // edge group 0..7
    int l = lane & 7;         // channel octet (8 bf16 per lane)
    int beg = rowptr[node], end = rowptr[node + 1];
    float acc[8] = {0.f, 0.f, 0.f, 0.f, 0.f, 0.f, 0.f, 0.f};
    for (int e = beg + g; e < end; e += 8) {
        int s = csr[e];
        uint4 u = *(const uint4*)(hb + (size_t)s * 64 + l * 8);
        acc[0] += bflo(u.x); acc[1] += bfhi(u.x);
        acc[2] += bflo(u.y); acc[3] += bfhi(u.y);
        acc[4] += bflo(u.z); acc[5] += bfhi(u.z);
        acc[6] += bflo(u.w); acc[7] += bfhi(u.w);
    }
    #pragma unroll
    for (int st = 8; st < 64; st <<= 1) {
        #pragma unroll
        for (int j = 0; j < 8; ++j) acc[j] += __shfl_xor(acc[j], st, 64);
    }
    if (g == 0) {
        float dd = dinv[node];
        uint4 us = *(const uint4*)(hb + (size_t)node * 64 + l * 8);
        float sf[8] = {bflo(us.x), bfhi(us.x), bflo(us.y), bfhi(us.y),
                       bflo(us.z), bfhi(us.z), bflo(us.w), bfhi(us.w)};
        float4 c0 = *(const float4*)(convb + l * 8);
        float4 c1 = *(const float4*)(convb + l * 8 + 4);
        float4 s0 = *(const float4*)(state + (size_t)node * 64 + l * 8);
        float4 s1 = *(const float4*)(state + (size_t)node * 64 + l * 8 + 4);
        float cb[8] = {c0.x, c0.y, c0.z, c0.w, c1.x, c1.y, c1.z, c1.w};
        float sv[8] = {s0.x, s0.y, s0.z, s0.w, s1.x, s1.y, s1.z, s1.w};
        float o[8];
        #pragma unroll
        for (int j = 0; j < 8; ++j) {
            float v = dd * (acc[j] + sf[j]) + cb[j];
            v = (v > 0.f) ? v : 0.f;
            o[j] = v + sv[j];
        }
        uint2 p0 = make_uint2(pack2bf(o[0], o[1]), pack2bf(o[2], o[3]));
        uint2 p1 = make_uint2(pack2bf(o[4], o[5]), pack2bf(o[6], o[7]));
        unsigned short* xp = xb + (size_t)node * 64 + l * 8;
        *(uint2*)xp       = p0;
        *(uint2*)(xp + 4) = p1;
    }
}

// ---------------- cast all weights to bf16 (gW1, l1W padded 96, l2W) ----------------
__global__ void cast_weights(const float* __restrict__ gW1, const float* __restrict__ l1W,
                             const float* __restrict__ l2W,
                             unsigned short* __restrict__ w1b,   // [256*384]
                             unsigned short* __restrict__ w1p,   // [32*96] zero-padded
                             unsigned short* __restrict__ w2p) { // [32*32]
    int i = blockIdx.x * blockDim.x + threadIdx.x;
    if (i < 98304) {
        w1b[i] = f2bf(gW1[i]);
    } else if (i < 98304 + 3072) {
        int j = i - 98304;
        int r = j / 96, c = j - r * 96;
        w1p[j] = (c < 74) ? f2bf(l1W[r * 74 + c]) : 0;
    } else if (i < 98304 + 3072 + 1024) {
        int j = i - 98304 - 3072;
        w2p[j] = f2bf(l2W[j]);
    }
}

// ---------------- global branch layer 1 (MFMA bf16, LDS-free) ----------------
__global__ __launch_bounds__(256) void global_gemm1_mfma(
        const unsigned short* __restrict__ Ab,   // [25000][384] bf16
        const unsigned short* __restrict__ Wb,   // [256][384] bf16
        const float* __restrict__ bias,          // gb1
        unsigned short* __restrict__ y1b, int M) {
    int wave = threadIdx.x >> 6;
    int lane = threadIdx.x & 63;
    int quad = lane >> 4;
    int lm   = lane & 15;
    int mtile = blockIdx.x >> 1;
    int nhalf = blockIdx.x & 1;
    int row0 = mtile * 64 + wave * 16;
    int col0 = nhalf * 128;

    int arow = row0 + lm;
    if (arow >= M) arow = M - 1;             // clamp; stores predicated
    const unsigned short* ap = Ab + (size_t)arow * 384 + quad * 8;
    const unsigned short* bp = Wb + (size_t)(col0 + lm) * 384 + quad * 8;

    f32x4v acc[8];
    #pragma unroll
    for (int t = 0; t < 8; ++t) acc[t] = (f32x4v){0.f, 0.f, 0.f, 0.f};

    #pragma unroll
    for (int ks = 0; ks < 12; ++ks) {
        bf16x8 af = *(const bf16x8*)(ap + ks * 32);
        #pragma unroll
        for (int t = 0; t < 8; ++t) {
            bf16x8 bfr = *(const bf16x8*)(bp + (size_t)t * 16 * 384 + ks * 32);
            acc[t] = __builtin_amdgcn_mfma_f32_16x16x32_bf16(af, bfr, acc[t], 0, 0, 0);
        }
    }

    #pragma unroll
    for (int t = 0; t < 8; ++t) {
        int nn = col0 + t * 16 + lm;
        float bv = bias[nn];
        #pragma unroll
        for (int r = 0; r < 4; ++r) {
            int m = row0 + quad * 4 + r;
            if (m < M) {
                float v = acc[t][r] + bv;
                v = (v > 0.f) ? v : 0.01f * v;
                y1b[(size_t)m * 256 + nn] = f2bf(v);
            }
        }
    }
}

// ---------------- global branch layer 2: xgb = bf16 [B][16] (zero-padded) ----------------
__global__ void global_gemm2(const unsigned short* __restrict__ y1b, const float* __restrict__ W2,
                             const float* __restrict__ b2, unsigned short* __restrict__ xgb, int B) {
    int wave = (blockIdx.x * blockDim.x + threadIdx.x) >> 6;
    int lane = threadIdx.x & 63;
    if (wave >= B) return;
    const unsigned short* yr = y1b + (size_t)wave * 256;
    float yv[4];
    #pragma unroll
    for (int j = 0; j < 4; ++j) yv[j] = bf1(yr[lane + 64 * j]);
    float res[10];
    #pragma unroll
    for (int o = 0; o < 10; ++o) {
        const float* w = W2 + o * 256;
        float p = 0.f;
        #pragma unroll
        for (int j = 0; j < 4; ++j) p += yv[j] * w[lane + 64 * j];
        #pragma unroll
        for (int off = 32; off > 0; off >>= 1) p += __shfl_down(p, off, 64);
        res[o] = p;
    }
    if (lane == 0) {
        float v[10];
        #pragma unroll
        for (int o = 0; o < 10; ++o) {
            float t = res[o] + b2[o];
            v[o] = (t > 0.f) ? t : 0.01f * t;
        }
        uint4 pa = make_uint4(pack2bf(v[0], v[1]), pack2bf(v[2], v[3]),
                              pack2bf(v[4], v[5]), pack2bf(v[6], v[7]));
        uint4 pb = make_uint4(pack2bf(v[8], v[9]), 0u, 0u, 0u);
        unsigned short* xp = xgb + (size_t)wave * 16;
        *(uint4*)xp       = pa;
        *(uint4*)(xp + 8) = pb;
    }
}

// ---------------- final MLP via MFMA: one wave = 48 nodes (3 m-tiles) ----------------
#define Y1_STRIDE 40
__global__ __launch_bounds__(256) void mlp_mfma(
        const unsigned short* __restrict__ xb,    // [N][64] bf16
        const unsigned short* __restrict__ xgb,   // [B][16] bf16 zero-padded
        const unsigned short* __restrict__ w1p,   // [32][96] bf16 zero-padded
        const unsigned short* __restrict__ w2p,   // [32][32] bf16
        const float* __restrict__ l1b, const float* __restrict__ l2b,
        const float* __restrict__ l3W, const float* __restrict__ l3b,
        float* __restrict__ out, float* __restrict__ reg_out, int n) {
    __shared__ unsigned short y1L[4][16 * Y1_STRIDE];
    __shared__ float concL[4][48];

    int wid  = threadIdx.x >> 6;
    int lane = threadIdx.x & 63;
    int quad = lane >> 4;
    int lm   = lane & 15;
    int base = (blockIdx.x * 4 + wid) * 48;
    if (base >= n) return;                        // wave-uniform; no __syncthreads below

    // layer-1 B-frags: 2 n-tiles x 3 k-steps
    bf16x8 b1[2][3];
    #pragma unroll
    for (int t2 = 0; t2 < 2; ++t2)
        #pragma unroll
        for (int ks = 0; ks < 3; ++ks)
            b1[t2][ks] = *(const bf16x8*)(w1p + (t2 * 16 + lm) * 96 + ks * 32 + quad * 8);
    // layer-2 B-frags
    bf16x8 b2f[2];
    #pragma unroll
    for (int t2 = 0; t2 < 2; ++t2)
        b2f[t2] = *(const bf16x8*)(w2p + (t2 * 16 + lm) * 32 + quad * 8);

    float bias1a = l1b[lm],      bias1b = l1b[16 + lm];
    float bias2a = l2b[lm],      bias2b = l2b[16 + lm];
    float w3a    = l3W[lm],      w3b    = l3W[16 + lm];
    float b3     = l3b[0];

    unsigned short* myY = y1L[wid];
    float* myC = concL[wid];

    for (int t = 0; t < 3; ++t) {
        int node = base + t * 16 + lm;
        // layer-1 A-frags
        bf16x8 a0 = *(const bf16x8*)(xb + (size_t)node * 64 + quad * 8);
        bf16x8 a1 = *(const bf16x8*)(xb + (size_t)node * 64 + 32 + quad * 8);
        bf16x8 a2 = (bf16x8){0, 0, 0, 0, 0, 0, 0, 0};
        if (quad < 2) a2 = *(const bf16x8*)(xgb + (size_t)(node / 6) * 16 + quad * 8);

        f32x4v acc0 = (f32x4v){0.f, 0.f, 0.f, 0.f};
        f32x4v acc1 = acc0;
        acc0 = __builtin_amdgcn_mfma_f32_16x16x32_bf16(a0, b1[0][0], acc0, 0, 0, 0);
        acc1 = __builtin_amdgcn_mfma_f32_16x16x32_bf16(a0, b1[1][0], acc1, 0, 0, 0);
        acc0 = __builtin_amdgcn_mfma_f32_16x16x32_bf16(a1, b1[0][1], acc0, 0, 0, 0);
        acc1 = __builtin_amdgcn_mfma_f32_16x16x32_bf16(a1, b1[1][1], acc1, 0, 0, 0);
        acc0 = __builtin_amdgcn_mfma_f32_16x16x32_bf16(a2, b1[0][2], acc0, 0, 0, 0);
        acc1 = __builtin_amdgcn_mfma_f32_16x16x32_bf16(a2, b1[1][2], acc1, 0, 0, 0);

        // bias + leaky, transpose C->A via LDS (bf16)
        #pragma unroll
        for (int r = 0; r < 4; ++r) {
            float v0 = acc0[r] + bias1a;
            float v1 = acc1[r] + bias1b;
            v0 = (v0 > 0.f) ? v0 : 0.01f * v0;
            v1 = (v1 > 0.f) ? v1 : 0.01f * v1;
            myY[(quad * 4 + r) * Y1_STRIDE + lm]      = f2bf(v0);
            myY[(quad * 4 + r) * Y1_STRIDE + 16 + lm] = f2bf(v1);
        }
        // layer-2
        bf16x8 a2f = *(const bf16x8*)(myY + lm * Y1_STRIDE + quad * 8);
        f32x4v acc20 = (f32x4v){0.f, 0.f, 0.f, 0.f};
        f32x4v acc21 = acc20;
        acc20 = __builtin_amdgcn_mfma_f32_16x16x32_bf16(a2f, b2f[0], acc20, 0, 0, 0);
        acc21 = __builtin_amdgcn_mfma_f32_16x16x32_bf16(a2f, b2f[1], acc21, 0, 0, 0);

        // layer-3 partial per lane, butterfly over lm
        float part[4];
        #pragma unroll
        for (int r = 0; r < 4; ++r) {
            float y2a = acc20[r] + bias2a;
            float y2b = acc21[r] + bias2b;
            y2a = (y2a > 0.f) ? y2a : 0.01f * y2a;
            y2b = (y2b > 0.f) ? y2b : 0.01f * y2b;
            part[r] = y2a * w3a + y2b * w3b;
        }
        #pragma unroll
        for (int st = 1; st < 16; st <<= 1) {
            #pragma unroll
            for (int r = 0; r < 4; ++r) part[r] += __shfl_xor(part[r], st, 64);
        }
        if (lm == 0) {
            #pragma unroll
            for (int r = 0; r < 4; ++r) {
                float a3 = part[r] + b3;
                myC[t * 16 + quad * 4 + r] = (a3 > 20.f) ? a3 : log1pf(expf(a3));
            }
        }
    }

    // normalize (groups of 6 are wave-local: 48 % 6 == 0) + regularize
    float myabs = 0.f;
    if (lane < 48) {
        int g0 = (lane / 6) * 6;
        float s = 0.f;
        #pragma unroll
        for (int i = 0; i < 6; ++i) s += myC[g0 + i];
        float c = myC[lane];
        out[base + lane] = c / (s + 1e-20f);
        myabs = fabsf(c);
    }
    #pragma unroll
    for (int off = 32; off > 0; off >>= 1) myabs += __shfl_down(myabs, off, 64);
    if (lane == 0) atomicAdd(reg_out, myabs * (1.0f / (float)N_NODES));
}

extern "C" void kernel_launch(void* const* d_in, const int* in_sizes, int n_in,
                              void* d_out, int out_size, void* d_ws, size_t ws_size,
                              hipStream_t stream) {
    const float* state = (const float*)d_in[0];
    const int*   ei    = (const int*)d_in[1];
    const float* convW = (const float*)d_in[2];
    const float* convb = (const float*)d_in[3];
    const float* gW1   = (const float*)d_in[4];
    const float* gb1   = (const float*)d_in[5];
    const float* gW2   = (const float*)d_in[6];
    const float* gb2   = (const float*)d_in[7];
    const float* l1W   = (const float*)d_in[8];
    const float* l1b   = (const float*)d_in[9];
    const float* l2W   = (const float*)d_in[10];
    const float* l2b   = (const float*)d_in[11];
    const float* l3W   = (const float*)d_in[12];
    const float* l3b   = (const float*)d_in[13];

    const int n = N_NODES, E = N_EDGES, B = B_ROWS;
    const int* src = ei;
    const int* dst = ei + E;

    // ---- workspace layout ----
    char* w = (char*)d_ws;
    int*   counts = (int*)w;                 w += NPAD * 4;
    int*   rank   = (int*)w;                 w += (size_t)E * 4;      // per-edge rank
    int*   rowptr = (int*)w;                 w += NPAD * 4;
    int*   bsum   = (int*)w;                 w += 256 * 4;
    float* dinv   = (float*)w;               w += NPAD * 4;
    int*   csr    = (int*)w;                 w += (size_t)E * 4;
    float* hregion= (float*)w;               w += (size_t)n * 64 * 4; // 38.4 MB
    unsigned short* xb = (unsigned short*)w; w += (size_t)n * 64 * 2; // 19.2 MB bf16 x
    unsigned short* w1b = (unsigned short*)w; w += 98304 * 2;
    unsigned short* w1p = (unsigned short*)w; w += 3072 * 2;
    unsigned short* w2p = (unsigned short*)w; w += 1024 * 2;
    // hregion phases:
    //   phase 1: hb = [0..19.2MB) bf16 h*dinv ; sb = [19.2..38.4MB) bf16 state
    //   phase 2: y1b = [0..12.8MB) bf16 y1 (hb dead) ; xgb = [12.8..13.6MB) bf16 [B][16]
    unsigned short* hb  = (unsigned short*)hregion;
    unsigned short* sb  = (unsigned short*)(hregion + 4800000);
    unsigned short* y1b = (unsigned short*)hregion;
    unsigned short* xgb = (unsigned short*)(hregion + 3200000);

    float* out    = (float*)d_out;
    float* regptr = out + n;

    hipMemsetAsync(counts, 0, NPAD * 4, stream);
    hipMemsetAsync(regptr, 0, 4, stream);

    degree_kernel<<<(E + 255) / 256, 256, 0, stream>>>(dst, counts, rank, E);
    scan_block<<<NSCAN, 256, 0, stream>>>(counts, rowptr, bsum, n);
    scan_sums<<<1, 256, 0, stream>>>(bsum, NSCAN);
    scan_add<<<(n + 256) / 256, 256, 0, stream>>>(rowptr, bsum, counts, dinv, n, E);
    fill_csr<<<(E + 255) / 256, 256, 0, stream>>>(src, dst, rowptr, rank, csr, E);
    cast_weights<<<(98304 + 3072 + 1024 + 255) / 256, 256, 0, stream>>>(
        gW1, l1W, l2W, w1b, w1p, w2p);
    conv_gemm<<<1024, 256, 0, stream>>>(state, convW, dinv, hb, sb, n);
    gather_fused<<<(n + 3) / 4, 256, 0, stream>>>(rowptr, csr, hb, dinv, convb, state, xb, n);
    global_gemm1_mfma<<<391 * 2, 256, 0, stream>>>(sb, w1b, gb1, y1b, B);
    global_gemm2<<<(B * 64 + 255) / 256, 256, 0, stream>>>(y1b, gW2, gb2, xgb, B);
    mlp_mfma<<<(3125 + 3) / 4, 256, 0, stream>>>(xb, xgb, w1p, w2p, l1b, l2b, l3W, l3b,
                                                 out, regptr, n);
}

// Round 9
// 384.400 us; speedup vs baseline: 2.4624x; 1.0905x over previous
//
#include <hip/hip_runtime.h>
#include <math.h>

#define N_NODES 150000
#define N_EDGES 1200000
#define C 64
#define ACT 6
#define B_ROWS 25000   // N/ACT
#define GLOB 256
#define GOUT 10
#define H 32

#define NPAD 150016            // N rounded up (alignment)
#define SCAN_CHUNK 1024
#define NSCAN 147              // ceil(150000/1024)

typedef short bf16x8 __attribute__((ext_vector_type(8)));
typedef float f32x4v __attribute__((ext_vector_type(4)));

// ---- bf16 helpers ----
__device__ __forceinline__ unsigned short f2bf(float f) {
    unsigned int u = __builtin_bit_cast(unsigned int, f);
    unsigned int r = (u + 0x7fffu + ((u >> 16) & 1u)) >> 16;   // RTNE
    return (unsigned short)r;
}
__device__ __forceinline__ unsigned int pack2bf(float a, float b) {
    return (unsigned int)f2bf(a) | ((unsigned int)f2bf(b) << 16);
}
__device__ __forceinline__ float bflo(unsigned int u) {
    return __builtin_bit_cast(float, u << 16);
}
__device__ __forceinline__ float bfhi(unsigned int u) {
    return __builtin_bit_cast(float, u & 0xffff0000u);
}
__device__ __forceinline__ float bf1(unsigned short us) {
    return __builtin_bit_cast(float, ((unsigned int)us) << 16);
}

// ---------------- degree histogram + per-edge rank ----------------
__global__ void degree_kernel(const int* __restrict__ dst, int* __restrict__ counts,
                              int* __restrict__ rank, int E) {
    int e = blockIdx.x * blockDim.x + threadIdx.x;
    if (e < E) rank[e] = atomicAdd(&counts[dst[e]], 1);
}

// ---------------- prefix scan (3 kernels) ----------------
__global__ void scan_block(const int* __restrict__ counts, int* __restrict__ rowptr,
                           int* __restrict__ bsum, int n) {
    __shared__ int lds[256];
    int base = blockIdx.x * SCAN_CHUNK;
    int t = threadIdx.x;
    int v[4]; int s = 0;
    #pragma unroll
    for (int i = 0; i < 4; ++i) {
        int idx = base + t * 4 + i;
        v[i] = (idx < n) ? counts[idx] : 0;
        s += v[i];
    }
    lds[t] = s; __syncthreads();
    for (int off = 1; off < 256; off <<= 1) {
        int x = (t >= off) ? lds[t - off] : 0;
        __syncthreads();
        lds[t] += x;
        __syncthreads();
    }
    int excl = lds[t] - s;
    if (t == 255) bsum[blockIdx.x] = lds[255];
    int run = excl;
    #pragma unroll
    for (int i = 0; i < 4; ++i) {
        int idx = base + t * 4 + i;
        if (idx < n) rowptr[idx] = run;
        run += v[i];
    }
}

__global__ void scan_sums(int* __restrict__ bsum, int nb) {
    __shared__ int lds[256];
    int t = threadIdx.x;
    int v = (t < nb) ? bsum[t] : 0;
    lds[t] = v; __syncthreads();
    for (int off = 1; off < 256; off <<= 1) {
        int x = (t >= off) ? lds[t - off] : 0;
        __syncthreads();
        lds[t] += x;
        __syncthreads();
    }
    if (t < nb) bsum[t] = lds[t] - v;   // exclusive
}

__global__ void scan_add(int* __restrict__ rowptr, const int* __restrict__ bsum,
                         const int* __restrict__ counts, float* __restrict__ dinv,
                         int n, int E) {
    int i = blockIdx.x * blockDim.x + threadIdx.x;
    if (i < n) {
        rowptr[i] += bsum[i >> 10];
        dinv[i] = rsqrtf((float)counts[i] + 1.0f);
    }
    if (i == n) rowptr[n] = E;
}

// ---------------- CSR fill (atomic-free: rank precomputed) ----------------
__global__ void fill_csr(const int* __restrict__ src, const int* __restrict__ dst,
                         const int* __restrict__ rowptr, const int* __restrict__ rank,
                         int* __restrict__ csr, int E) {
    int e = blockIdx.x * blockDim.x + threadIdx.x;
    if (e >= E) return;
    int d = dst[e];
    csr[rowptr[d] + rank[e]] = src[e];
}

// ---------------- prep: cast state + all weights to bf16 ----------------
#define NSTATE_V8 1200000      // 9.6M / 8
__global__ void prep_cast(const float* __restrict__ state, const float* __restrict__ convW,
                          const float* __restrict__ gW1, const float* __restrict__ l1W,
                          const float* __restrict__ l2W,
                          unsigned short* __restrict__ sb,    // [N*64]
                          unsigned short* __restrict__ wcb,   // [64*64]
                          unsigned short* __restrict__ w1b,   // [256*384]
                          unsigned short* __restrict__ w1p,   // [32*96] zero-padded
                          unsigned short* __restrict__ w2p) { // [32*32]
    int i = blockIdx.x * blockDim.x + threadIdx.x;
    if (i < NSTATE_V8) {
        const float4* p = (const float4*)(state + (size_t)i * 8);
        float4 a = p[0], b = p[1];
        uint4 o = make_uint4(pack2bf(a.x, a.y), pack2bf(a.z, a.w),
                             pack2bf(b.x, b.y), pack2bf(b.z, b.w));
        *(uint4*)(sb + (size_t)i * 8) = o;
        return;
    }
    int j = i - NSTATE_V8;
    if (j < 4096) {
        wcb[j] = f2bf(convW[j]);
    } else if (j < 4096 + 98304) {
        int k = j - 4096;
        w1b[k] = f2bf(gW1[k]);
    } else if (j < 4096 + 98304 + 3072) {
        int k = j - 4096 - 98304;
        int r = k / 96, c = k - r * 96;
        w1p[k] = (c < 74) ? f2bf(l1W[r * 74 + c]) : 0;
    } else if (j < 4096 + 98304 + 3072 + 1024) {
        int k = j - 4096 - 98304 - 3072;
        w2p[k] = f2bf(l2W[k]);
    }
}

// ---------------- conv via MFMA: hb = bf16((sb @ Wc^T) * dinv), one wave = 16 rows ----------------
__global__ __launch_bounds__(256) void conv_mfma(
        const unsigned short* __restrict__ sb,    // [N][64] bf16
        const unsigned short* __restrict__ wcb,   // [64][64] bf16
        const float* __restrict__ dinv,
        unsigned short* __restrict__ hb, int n) {
    int wid  = threadIdx.x >> 6;
    int lane = threadIdx.x & 63;
    int quad = lane >> 4;
    int lm   = lane & 15;
    int row0 = (blockIdx.x * 4 + wid) * 16;
    if (row0 >= n) return;                        // n = 150000 = 16*9375: no partial waves

    const unsigned short* ap = sb + (size_t)(row0 + lm) * 64 + quad * 8;
    bf16x8 a0 = *(const bf16x8*)ap;
    bf16x8 a1 = *(const bf16x8*)(ap + 32);

    f32x4v acc[4];
    #pragma unroll
    for (int t = 0; t < 4; ++t) acc[t] = (f32x4v){0.f, 0.f, 0.f, 0.f};
    #pragma unroll
    for (int t = 0; t < 4; ++t) {
        const unsigned short* bp = wcb + (size_t)(t * 16 + lm) * 64 + quad * 8;
        bf16x8 b0 = *(const bf16x8*)bp;
        bf16x8 b1 = *(const bf16x8*)(bp + 32);
        acc[t] = __builtin_amdgcn_mfma_f32_16x16x32_bf16(a0, b0, acc[t], 0, 0, 0);
        acc[t] = __builtin_amdgcn_mfma_f32_16x16x32_bf16(a1, b1, acc[t], 0, 0, 0);
    }

    float dv[4];
    #pragma unroll
    for (int r = 0; r < 4; ++r) dv[r] = dinv[row0 + quad * 4 + r];
    #pragma unroll
    for (int t = 0; t < 4; ++t) {
        #pragma unroll
        for (int r = 0; r < 4; ++r) {
            int m = row0 + quad * 4 + r;
            hb[(size_t)m * 64 + t * 16 + lm] = f2bf(acc[t][r] * dv[r]);
        }
    }
}

// ---------------- gather (CSR, bf16 rows): 8 edge-groups x 8 lanes -> bf16 x ----------------
__global__ void gather_fused(const int* __restrict__ rowptr, const int* __restrict__ csr,
                             const unsigned short* __restrict__ hb, const float* __restrict__ dinv,
                             const float* __restrict__ convb, const float* __restrict__ state,
                             unsigned short* __restrict__ xb, int n) {
    int node = blockIdx.x * 4 + (threadIdx.x >> 6);
    if (node >= n) return;
    int lane = threadIdx.x & 63;
    int g = lane >> 3;        // edge group 0..7
    int l = lane & 7;         // channel octet (8 bf16 per lane)
    int beg = rowptr[node], end = rowptr[node + 1];
    float acc[8] = {0.f, 0.f, 0.f, 0.f, 0.f, 0.f, 0.f, 0.f};
    for (int e = beg + g; e < end; e += 8) {
        int s = csr[e];
        uint4 u = *(const uint4*)(hb + (size_t)s * 64 + l * 8);
        acc[0] += bflo(u.x); acc[1] += bfhi(u.x);
        acc[2] += bflo(u.y); acc[3] += bfhi(u.y);
        acc[4] += bflo(u.z); acc[5] += bfhi(u.z);
        acc[6] += bflo(u.w); acc[7] += bfhi(u.w);
    }
    #pragma unroll
    for (int st = 8; st < 64; st <<= 1) {
        #pragma unroll
        for (int j = 0; j < 8; ++j) acc[j] += __shfl_xor(acc[j], st, 64);
    }
    if (g == 0) {
        float dd = dinv[node];
        uint4 us = *(const uint4*)(hb + (size_t)node * 64 + l * 8);
        float sf[8] = {bflo(us.x), bfhi(us.x), bflo(us.y), bfhi(us.y),
                       bflo(us.z), bfhi(us.z), bflo(us.w), bfhi(us.w)};
        float4 c0 = *(const float4*)(convb + l * 8);
        float4 c1 = *(const float4*)(convb + l * 8 + 4);
        float4 s0 = *(const float4*)(state + (size_t)node * 64 + l * 8);
        float4 s1 = *(const float4*)(state + (size_t)node * 64 + l * 8 + 4);
        float cb[8] = {c0.x, c0.y, c0.z, c0.w, c1.x, c1.y, c1.z, c1.w};
        float sv[8] = {s0.x, s0.y, s0.z, s0.w, s1.x, s1.y, s1.z, s1.w};
        float o[8];
        #pragma unroll
        for (int j = 0; j < 8; ++j) {
            float v = dd * (acc[j] + sf[j]) + cb[j];
            v = (v > 0.f) ? v : 0.f;
            o[j] = v + sv[j];
        }
        uint2 p0 = make_uint2(pack2bf(o[0], o[1]), pack2bf(o[2], o[3]));
        uint2 p1 = make_uint2(pack2bf(o[4], o[5]), pack2bf(o[6], o[7]));
        unsigned short* xp = xb + (size_t)node * 64 + l * 8;
        *(uint2*)xp       = p0;
        *(uint2*)(xp + 4) = p1;
    }
}

// ---------------- global branch layer 1 (MFMA bf16, LDS-free) ----------------
__global__ __launch_bounds__(256) void global_gemm1_mfma(
        const unsigned short* __restrict__ Ab,   // [25000][384] bf16
        const unsigned short* __restrict__ Wb,   // [256][384] bf16
        const float* __restrict__ bias,          // gb1
        unsigned short* __restrict__ y1b, int M) {
    int wave = threadIdx.x >> 6;
    int lane = threadIdx.x & 63;
    int quad = lane >> 4;
    int lm   = lane & 15;
    int mtile = blockIdx.x >> 1;
    int nhalf = blockIdx.x & 1;
    int row0 = mtile * 64 + wave * 16;
    int col0 = nhalf * 128;

    int arow = row0 + lm;
    if (arow >= M) arow = M - 1;             // clamp; stores predicated
    const unsigned short* ap = Ab + (size_t)arow * 384 + quad * 8;
    const unsigned short* bp = Wb + (size_t)(col0 + lm) * 384 + quad * 8;

    f32x4v acc[8];
    #pragma unroll
    for (int t = 0; t < 8; ++t) acc[t] = (f32x4v){0.f, 0.f, 0.f, 0.f};

    #pragma unroll
    for (int ks = 0; ks < 12; ++ks) {
        bf16x8 af = *(const bf16x8*)(ap + ks * 32);
        #pragma unroll
        for (int t = 0; t < 8; ++t) {
            bf16x8 bfr = *(const bf16x8*)(bp + (size_t)t * 16 * 384 + ks * 32);
            acc[t] = __builtin_amdgcn_mfma_f32_16x16x32_bf16(af, bfr, acc[t], 0, 0, 0);
        }
    }

    #pragma unroll
    for (int t = 0; t < 8; ++t) {
        int nn = col0 + t * 16 + lm;
        float bv = bias[nn];
        #pragma unroll
        for (int r = 0; r < 4; ++r) {
            int m = row0 + quad * 4 + r;
            if (m < M) {
                float v = acc[t][r] + bv;
                v = (v > 0.f) ? v : 0.01f * v;
                y1b[(size_t)m * 256 + nn] = f2bf(v);
            }
        }
    }
}

// ---------------- global branch layer 2: xgb = bf16 [B][16] (zero-padded) ----------------
__global__ void global_gemm2(const unsigned short* __restrict__ y1b, const float* __restrict__ W2,
                             const float* __restrict__ b2, unsigned short* __restrict__ xgb, int B) {
    int wave = (blockIdx.x * blockDim.x + threadIdx.x) >> 6;
    int lane = threadIdx.x & 63;
    if (wave >= B) return;
    const unsigned short* yr = y1b + (size_t)wave * 256;
    float yv[4];
    #pragma unroll
    for (int j = 0; j < 4; ++j) yv[j] = bf1(yr[lane + 64 * j]);
    float res[10];
    #pragma unroll
    for (int o = 0; o < 10; ++o) {
        const float* w = W2 + o * 256;
        float p = 0.f;
        #pragma unroll
        for (int j = 0; j < 4; ++j) p += yv[j] * w[lane + 64 * j];
        #pragma unroll
        for (int off = 32; off > 0; off >>= 1) p += __shfl_down(p, off, 64);
        res[o] = p;
    }
    if (lane == 0) {
        float v[10];
        #pragma unroll
        for (int o = 0; o < 10; ++o) {
            float t = res[o] + b2[o];
            v[o] = (t > 0.f) ? t : 0.01f * t;
        }
        uint4 pa = make_uint4(pack2bf(v[0], v[1]), pack2bf(v[2], v[3]),
                              pack2bf(v[4], v[5]), pack2bf(v[6], v[7]));
        uint4 pb = make_uint4(pack2bf(v[8], v[9]), 0u, 0u, 0u);
        unsigned short* xp = xgb + (size_t)wave * 16;
        *(uint4*)xp       = pa;
        *(uint4*)(xp + 8) = pb;
    }
}

// ---------------- final MLP via MFMA: one wave = 48 nodes (3 m-tiles) ----------------
#define Y1_STRIDE 40
__global__ __launch_bounds__(256) void mlp_mfma(
        const unsigned short* __restrict__ xb,    // [N][64] bf16
        const unsigned short* __restrict__ xgb,   // [B][16] bf16 zero-padded
        const unsigned short* __restrict__ w1p,   // [32][96] bf16 zero-padded
        const unsigned short* __restrict__ w2p,   // [32][32] bf16
        const float* __restrict__ l1b, const float* __restrict__ l2b,
        const float* __restrict__ l3W, const float* __restrict__ l3b,
        float* __restrict__ out, float* __restrict__ reg_out, int n) {
    __shared__ unsigned short y1L[4][16 * Y1_STRIDE];
    __shared__ float concL[4][48];

    int wid  = threadIdx.x >> 6;
    int lane = threadIdx.x & 63;
    int quad = lane >> 4;
    int lm   = lane & 15;
    int base = (blockIdx.x * 4 + wid) * 48;
    if (base >= n) return;                        // wave-uniform; no __syncthreads below

    bf16x8 b1[2][3];
    #pragma unroll
    for (int t2 = 0; t2 < 2; ++t2)
        #pragma unroll
        for (int ks = 0; ks < 3; ++ks)
            b1[t2][ks] = *(const bf16x8*)(w1p + (t2 * 16 + lm) * 96 + ks * 32 + quad * 8);
    bf16x8 b2f[2];
    #pragma unroll
    for (int t2 = 0; t2 < 2; ++t2)
        b2f[t2] = *(const bf16x8*)(w2p + (t2 * 16 + lm) * 32 + quad * 8);

    float bias1a = l1b[lm],      bias1b = l1b[16 + lm];
    float bias2a = l2b[lm],      bias2b = l2b[16 + lm];
    float w3a    = l3W[lm],      w3b    = l3W[16 + lm];
    float b3     = l3b[0];

    unsigned short* myY = y1L[wid];
    float* myC = concL[wid];

    for (int t = 0; t < 3; ++t) {
        int node = base + t * 16 + lm;
        bf16x8 a0 = *(const bf16x8*)(xb + (size_t)node * 64 + quad * 8);
        bf16x8 a1 = *(const bf16x8*)(xb + (size_t)node * 64 + 32 + quad * 8);
        bf16x8 a2 = (bf16x8){0, 0, 0, 0, 0, 0, 0, 0};
        if (quad < 2) a2 = *(const bf16x8*)(xgb + (size_t)(node / 6) * 16 + quad * 8);

        f32x4v acc0 = (f32x4v){0.f, 0.f, 0.f, 0.f};
        f32x4v acc1 = acc0;
        acc0 = __builtin_amdgcn_mfma_f32_16x16x32_bf16(a0, b1[0][0], acc0, 0, 0, 0);
        acc1 = __builtin_amdgcn_mfma_f32_16x16x32_bf16(a0, b1[1][0], acc1, 0, 0, 0);
        acc0 = __builtin_amdgcn_mfma_f32_16x16x32_bf16(a1, b1[0][1], acc0, 0, 0, 0);
        acc1 = __builtin_amdgcn_mfma_f32_16x16x32_bf16(a1, b1[1][1], acc1, 0, 0, 0);
        acc0 = __builtin_amdgcn_mfma_f32_16x16x32_bf16(a2, b1[0][2], acc0, 0, 0, 0);
        acc1 = __builtin_amdgcn_mfma_f32_16x16x32_bf16(a2, b1[1][2], acc1, 0, 0, 0);

        #pragma unroll
        for (int r = 0; r < 4; ++r) {
            float v0 = acc0[r] + bias1a;
            float v1 = acc1[r] + bias1b;
            v0 = (v0 > 0.f) ? v0 : 0.01f * v0;
            v1 = (v1 > 0.f) ? v1 : 0.01f * v1;
            myY[(quad * 4 + r) * Y1_STRIDE + lm]      = f2bf(v0);
            myY[(quad * 4 + r) * Y1_STRIDE + 16 + lm] = f2bf(v1);
        }
        bf16x8 a2f = *(const bf16x8*)(myY + lm * Y1_STRIDE + quad * 8);
        f32x4v acc20 = (f32x4v){0.f, 0.f, 0.f, 0.f};
        f32x4v acc21 = acc20;
        acc20 = __builtin_amdgcn_mfma_f32_16x16x32_bf16(a2f, b2f[0], acc20, 0, 0, 0);
        acc21 = __builtin_amdgcn_mfma_f32_16x16x32_bf16(a2f, b2f[1], acc21, 0, 0, 0);

        float part[4];
        #pragma unroll
        for (int r = 0; r < 4; ++r) {
            float y2a = acc20[r] + bias2a;
            float y2b = acc21[r] + bias2b;
            y2a = (y2a > 0.f) ? y2a : 0.01f * y2a;
            y2b = (y2b > 0.f) ? y2b : 0.01f * y2b;
            part[r] = y2a * w3a + y2b * w3b;
        }
        #pragma unroll
        for (int st = 1; st < 16; st <<= 1) {
            #pragma unroll
            for (int r = 0; r < 4; ++r) part[r] += __shfl_xor(part[r], st, 64);
        }
        if (lm == 0) {
            #pragma unroll
            for (int r = 0; r < 4; ++r) {
                float a3 = part[r] + b3;
                myC[t * 16 + quad * 4 + r] = (a3 > 20.f) ? a3 : log1pf(expf(a3));
            }
        }
    }

    float myabs = 0.f;
    if (lane < 48) {
        int g0 = (lane / 6) * 6;
        float s = 0.f;
        #pragma unroll
        for (int i = 0; i < 6; ++i) s += myC[g0 + i];
        float c = myC[lane];
        out[base + lane] = c / (s + 1e-20f);
        myabs = fabsf(c);
    }
    #pragma unroll
    for (int off = 32; off > 0; off >>= 1) myabs += __shfl_down(myabs, off, 64);
    if (lane == 0) atomicAdd(reg_out, myabs * (1.0f / (float)N_NODES));
}

extern "C" void kernel_launch(void* const* d_in, const int* in_sizes, int n_in,
                              void* d_out, int out_size, void* d_ws, size_t ws_size,
                              hipStream_t stream) {
    const float* state = (const float*)d_in[0];
    const int*   ei    = (const int*)d_in[1];
    const float* convW = (const float*)d_in[2];
    const float* convb = (const float*)d_in[3];
    const float* gW1   = (const float*)d_in[4];
    const float* gb1   = (const float*)d_in[5];
    const float* gW2   = (const float*)d_in[6];
    const float* gb2   = (const float*)d_in[7];
    const float* l1W   = (const float*)d_in[8];
    const float* l1b   = (const float*)d_in[9];
    const float* l2W   = (const float*)d_in[10];
    const float* l2b   = (const float*)d_in[11];
    const float* l3W   = (const float*)d_in[12];
    const float* l3b   = (const float*)d_in[13];

    const int n = N_NODES, E = N_EDGES, B = B_ROWS;
    const int* src = ei;
    const int* dst = ei + E;

    // ---- workspace layout ----
    char* w = (char*)d_ws;
    int*   counts = (int*)w;                 w += NPAD * 4;
    int*   rank   = (int*)w;                 w += (size_t)E * 4;
    int*   rowptr = (int*)w;                 w += NPAD * 4;
    int*   bsum   = (int*)w;                 w += 256 * 4;
    float* dinv   = (float*)w;               w += NPAD * 4;
    int*   csr    = (int*)w;                 w += (size_t)E * 4;
    float* hregion= (float*)w;               w += (size_t)n * 64 * 4; // 38.4 MB
    unsigned short* xb = (unsigned short*)w; w += (size_t)n * 64 * 2; // 19.2 MB
    unsigned short* w1b = (unsigned short*)w; w += 98304 * 2;
    unsigned short* w1p = (unsigned short*)w; w += 3072 * 2;
    unsigned short* w2p = (unsigned short*)w; w += 1024 * 2;
    unsigned short* wcb = (unsigned short*)w; w += 4096 * 2;
    // hregion phases:
    //   phase 1: hb = [0..19.2MB) bf16 h*dinv ; sb = [19.2..38.4MB) bf16 state
    //   phase 2: y1b = [0..12.8MB) bf16 y1 (hb dead) ; xgb = [12.8..13.6MB) bf16 [B][16]
    unsigned short* hb  = (unsigned short*)hregion;
    unsigned short* sb  = (unsigned short*)(hregion + 4800000);
    unsigned short* y1b = (unsigned short*)hregion;
    unsigned short* xgb = (unsigned short*)(hregion + 3200000);

    float* out    = (float*)d_out;
    float* regptr = out + n;

    hipMemsetAsync(counts, 0, NPAD * 4, stream);
    hipMemsetAsync(regptr, 0, 4, stream);

    degree_kernel<<<(E + 255) / 256, 256, 0, stream>>>(dst, counts, rank, E);
    scan_block<<<NSCAN, 256, 0, stream>>>(counts, rowptr, bsum, n);
    scan_sums<<<1, 256, 0, stream>>>(bsum, NSCAN);
    scan_add<<<(n + 256) / 256, 256, 0, stream>>>(rowptr, bsum, counts, dinv, n, E);
    fill_csr<<<(E + 255) / 256, 256, 0, stream>>>(src, dst, rowptr, rank, csr, E);
    prep_cast<<<(NSTATE_V8 + 106496 + 255) / 256, 256, 0, stream>>>(
        state, convW, gW1, l1W, l2W, sb, wcb, w1b, w1p, w2p);
    conv_mfma<<<(9375 + 3) / 4, 256, 0, stream>>>(sb, wcb, dinv, hb, n);
    gather_fused<<<(n + 3) / 4, 256, 0, stream>>>(rowptr, csr, hb, dinv, convb, state, xb, n);
    global_gemm1_mfma<<<391 * 2, 256, 0, stream>>>(sb, w1b, gb1, y1b, B);
    global_gemm2<<<(B * 64 + 255) / 256, 256, 0, stream>>>(y1b, gW2, gb2, xgb, B);
    mlp_mfma<<<(3125 + 3) / 4, 256, 0, stream>>>(xb, xgb, w1p, w2p, l1b, l2b, l3W, l3b,
                                                 out, regptr, n);
}

// Round 10
// 359.039 us; speedup vs baseline: 2.6363x; 1.0706x over previous
//
#include <hip/hip_runtime.h>
#include <math.h>

#define N_NODES 150000
#define N_EDGES 1200000
#define C 64
#define ACT 6
#define B_ROWS 25000   // N/ACT
#define GLOB 256
#define GOUT 10
#define H 32

#define NPAD 150016            // N rounded up (alignment)
#define SCAN_CHUNK 1024
#define NSCAN 147              // ceil(150000/1024)

typedef short bf16x8 __attribute__((ext_vector_type(8)));
typedef float f32x4v __attribute__((ext_vector_type(4)));

// ---- bf16 helpers ----
__device__ __forceinline__ unsigned short f2bf(float f) {
    unsigned int u = __builtin_bit_cast(unsigned int, f);
    unsigned int r = (u + 0x7fffu + ((u >> 16) & 1u)) >> 16;   // RTNE
    return (unsigned short)r;
}
__device__ __forceinline__ unsigned int pack2bf(float a, float b) {
    return (unsigned int)f2bf(a) | ((unsigned int)f2bf(b) << 16);
}
__device__ __forceinline__ float bflo(unsigned int u) {
    return __builtin_bit_cast(float, u << 16);
}
__device__ __forceinline__ float bfhi(unsigned int u) {
    return __builtin_bit_cast(float, u & 0xffff0000u);
}
__device__ __forceinline__ float bf1(unsigned short us) {
    return __builtin_bit_cast(float, ((unsigned int)us) << 16);
}

// ---------------- degree histogram + per-edge rank ----------------
__global__ void degree_kernel(const int* __restrict__ dst, int* __restrict__ counts,
                              int* __restrict__ rank, int E) {
    int e = blockIdx.x * blockDim.x + threadIdx.x;
    if (e < E) rank[e] = atomicAdd(&counts[dst[e]], 1);
}

// ---------------- prefix scan (3 kernels) ----------------
__global__ void scan_block(const int* __restrict__ counts, int* __restrict__ rowptr,
                           int* __restrict__ bsum, int n) {
    __shared__ int lds[256];
    int base = blockIdx.x * SCAN_CHUNK;
    int t = threadIdx.x;
    int v[4]; int s = 0;
    #pragma unroll
    for (int i = 0; i < 4; ++i) {
        int idx = base + t * 4 + i;
        v[i] = (idx < n) ? counts[idx] : 0;
        s += v[i];
    }
    lds[t] = s; __syncthreads();
    for (int off = 1; off < 256; off <<= 1) {
        int x = (t >= off) ? lds[t - off] : 0;
        __syncthreads();
        lds[t] += x;
        __syncthreads();
    }
    int excl = lds[t] - s;
    if (t == 255) bsum[blockIdx.x] = lds[255];
    int run = excl;
    #pragma unroll
    for (int i = 0; i < 4; ++i) {
        int idx = base + t * 4 + i;
        if (idx < n) rowptr[idx] = run;
        run += v[i];
    }
}

__global__ void scan_sums(int* __restrict__ bsum, int nb) {
    __shared__ int lds[256];
    int t = threadIdx.x;
    int v = (t < nb) ? bsum[t] : 0;
    lds[t] = v; __syncthreads();
    for (int off = 1; off < 256; off <<= 1) {
        int x = (t >= off) ? lds[t - off] : 0;
        __syncthreads();
        lds[t] += x;
        __syncthreads();
    }
    if (t < nb) bsum[t] = lds[t] - v;   // exclusive
}

__global__ void scan_add(int* __restrict__ rowptr, const int* __restrict__ bsum,
                         const int* __restrict__ counts, float* __restrict__ dinv,
                         int n, int E) {
    int i = blockIdx.x * blockDim.x + threadIdx.x;
    if (i < n) {
        rowptr[i] += bsum[i >> 10];
        dinv[i] = rsqrtf((float)counts[i] + 1.0f);
    }
    if (i == n) rowptr[n] = E;
}

// ---------------- CSR fill (atomic-free: rank precomputed) ----------------
__global__ void fill_csr(const int* __restrict__ src, const int* __restrict__ dst,
                         const int* __restrict__ rowptr, const int* __restrict__ rank,
                         int* __restrict__ csr, int E) {
    int e = blockIdx.x * blockDim.x + threadIdx.x;
    if (e >= E) return;
    int d = dst[e];
    csr[rowptr[d] + rank[e]] = src[e];
}

// ---------------- prep: cast state + all weights to bf16 ----------------
#define NSTATE_V8 1200000      // 9.6M / 8
__global__ void prep_cast(const float* __restrict__ state, const float* __restrict__ convW,
                          const float* __restrict__ gW1, const float* __restrict__ l1W,
                          const float* __restrict__ l2W,
                          unsigned short* __restrict__ sb,    // [N*64]
                          unsigned short* __restrict__ wcb,   // [64*64]
                          unsigned short* __restrict__ w1b,   // [256*384]
                          unsigned short* __restrict__ w1p,   // [32*96] zero-padded
                          unsigned short* __restrict__ w2p) { // [32*32]
    int i = blockIdx.x * blockDim.x + threadIdx.x;
    if (i < NSTATE_V8) {
        const float4* p = (const float4*)(state + (size_t)i * 8);
        float4 a = p[0], b = p[1];
        uint4 o = make_uint4(pack2bf(a.x, a.y), pack2bf(a.z, a.w),
                             pack2bf(b.x, b.y), pack2bf(b.z, b.w));
        *(uint4*)(sb + (size_t)i * 8) = o;
        return;
    }
    int j = i - NSTATE_V8;
    if (j < 4096) {
        wcb[j] = f2bf(convW[j]);
    } else if (j < 4096 + 98304) {
        int k = j - 4096;
        w1b[k] = f2bf(gW1[k]);
    } else if (j < 4096 + 98304 + 3072) {
        int k = j - 4096 - 98304;
        int r = k / 96, c = k - r * 96;
        w1p[k] = (c < 74) ? f2bf(l1W[r * 74 + c]) : 0;
    } else if (j < 4096 + 98304 + 3072 + 1024) {
        int k = j - 4096 - 98304 - 3072;
        w2p[k] = f2bf(l2W[k]);
    }
}

// ---------------- conv via MFMA: hb = bf16((sb @ Wc^T) * dinv), one wave = 16 rows ----------------
__global__ __launch_bounds__(256) void conv_mfma(
        const unsigned short* __restrict__ sb,    // [N][64] bf16
        const unsigned short* __restrict__ wcb,   // [64][64] bf16
        const float* __restrict__ dinv,
        unsigned short* __restrict__ hb, int n) {
    int wid  = threadIdx.x >> 6;
    int lane = threadIdx.x & 63;
    int quad = lane >> 4;
    int lm   = lane & 15;
    int row0 = (blockIdx.x * 4 + wid) * 16;
    if (row0 >= n) return;                        // n = 150000 = 16*9375: no partial waves

    const unsigned short* ap = sb + (size_t)(row0 + lm) * 64 + quad * 8;
    bf16x8 a0 = *(const bf16x8*)ap;
    bf16x8 a1 = *(const bf16x8*)(ap + 32);

    f32x4v acc[4];
    #pragma unroll
    for (int t = 0; t < 4; ++t) acc[t] = (f32x4v){0.f, 0.f, 0.f, 0.f};
    #pragma unroll
    for (int t = 0; t < 4; ++t) {
        const unsigned short* bp = wcb + (size_t)(t * 16 + lm) * 64 + quad * 8;
        bf16x8 b0 = *(const bf16x8*)bp;
        bf16x8 b1 = *(const bf16x8*)(bp + 32);
        acc[t] = __builtin_amdgcn_mfma_f32_16x16x32_bf16(a0, b0, acc[t], 0, 0, 0);
        acc[t] = __builtin_amdgcn_mfma_f32_16x16x32_bf16(a1, b1, acc[t], 0, 0, 0);
    }

    float dv[4];
    #pragma unroll
    for (int r = 0; r < 4; ++r) dv[r] = dinv[row0 + quad * 4 + r];
    #pragma unroll
    for (int t = 0; t < 4; ++t) {
        #pragma unroll
        for (int r = 0; r < 4; ++r) {
            int m = row0 + quad * 4 + r;
            hb[(size_t)m * 64 + t * 16 + lm] = f2bf(acc[t][r] * dv[r]);
        }
    }
}

// ---------------- gather: 8 nodes/wave, 8 lanes/node, no cross-lane reduction ----------------
__global__ void gather_fused(const int* __restrict__ rowptr, const int* __restrict__ csr,
                             const unsigned short* __restrict__ hb, const float* __restrict__ dinv,
                             const float* __restrict__ convb, const unsigned short* __restrict__ sb,
                             unsigned short* __restrict__ xb, int n, int E) {
    int wid  = threadIdx.x >> 6;
    int lane = threadIdx.x & 63;
    int g = lane >> 3;        // node slot within wave (0..7)
    int l = lane & 7;         // channel octet (8 bf16 per lane)
    int node = (blockIdx.x * 4 + wid) * 8 + g;
    bool valid = node < n;
    int nodec = valid ? node : (n - 1);
    int beg = rowptr[nodec], end = rowptr[nodec + 1];
    int deg = valid ? (end - beg) : 0;

    float acc[8] = {0.f, 0.f, 0.f, 0.f, 0.f, 0.f, 0.f, 0.f};
    int pidx = beg + l; if (pidx > E - 1) pidx = E - 1;
    int eid = csr[pidx];                        // prefetch up to 8 edge ids per node
    for (int i = 0; i < deg; ++i) {
        if ((i & 7) == 0 && i != 0) {
            int q = beg + i + l; if (q > E - 1) q = E - 1;
            eid = csr[q];
        }
        int s = __shfl(eid, (g << 3) + (i & 7), 64);   // broadcast within group
        uint4 u = *(const uint4*)(hb + (size_t)s * 64 + l * 8);
        acc[0] += bflo(u.x); acc[1] += bfhi(u.x);
        acc[2] += bflo(u.y); acc[3] += bfhi(u.y);
        acc[4] += bflo(u.z); acc[5] += bfhi(u.z);
        acc[6] += bflo(u.w); acc[7] += bfhi(u.w);
    }

    if (valid) {
        float dd = dinv[node];
        uint4 us = *(const uint4*)(hb + (size_t)node * 64 + l * 8);
        uint4 uv = *(const uint4*)(sb + (size_t)node * 64 + l * 8);
        float4 c0 = *(const float4*)(convb + l * 8);
        float4 c1 = *(const float4*)(convb + l * 8 + 4);
        float sf[8] = {bflo(us.x), bfhi(us.x), bflo(us.y), bfhi(us.y),
                       bflo(us.z), bfhi(us.z), bflo(us.w), bfhi(us.w)};
        float sv[8] = {bflo(uv.x), bfhi(uv.x), bflo(uv.y), bfhi(uv.y),
                       bflo(uv.z), bfhi(uv.z), bflo(uv.w), bfhi(uv.w)};
        float cb[8] = {c0.x, c0.y, c0.z, c0.w, c1.x, c1.y, c1.z, c1.w};
        float o[8];
        #pragma unroll
        for (int j = 0; j < 8; ++j) {
            float v = dd * (acc[j] + sf[j]) + cb[j];
            v = (v > 0.f) ? v : 0.f;
            o[j] = v + sv[j];
        }
        uint2 p0 = make_uint2(pack2bf(o[0], o[1]), pack2bf(o[2], o[3]));
        uint2 p1 = make_uint2(pack2bf(o[4], o[5]), pack2bf(o[6], o[7]));
        unsigned short* xp = xb + (size_t)node * 64 + l * 8;
        *(uint2*)xp       = p0;
        *(uint2*)(xp + 4) = p1;
    }
}

// ---------------- global branch layer 1 (MFMA bf16, LDS-free) ----------------
__global__ __launch_bounds__(256) void global_gemm1_mfma(
        const unsigned short* __restrict__ Ab,   // [25000][384] bf16
        const unsigned short* __restrict__ Wb,   // [256][384] bf16
        const float* __restrict__ bias,          // gb1
        unsigned short* __restrict__ y1b, int M) {
    int wave = threadIdx.x >> 6;
    int lane = threadIdx.x & 63;
    int quad = lane >> 4;
    int lm   = lane & 15;
    int mtile = blockIdx.x >> 1;
    int nhalf = blockIdx.x & 1;
    int row0 = mtile * 64 + wave * 16;
    int col0 = nhalf * 128;

    int arow = row0 + lm;
    if (arow >= M) arow = M - 1;             // clamp; stores predicated
    const unsigned short* ap = Ab + (size_t)arow * 384 + quad * 8;
    const unsigned short* bp = Wb + (size_t)(col0 + lm) * 384 + quad * 8;

    f32x4v acc[8];
    #pragma unroll
    for (int t = 0; t < 8; ++t) acc[t] = (f32x4v){0.f, 0.f, 0.f, 0.f};

    #pragma unroll
    for (int ks = 0; ks < 12; ++ks) {
        bf16x8 af = *(const bf16x8*)(ap + ks * 32);
        #pragma unroll
        for (int t = 0; t < 8; ++t) {
            bf16x8 bfr = *(const bf16x8*)(bp + (size_t)t * 16 * 384 + ks * 32);
            acc[t] = __builtin_amdgcn_mfma_f32_16x16x32_bf16(af, bfr, acc[t], 0, 0, 0);
        }
    }

    #pragma unroll
    for (int t = 0; t < 8; ++t) {
        int nn = col0 + t * 16 + lm;
        float bv = bias[nn];
        #pragma unroll
        for (int r = 0; r < 4; ++r) {
            int m = row0 + quad * 4 + r;
            if (m < M) {
                float v = acc[t][r] + bv;
                v = (v > 0.f) ? v : 0.01f * v;
                y1b[(size_t)m * 256 + nn] = f2bf(v);
            }
        }
    }
}

// ---------------- global branch layer 2: xgb = bf16 [B][16] (zero-padded) ----------------
__global__ void global_gemm2(const unsigned short* __restrict__ y1b, const float* __restrict__ W2,
                             const float* __restrict__ b2, unsigned short* __restrict__ xgb, int B) {
    int wave = (blockIdx.x * blockDim.x + threadIdx.x) >> 6;
    int lane = threadIdx.x & 63;
    if (wave >= B) return;
    const unsigned short* yr = y1b + (size_t)wave * 256;
    float yv[4];
    #pragma unroll
    for (int j = 0; j < 4; ++j) yv[j] = bf1(yr[lane + 64 * j]);
    float res[10];
    #pragma unroll
    for (int o = 0; o < 10; ++o) {
        const float* w = W2 + o * 256;
        float p = 0.f;
        #pragma unroll
        for (int j = 0; j < 4; ++j) p += yv[j] * w[lane + 64 * j];
        #pragma unroll
        for (int off = 32; off > 0; off >>= 1) p += __shfl_down(p, off, 64);
        res[o] = p;
    }
    if (lane == 0) {
        float v[10];
        #pragma unroll
        for (int o = 0; o < 10; ++o) {
            float t = res[o] + b2[o];
            v[o] = (t > 0.f) ? t : 0.01f * t;
        }
        uint4 pa = make_uint4(pack2bf(v[0], v[1]), pack2bf(v[2], v[3]),
                              pack2bf(v[4], v[5]), pack2bf(v[6], v[7]));
        uint4 pb = make_uint4(pack2bf(v[8], v[9]), 0u, 0u, 0u);
        unsigned short* xp = xgb + (size_t)wave * 16;
        *(uint4*)xp       = pa;
        *(uint4*)(xp + 8) = pb;
    }
}

// ---------------- final MLP via MFMA: one wave = 48 nodes (3 m-tiles) ----------------
#define Y1_STRIDE 40
__global__ __launch_bounds__(256) void mlp_mfma(
        const unsigned short* __restrict__ xb,    // [N][64] bf16
        const unsigned short* __restrict__ xgb,   // [B][16] bf16 zero-padded
        const unsigned short* __restrict__ w1p,   // [32][96] bf16 zero-padded
        const unsigned short* __restrict__ w2p,   // [32][32] bf16
        const float* __restrict__ l1b, const float* __restrict__ l2b,
        const float* __restrict__ l3W, const float* __restrict__ l3b,
        float* __restrict__ out, float* __restrict__ reg_out, int n) {
    __shared__ unsigned short y1L[4][16 * Y1_STRIDE];
    __shared__ float concL[4][48];

    int wid  = threadIdx.x >> 6;
    int lane = threadIdx.x & 63;
    int quad = lane >> 4;
    int lm   = lane & 15;
    int base = (blockIdx.x * 4 + wid) * 48;
    if (base >= n) return;                        // wave-uniform; no __syncthreads below

    bf16x8 b1[2][3];
    #pragma unroll
    for (int t2 = 0; t2 < 2; ++t2)
        #pragma unroll
        for (int ks = 0; ks < 3; ++ks)
            b1[t2][ks] = *(const bf16x8*)(w1p + (t2 * 16 + lm) * 96 + ks * 32 + quad * 8);
    bf16x8 b2f[2];
    #pragma unroll
    for (int t2 = 0; t2 < 2; ++t2)
        b2f[t2] = *(const bf16x8*)(w2p + (t2 * 16 + lm) * 32 + quad * 8);

    float bias1a = l1b[lm],      bias1b = l1b[16 + lm];
    float bias2a = l2b[lm],      bias2b = l2b[16 + lm];
    float w3a    = l3W[lm],      w3b    = l3W[16 + lm];
    float b3     = l3b[0];

    unsigned short* myY = y1L[wid];
    float* myC = concL[wid];

    for (int t = 0; t < 3; ++t) {
        int node = base + t * 16 + lm;
        bf16x8 a0 = *(const bf16x8*)(xb + (size_t)node * 64 + quad * 8);
        bf16x8 a1 = *(const bf16x8*)(xb + (size_t)node * 64 + 32 + quad * 8);
        bf16x8 a2 = (bf16x8){0, 0, 0, 0, 0, 0, 0, 0};
        if (quad < 2) a2 = *(const bf16x8*)(xgb + (size_t)(node / 6) * 16 + quad * 8);

        f32x4v acc0 = (f32x4v){0.f, 0.f, 0.f, 0.f};
        f32x4v acc1 = acc0;
        acc0 = __builtin_amdgcn_mfma_f32_16x16x32_bf16(a0, b1[0][0], acc0, 0, 0, 0);
        acc1 = __builtin_amdgcn_mfma_f32_16x16x32_bf16(a0, b1[1][0], acc1, 0, 0, 0);
        acc0 = __builtin_amdgcn_mfma_f32_16x16x32_bf16(a1, b1[0][1], acc0, 0, 0, 0);
        acc1 = __builtin_amdgcn_mfma_f32_16x16x32_bf16(a1, b1[1][1], acc1, 0, 0, 0);
        acc0 = __builtin_amdgcn_mfma_f32_16x16x32_bf16(a2, b1[0][2], acc0, 0, 0, 0);
        acc1 = __builtin_amdgcn_mfma_f32_16x16x32_bf16(a2, b1[1][2], acc1, 0, 0, 0);

        #pragma unroll
        for (int r = 0; r < 4; ++r) {
            float v0 = acc0[r] + bias1a;
            float v1 = acc1[r] + bias1b;
            v0 = (v0 > 0.f) ? v0 : 0.01f * v0;
            v1 = (v1 > 0.f) ? v1 : 0.01f * v1;
            myY[(quad * 4 + r) * Y1_STRIDE + lm]      = f2bf(v0);
            myY[(quad * 4 + r) * Y1_STRIDE + 16 + lm] = f2bf(v1);
        }
        bf16x8 a2f = *(const bf16x8*)(myY + lm * Y1_STRIDE + quad * 8);
        f32x4v acc20 = (f32x4v){0.f, 0.f, 0.f, 0.f};
        f32x4v acc21 = acc20;
        acc20 = __builtin_amdgcn_mfma_f32_16x16x32_bf16(a2f, b2f[0], acc20, 0, 0, 0);
        acc21 = __builtin_amdgcn_mfma_f32_16x16x32_bf16(a2f, b2f[1], acc21, 0, 0, 0);

        float part[4];
        #pragma unroll
        for (int r = 0; r < 4; ++r) {
            float y2a = acc20[r] + bias2a;
            float y2b = acc21[r] + bias2b;
            y2a = (y2a > 0.f) ? y2a : 0.01f * y2a;
            y2b = (y2b > 0.f) ? y2b : 0.01f * y2b;
            part[r] = y2a * w3a + y2b * w3b;
        }
        #pragma unroll
        for (int st = 1; st < 16; st <<= 1) {
            #pragma unroll
            for (int r = 0; r < 4; ++r) part[r] += __shfl_xor(part[r], st, 64);
        }
        if (lm == 0) {
            #pragma unroll
            for (int r = 0; r < 4; ++r) {
                float a3 = part[r] + b3;
                myC[t * 16 + quad * 4 + r] = (a3 > 20.f) ? a3 : log1pf(expf(a3));
            }
        }
    }

    float myabs = 0.f;
    if (lane < 48) {
        int g0 = (lane / 6) * 6;
        float s = 0.f;
        #pragma unroll
        for (int i = 0; i < 6; ++i) s += myC[g0 + i];
        float c = myC[lane];
        out[base + lane] = c / (s + 1e-20f);
        myabs = fabsf(c);
    }
    #pragma unroll
    for (int off = 32; off > 0; off >>= 1) myabs += __shfl_down(myabs, off, 64);
    if (lane == 0) atomicAdd(reg_out, myabs * (1.0f / (float)N_NODES));
}

extern "C" void kernel_launch(void* const* d_in, const int* in_sizes, int n_in,
                              void* d_out, int out_size, void* d_ws, size_t ws_size,
                              hipStream_t stream) {
    const float* state = (const float*)d_in[0];
    const int*   ei    = (const int*)d_in[1];
    const float* convW = (const float*)d_in[2];
    const float* convb = (const float*)d_in[3];
    const float* gW1   = (const float*)d_in[4];
    const float* gb1   = (const float*)d_in[5];
    const float* gW2   = (const float*)d_in[6];
    const float* gb2   = (const float*)d_in[7];
    const float* l1W   = (const float*)d_in[8];
    const float* l1b   = (const float*)d_in[9];
    const float* l2W   = (const float*)d_in[10];
    const float* l2b   = (const float*)d_in[11];
    const float* l3W   = (const float*)d_in[12];
    const float* l3b   = (const float*)d_in[13];

    const int n = N_NODES, E = N_EDGES, B = B_ROWS;
    const int* src = ei;
    const int* dst = ei + E;

    // ---- workspace layout ----
    char* w = (char*)d_ws;
    int*   counts = (int*)w;                 w += NPAD * 4;
    int*   rank   = (int*)w;                 w += (size_t)E * 4;
    int*   rowptr = (int*)w;                 w += NPAD * 4;
    int*   bsum   = (int*)w;                 w += 256 * 4;
    float* dinv   = (float*)w;               w += NPAD * 4;
    int*   csr    = (int*)w;                 w += (size_t)E * 4;
    float* hregion= (float*)w;               w += (size_t)n * 64 * 4; // 38.4 MB
    unsigned short* xb = (unsigned short*)w; w += (size_t)n * 64 * 2; // 19.2 MB
    unsigned short* w1b = (unsigned short*)w; w += 98304 * 2;
    unsigned short* w1p = (unsigned short*)w; w += 3072 * 2;
    unsigned short* w2p = (unsigned short*)w; w += 1024 * 2;
    unsigned short* wcb = (unsigned short*)w; w += 4096 * 2;
    // hregion phases:
    //   phase 1: hb = [0..19.2MB) bf16 h*dinv ; sb = [19.2..38.4MB) bf16 state
    //   phase 2: y1b = [0..12.8MB) bf16 y1 (hb dead) ; xgb = [12.8..13.6MB) bf16 [B][16]
    unsigned short* hb  = (unsigned short*)hregion;
    unsigned short* sb  = (unsigned short*)(hregion + 4800000);
    unsigned short* y1b = (unsigned short*)hregion;
    unsigned short* xgb = (unsigned short*)(hregion + 3200000);

    float* out    = (float*)d_out;
    float* regptr = out + n;

    hipMemsetAsync(counts, 0, NPAD * 4, stream);
    hipMemsetAsync(regptr, 0, 4, stream);

    degree_kernel<<<(E + 255) / 256, 256, 0, stream>>>(dst, counts, rank, E);
    scan_block<<<NSCAN, 256, 0, stream>>>(counts, rowptr, bsum, n);
    scan_sums<<<1, 256, 0, stream>>>(bsum, NSCAN);
    scan_add<<<(n + 256) / 256, 256, 0, stream>>>(rowptr, bsum, counts, dinv, n, E);
    fill_csr<<<(E + 255) / 256, 256, 0, stream>>>(src, dst, rowptr, rank, csr, E);
    prep_cast<<<(NSTATE_V8 + 106496 + 255) / 256, 256, 0, stream>>>(
        state, convW, gW1, l1W, l2W, sb, wcb, w1b, w1p, w2p);
    conv_mfma<<<(9375 + 3) / 4, 256, 0, stream>>>(sb, wcb, dinv, hb, n);
    gather_fused<<<(n + 31) / 32, 256, 0, stream>>>(rowptr, csr, hb, dinv, convb, sb, xb, n, E);
    global_gemm1_mfma<<<391 * 2, 256, 0, stream>>>(sb, w1b, gb1, y1b, B);
    global_gemm2<<<(B * 64 + 255) / 256, 256, 0, stream>>>(y1b, gW2, gb2, xgb, B);
    mlp_mfma<<<(3125 + 3) / 4, 256, 0, stream>>>(xb, xgb, w1p, w2p, l1b, l2b, l3W, l3b,
                                                 out, regptr, n);
}

// Round 11
// 323.551 us; speedup vs baseline: 2.9255x; 1.1097x over previous
//
#include <hip/hip_runtime.h>
#include <math.h>

#define N_NODES 150000
#define N_EDGES 1200000
#define C 64
#define ACT 6
#define B_ROWS 25000   // N/ACT
#define GLOB 256
#define GOUT 10
#define H 32

#define NPAD 150016            // N rounded up (alignment)
#define SCAN_CHUNK 1024
#define NSCAN 147              // ceil(150000/1024)
#define MLP_BLOCKS 1563        // ceil(150000/96)

typedef short bf16x8 __attribute__((ext_vector_type(8)));
typedef float f32x4v __attribute__((ext_vector_type(4)));

// ---- bf16 helpers ----
__device__ __forceinline__ unsigned short f2bf(float f) {
    unsigned int u = __builtin_bit_cast(unsigned int, f);
    unsigned int r = (u + 0x7fffu + ((u >> 16) & 1u)) >> 16;   // RTNE
    return (unsigned short)r;
}
__device__ __forceinline__ unsigned int pack2bf(float a, float b) {
    return (unsigned int)f2bf(a) | ((unsigned int)f2bf(b) << 16);
}
__device__ __forceinline__ float bflo(unsigned int u) {
    return __builtin_bit_cast(float, u << 16);
}
__device__ __forceinline__ float bfhi(unsigned int u) {
    return __builtin_bit_cast(float, u & 0xffff0000u);
}
__device__ __forceinline__ float bf1(unsigned short us) {
    return __builtin_bit_cast(float, ((unsigned int)us) << 16);
}

// ---------------- degree histogram + per-edge rank ----------------
__global__ void degree_kernel(const int* __restrict__ dst, int* __restrict__ counts,
                              int* __restrict__ rank, int E) {
    int e = blockIdx.x * blockDim.x + threadIdx.x;
    if (e < E) rank[e] = atomicAdd(&counts[dst[e]], 1);
}

// ---------------- prefix scan (3 kernels) ----------------
__global__ void scan_block(const int* __restrict__ counts, int* __restrict__ rowptr,
                           int* __restrict__ bsum, int n) {
    __shared__ int lds[256];
    int base = blockIdx.x * SCAN_CHUNK;
    int t = threadIdx.x;
    int v[4]; int s = 0;
    #pragma unroll
    for (int i = 0; i < 4; ++i) {
        int idx = base + t * 4 + i;
        v[i] = (idx < n) ? counts[idx] : 0;
        s += v[i];
    }
    lds[t] = s; __syncthreads();
    for (int off = 1; off < 256; off <<= 1) {
        int x = (t >= off) ? lds[t - off] : 0;
        __syncthreads();
        lds[t] += x;
        __syncthreads();
    }
    int excl = lds[t] - s;
    if (t == 255) bsum[blockIdx.x] = lds[255];
    int run = excl;
    #pragma unroll
    for (int i = 0; i < 4; ++i) {
        int idx = base + t * 4 + i;
        if (idx < n) rowptr[idx] = run;
        run += v[i];
    }
}

__global__ void scan_sums(int* __restrict__ bsum, int nb) {
    __shared__ int lds[256];
    int t = threadIdx.x;
    int v = (t < nb) ? bsum[t] : 0;
    lds[t] = v; __syncthreads();
    for (int off = 1; off < 256; off <<= 1) {
        int x = (t >= off) ? lds[t - off] : 0;
        __syncthreads();
        lds[t] += x;
        __syncthreads();
    }
    if (t < nb) bsum[t] = lds[t] - v;   // exclusive
}

__global__ void scan_add(int* __restrict__ rowptr, const int* __restrict__ bsum,
                         const int* __restrict__ counts, float* __restrict__ dinv,
                         int n, int E) {
    int i = blockIdx.x * blockDim.x + threadIdx.x;
    if (i < n) {
        rowptr[i] += bsum[i >> 10];
        dinv[i] = rsqrtf((float)counts[i] + 1.0f);
    }
    if (i == n) rowptr[n] = E;
}

// ---------------- CSR fill (atomic-free: rank precomputed) ----------------
__global__ void fill_csr(const int* __restrict__ src, const int* __restrict__ dst,
                         const int* __restrict__ rowptr, const int* __restrict__ rank,
                         int* __restrict__ csr, int E) {
    int e = blockIdx.x * blockDim.x + threadIdx.x;
    if (e >= E) return;
    int d = dst[e];
    csr[rowptr[d] + rank[e]] = src[e];
}

// ---------------- prep: cast state + all weights to bf16 ----------------
#define NSTATE_V8 1200000      // 9.6M / 8
__global__ void prep_cast(const float* __restrict__ state, const float* __restrict__ convW,
                          const float* __restrict__ gW1, const float* __restrict__ l1W,
                          const float* __restrict__ l2W,
                          unsigned short* __restrict__ sb,    // [N*64]
                          unsigned short* __restrict__ wcb,   // [64*64]
                          unsigned short* __restrict__ w1b,   // [256*384]
                          unsigned short* __restrict__ w1p,   // [32*96] zero-padded
                          unsigned short* __restrict__ w2p) { // [32*32]
    int i = blockIdx.x * blockDim.x + threadIdx.x;
    if (i < NSTATE_V8) {
        const float4* p = (const float4*)(state + (size_t)i * 8);
        float4 a = p[0], b = p[1];
        uint4 o = make_uint4(pack2bf(a.x, a.y), pack2bf(a.z, a.w),
                             pack2bf(b.x, b.y), pack2bf(b.z, b.w));
        *(uint4*)(sb + (size_t)i * 8) = o;
        return;
    }
    int j = i - NSTATE_V8;
    if (j < 4096) {
        wcb[j] = f2bf(convW[j]);
    } else if (j < 4096 + 98304) {
        int k = j - 4096;
        w1b[k] = f2bf(gW1[k]);
    } else if (j < 4096 + 98304 + 3072) {
        int k = j - 4096 - 98304;
        int r = k / 96, c = k - r * 96;
        w1p[k] = (c < 74) ? f2bf(l1W[r * 74 + c]) : 0;
    } else if (j < 4096 + 98304 + 3072 + 1024) {
        int k = j - 4096 - 98304 - 3072;
        w2p[k] = f2bf(l2W[k]);
    }
}

// ---------------- conv via MFMA: hb = bf16((sb @ Wc^T) * dinv), one wave = 16 rows ----------------
__global__ __launch_bounds__(256) void conv_mfma(
        const unsigned short* __restrict__ sb,    // [N][64] bf16
        const unsigned short* __restrict__ wcb,   // [64][64] bf16
        const float* __restrict__ dinv,
        unsigned short* __restrict__ hb, int n) {
    int wid  = threadIdx.x >> 6;
    int lane = threadIdx.x & 63;
    int quad = lane >> 4;
    int lm   = lane & 15;
    int row0 = (blockIdx.x * 4 + wid) * 16;
    if (row0 >= n) return;                        // n = 150000 = 16*9375: no partial waves

    const unsigned short* ap = sb + (size_t)(row0 + lm) * 64 + quad * 8;
    bf16x8 a0 = *(const bf16x8*)ap;
    bf16x8 a1 = *(const bf16x8*)(ap + 32);

    f32x4v acc[4];
    #pragma unroll
    for (int t = 0; t < 4; ++t) acc[t] = (f32x4v){0.f, 0.f, 0.f, 0.f};
    #pragma unroll
    for (int t = 0; t < 4; ++t) {
        const unsigned short* bp = wcb + (size_t)(t * 16 + lm) * 64 + quad * 8;
        bf16x8 b0 = *(const bf16x8*)bp;
        bf16x8 b1 = *(const bf16x8*)(bp + 32);
        acc[t] = __builtin_amdgcn_mfma_f32_16x16x32_bf16(a0, b0, acc[t], 0, 0, 0);
        acc[t] = __builtin_amdgcn_mfma_f32_16x16x32_bf16(a1, b1, acc[t], 0, 0, 0);
    }

    float dv[4];
    #pragma unroll
    for (int r = 0; r < 4; ++r) dv[r] = dinv[row0 + quad * 4 + r];
    #pragma unroll
    for (int t = 0; t < 4; ++t) {
        #pragma unroll
        for (int r = 0; r < 4; ++r) {
            int m = row0 + quad * 4 + r;
            hb[(size_t)m * 64 + t * 16 + lm] = f2bf(acc[t][r] * dv[r]);
        }
    }
}

// ---------------- gather: 8 nodes/wave, 8 lanes/node, no cross-lane reduction ----------------
__global__ void gather_fused(const int* __restrict__ rowptr, const int* __restrict__ csr,
                             const unsigned short* __restrict__ hb, const float* __restrict__ dinv,
                             const float* __restrict__ convb, const unsigned short* __restrict__ sb,
                             unsigned short* __restrict__ xb, int n, int E) {
    int wid  = threadIdx.x >> 6;
    int lane = threadIdx.x & 63;
    int g = lane >> 3;        // node slot within wave (0..7)
    int l = lane & 7;         // channel octet (8 bf16 per lane)
    int node = (blockIdx.x * 4 + wid) * 8 + g;
    bool valid = node < n;
    int nodec = valid ? node : (n - 1);
    int beg = rowptr[nodec], end = rowptr[nodec + 1];
    int deg = valid ? (end - beg) : 0;

    float acc[8] = {0.f, 0.f, 0.f, 0.f, 0.f, 0.f, 0.f, 0.f};
    int pidx = beg + l; if (pidx > E - 1) pidx = E - 1;
    int eid = csr[pidx];                        // prefetch up to 8 edge ids per node
    for (int i = 0; i < deg; ++i) {
        if ((i & 7) == 0 && i != 0) {
            int q = beg + i + l; if (q > E - 1) q = E - 1;
            eid = csr[q];
        }
        int s = __shfl(eid, (g << 3) + (i & 7), 64);   // broadcast within group
        uint4 u = *(const uint4*)(hb + (size_t)s * 64 + l * 8);
        acc[0] += bflo(u.x); acc[1] += bfhi(u.x);
        acc[2] += bflo(u.y); acc[3] += bfhi(u.y);
        acc[4] += bflo(u.z); acc[5] += bfhi(u.z);
        acc[6] += bflo(u.w); acc[7] += bfhi(u.w);
    }

    if (valid) {
        float dd = dinv[node];
        uint4 us = *(const uint4*)(hb + (size_t)node * 64 + l * 8);
        uint4 uv = *(const uint4*)(sb + (size_t)node * 64 + l * 8);
        float4 c0 = *(const float4*)(convb + l * 8);
        float4 c1 = *(const float4*)(convb + l * 8 + 4);
        float sf[8] = {bflo(us.x), bfhi(us.x), bflo(us.y), bfhi(us.y),
                       bflo(us.z), bfhi(us.z), bflo(us.w), bfhi(us.w)};
        float sv[8] = {bflo(uv.x), bfhi(uv.x), bflo(uv.y), bfhi(uv.y),
                       bflo(uv.z), bfhi(uv.z), bflo(uv.w), bfhi(uv.w)};
        float cb[8] = {c0.x, c0.y, c0.z, c0.w, c1.x, c1.y, c1.z, c1.w};
        float o[8];
        #pragma unroll
        for (int j = 0; j < 8; ++j) {
            float v = dd * (acc[j] + sf[j]) + cb[j];
            v = (v > 0.f) ? v : 0.f;
            o[j] = v + sv[j];
        }
        uint2 p0 = make_uint2(pack2bf(o[0], o[1]), pack2bf(o[2], o[3]));
        uint2 p1 = make_uint2(pack2bf(o[4], o[5]), pack2bf(o[6], o[7]));
        unsigned short* xp = xb + (size_t)node * 64 + l * 8;
        *(uint2*)xp       = p0;
        *(uint2*)(xp + 4) = p1;
    }
}

// ---------------- global branch layer 1 (MFMA bf16, LDS-free) ----------------
__global__ __launch_bounds__(256) void global_gemm1_mfma(
        const unsigned short* __restrict__ Ab,   // [25000][384] bf16
        const unsigned short* __restrict__ Wb,   // [256][384] bf16
        const float* __restrict__ bias,          // gb1
        unsigned short* __restrict__ y1b, int M) {
    int wave = threadIdx.x >> 6;
    int lane = threadIdx.x & 63;
    int quad = lane >> 4;
    int lm   = lane & 15;
    int mtile = blockIdx.x >> 1;
    int nhalf = blockIdx.x & 1;
    int row0 = mtile * 64 + wave * 16;
    int col0 = nhalf * 128;

    int arow = row0 + lm;
    if (arow >= M) arow = M - 1;             // clamp; stores predicated
    const unsigned short* ap = Ab + (size_t)arow * 384 + quad * 8;
    const unsigned short* bp = Wb + (size_t)(col0 + lm) * 384 + quad * 8;

    f32x4v acc[8];
    #pragma unroll
    for (int t = 0; t < 8; ++t) acc[t] = (f32x4v){0.f, 0.f, 0.f, 0.f};

    #pragma unroll
    for (int ks = 0; ks < 12; ++ks) {
        bf16x8 af = *(const bf16x8*)(ap + ks * 32);
        #pragma unroll
        for (int t = 0; t < 8; ++t) {
            bf16x8 bfr = *(const bf16x8*)(bp + (size_t)t * 16 * 384 + ks * 32);
            acc[t] = __builtin_amdgcn_mfma_f32_16x16x32_bf16(af, bfr, acc[t], 0, 0, 0);
        }
    }

    #pragma unroll
    for (int t = 0; t < 8; ++t) {
        int nn = col0 + t * 16 + lm;
        float bv = bias[nn];
        #pragma unroll
        for (int r = 0; r < 4; ++r) {
            int m = row0 + quad * 4 + r;
            if (m < M) {
                float v = acc[t][r] + bv;
                v = (v > 0.f) ? v : 0.01f * v;
                y1b[(size_t)m * 256 + nn] = f2bf(v);
            }
        }
    }
}

// ---------------- global branch layer 2: xgb = bf16 [B][16] (zero-padded) ----------------
__global__ void global_gemm2(const unsigned short* __restrict__ y1b, const float* __restrict__ W2,
                             const float* __restrict__ b2, unsigned short* __restrict__ xgb, int B) {
    int wave = (blockIdx.x * blockDim.x + threadIdx.x) >> 6;
    int lane = threadIdx.x & 63;
    if (wave >= B) return;
    const unsigned short* yr = y1b + (size_t)wave * 256;
    float yv[4];
    #pragma unroll
    for (int j = 0; j < 4; ++j) yv[j] = bf1(yr[lane + 64 * j]);
    float res[10];
    #pragma unroll
    for (int o = 0; o < 10; ++o) {
        const float* w = W2 + o * 256;
        float p = 0.f;
        #pragma unroll
        for (int j = 0; j < 4; ++j) p += yv[j] * w[lane + 64 * j];
        #pragma unroll
        for (int off = 32; off > 0; off >>= 1) p += __shfl_down(p, off, 64);
        res[o] = p;
    }
    if (lane == 0) {
        float v[10];
        #pragma unroll
        for (int o = 0; o < 10; ++o) {
            float t = res[o] + b2[o];
            v[o] = (t > 0.f) ? t : 0.01f * t;
        }
        uint4 pa = make_uint4(pack2bf(v[0], v[1]), pack2bf(v[2], v[3]),
                              pack2bf(v[4], v[5]), pack2bf(v[6], v[7]));
        uint4 pb = make_uint4(pack2bf(v[8], v[9]), 0u, 0u, 0u);
        unsigned short* xp = xgb + (size_t)wave * 16;
        *(uint4*)xp       = pa;
        *(uint4*)(xp + 8) = pb;
    }
}

// ---------------- final MLP via MFMA: 6 waves/block, 1 tile (16 nodes) per wave ----------------
// block = 384 threads = 96 nodes (96 % 6 == 0: groups block-local); NO contended atomics —
// per-block partial |conc| sums reduced by reduce_reg.
#define Y1_STRIDE 40
__global__ __launch_bounds__(384) void mlp_mfma(
        const unsigned short* __restrict__ xb,    // [N][64] bf16
        const unsigned short* __restrict__ xgb,   // [B][16] bf16 zero-padded
        const unsigned short* __restrict__ w1p,   // [32][96] bf16 zero-padded
        const unsigned short* __restrict__ w2p,   // [32][32] bf16
        const float* __restrict__ l1b, const float* __restrict__ l2b,
        const float* __restrict__ l3W, const float* __restrict__ l3b,
        float* __restrict__ out, float* __restrict__ partial, int n) {
    __shared__ unsigned short y1L[6][16 * Y1_STRIDE];
    __shared__ float conc[96];
    __shared__ float wsum[6];

    int wid  = threadIdx.x >> 6;
    int lane = threadIdx.x & 63;
    int quad = lane >> 4;
    int lm   = lane & 15;
    int nbase = blockIdx.x * 96;
    int node  = nbase + wid * 16 + lm;
    int nodec = (node < n) ? node : (n - 1);      // clamp loads; stores predicated

    // B frags
    bf16x8 b1[2][3];
    #pragma unroll
    for (int t2 = 0; t2 < 2; ++t2)
        #pragma unroll
        for (int ks = 0; ks < 3; ++ks)
            b1[t2][ks] = *(const bf16x8*)(w1p + (t2 * 16 + lm) * 96 + ks * 32 + quad * 8);
    bf16x8 b2f[2];
    #pragma unroll
    for (int t2 = 0; t2 < 2; ++t2)
        b2f[t2] = *(const bf16x8*)(w2p + (t2 * 16 + lm) * 32 + quad * 8);

    float bias1a = l1b[lm],      bias1b = l1b[16 + lm];
    float bias2a = l2b[lm],      bias2b = l2b[16 + lm];
    float w3a    = l3W[lm],      w3b    = l3W[16 + lm];
    float b3     = l3b[0];

    // layer-1 A frags
    bf16x8 a0 = *(const bf16x8*)(xb + (size_t)nodec * 64 + quad * 8);
    bf16x8 a1 = *(const bf16x8*)(xb + (size_t)nodec * 64 + 32 + quad * 8);
    bf16x8 a2 = (bf16x8){0, 0, 0, 0, 0, 0, 0, 0};
    if (quad < 2) a2 = *(const bf16x8*)(xgb + (size_t)(nodec / 6) * 16 + quad * 8);

    f32x4v acc0 = (f32x4v){0.f, 0.f, 0.f, 0.f};
    f32x4v acc1 = acc0;
    acc0 = __builtin_amdgcn_mfma_f32_16x16x32_bf16(a0, b1[0][0], acc0, 0, 0, 0);
    acc1 = __builtin_amdgcn_mfma_f32_16x16x32_bf16(a0, b1[1][0], acc1, 0, 0, 0);
    acc0 = __builtin_amdgcn_mfma_f32_16x16x32_bf16(a1, b1[0][1], acc0, 0, 0, 0);
    acc1 = __builtin_amdgcn_mfma_f32_16x16x32_bf16(a1, b1[1][1], acc1, 0, 0, 0);
    acc0 = __builtin_amdgcn_mfma_f32_16x16x32_bf16(a2, b1[0][2], acc0, 0, 0, 0);
    acc1 = __builtin_amdgcn_mfma_f32_16x16x32_bf16(a2, b1[1][2], acc1, 0, 0, 0);

    unsigned short* myY = y1L[wid];
    #pragma unroll
    for (int r = 0; r < 4; ++r) {
        float v0 = acc0[r] + bias1a;
        float v1 = acc1[r] + bias1b;
        v0 = (v0 > 0.f) ? v0 : 0.01f * v0;
        v1 = (v1 > 0.f) ? v1 : 0.01f * v1;
        myY[(quad * 4 + r) * Y1_STRIDE + lm]      = f2bf(v0);
        myY[(quad * 4 + r) * Y1_STRIDE + 16 + lm] = f2bf(v1);
    }
    bf16x8 a2f = *(const bf16x8*)(myY + lm * Y1_STRIDE + quad * 8);
    f32x4v acc20 = (f32x4v){0.f, 0.f, 0.f, 0.f};
    f32x4v acc21 = acc20;
    acc20 = __builtin_amdgcn_mfma_f32_16x16x32_bf16(a2f, b2f[0], acc20, 0, 0, 0);
    acc21 = __builtin_amdgcn_mfma_f32_16x16x32_bf16(a2f, b2f[1], acc21, 0, 0, 0);

    float part[4];
    #pragma unroll
    for (int r = 0; r < 4; ++r) {
        float y2a = acc20[r] + bias2a;
        float y2b = acc21[r] + bias2b;
        y2a = (y2a > 0.f) ? y2a : 0.01f * y2a;
        y2b = (y2b > 0.f) ? y2b : 0.01f * y2b;
        part[r] = y2a * w3a + y2b * w3b;
    }
    #pragma unroll
    for (int st = 1; st < 16; st <<= 1) {
        #pragma unroll
        for (int r = 0; r < 4; ++r) part[r] += __shfl_xor(part[r], st, 64);
    }
    if (lm == 0) {
        #pragma unroll
        for (int r = 0; r < 4; ++r) {
            float a3 = part[r] + b3;
            conc[wid * 16 + quad * 4 + r] = (a3 > 20.f) ? a3 : log1pf(expf(a3));
        }
    }
    __syncthreads();

    // normalize (block covers 96 nodes, groups of 6 block-local) + per-block |conc| partial
    int tid = threadIdx.x;
    float myabs = 0.f;
    if (tid < 96) {
        int gnode = nbase + tid;
        if (gnode < n) {
            int g0 = (tid / 6) * 6;
            float s = 0.f;
            #pragma unroll
            for (int i = 0; i < 6; ++i) s += conc[g0 + i];
            float c = conc[tid];
            out[gnode] = c / (s + 1e-20f);
            myabs = fabsf(c);
        }
    }
    #pragma unroll
    for (int off = 32; off > 0; off >>= 1) myabs += __shfl_down(myabs, off, 64);
    if (lane == 0) wsum[wid] = myabs;
    __syncthreads();
    if (tid == 0)
        partial[blockIdx.x] = wsum[0] + wsum[1] + wsum[2] + wsum[3] + wsum[4] + wsum[5];
}

// ---------------- final reduction of per-block partials ----------------
__global__ void reduce_reg(const float* __restrict__ partial, float* __restrict__ regptr, int nb) {
    __shared__ float wsum[4];
    int tid = threadIdx.x;
    float s = 0.f;
    for (int i = tid; i < nb; i += 256) s += partial[i];
    #pragma unroll
    for (int off = 32; off > 0; off >>= 1) s += __shfl_down(s, off, 64);
    if ((tid & 63) == 0) wsum[tid >> 6] = s;
    __syncthreads();
    if (tid == 0)
        *regptr = (wsum[0] + wsum[1] + wsum[2] + wsum[3]) * (1.0f / (float)N_NODES);
}

extern "C" void kernel_launch(void* const* d_in, const int* in_sizes, int n_in,
                              void* d_out, int out_size, void* d_ws, size_t ws_size,
                              hipStream_t stream) {
    const float* state = (const float*)d_in[0];
    const int*   ei    = (const int*)d_in[1];
    const float* convW = (const float*)d_in[2];
    const float* convb = (const float*)d_in[3];
    const float* gW1   = (const float*)d_in[4];
    const float* gb1   = (const float*)d_in[5];
    const float* gW2   = (const float*)d_in[6];
    const float* gb2   = (const float*)d_in[7];
    const float* l1W   = (const float*)d_in[8];
    const float* l1b   = (const float*)d_in[9];
    const float* l2W   = (const float*)d_in[10];
    const float* l2b   = (const float*)d_in[11];
    const float* l3W   = (const float*)d_in[12];
    const float* l3b   = (const float*)d_in[13];

    const int n = N_NODES, E = N_EDGES, B = B_ROWS;
    const int* src = ei;
    const int* dst = ei + E;

    // ---- workspace layout ----
    char* w = (char*)d_ws;
    int*   counts = (int*)w;                 w += NPAD * 4;
    int*   rank   = (int*)w;                 w += (size_t)E * 4;
    int*   rowptr = (int*)w;                 w += NPAD * 4;
    int*   bsum   = (int*)w;                 w += 256 * 4;
    float* dinv   = (float*)w;               w += NPAD * 4;
    int*   csr    = (int*)w;                 w += (size_t)E * 4;
    float* hregion= (float*)w;               w += (size_t)n * 64 * 4; // 38.4 MB
    unsigned short* xb = (unsigned short*)w; w += (size_t)n * 64 * 2; // 19.2 MB
    unsigned short* w1b = (unsigned short*)w; w += 98304 * 2;
    unsigned short* w1p = (unsigned short*)w; w += 3072 * 2;
    unsigned short* w2p = (unsigned short*)w; w += 1024 * 2;
    unsigned short* wcb = (unsigned short*)w; w += 4096 * 2;
    float* partial = (float*)w;              w += MLP_BLOCKS * 4;
    // hregion phases:
    //   phase 1: hb = [0..19.2MB) bf16 h*dinv ; sb = [19.2..38.4MB) bf16 state
    //   phase 2: y1b = [0..12.8MB) bf16 y1 (hb dead) ; xgb = [12.8..13.6MB) bf16 [B][16]
    unsigned short* hb  = (unsigned short*)hregion;
    unsigned short* sb  = (unsigned short*)(hregion + 4800000);
    unsigned short* y1b = (unsigned short*)hregion;
    unsigned short* xgb = (unsigned short*)(hregion + 3200000);

    float* out    = (float*)d_out;
    float* regptr = out + n;

    hipMemsetAsync(counts, 0, NPAD * 4, stream);

    degree_kernel<<<(E + 255) / 256, 256, 0, stream>>>(dst, counts, rank, E);
    scan_block<<<NSCAN, 256, 0, stream>>>(counts, rowptr, bsum, n);
    scan_sums<<<1, 256, 0, stream>>>(bsum, NSCAN);
    scan_add<<<(n + 256) / 256, 256, 0, stream>>>(rowptr, bsum, counts, dinv, n, E);
    fill_csr<<<(E + 255) / 256, 256, 0, stream>>>(src, dst, rowptr, rank, csr, E);
    prep_cast<<<(NSTATE_V8 + 106496 + 255) / 256, 256, 0, stream>>>(
        state, convW, gW1, l1W, l2W, sb, wcb, w1b, w1p, w2p);
    conv_mfma<<<(9375 + 3) / 4, 256, 0, stream>>>(sb, wcb, dinv, hb, n);
    gather_fused<<<(n + 31) / 32, 256, 0, stream>>>(rowptr, csr, hb, dinv, convb, sb, xb, n, E);
    global_gemm1_mfma<<<391 * 2, 256, 0, stream>>>(sb, w1b, gb1, y1b, B);
    global_gemm2<<<(B * 64 + 255) / 256, 256, 0, stream>>>(y1b, gW2, gb2, xgb, B);
    mlp_mfma<<<MLP_BLOCKS, 384, 0, stream>>>(xb, xgb, w1p, w2p, l1b, l2b, l3W, l3b,
                                             out, partial, n);
    reduce_reg<<<1, 256, 0, stream>>>(partial, regptr, MLP_BLOCKS);
}

// Round 13
// 292.126 us; speedup vs baseline: 3.2402x; 1.1076x over previous
//
#include <hip/hip_runtime.h>
#include <math.h>

#define N_NODES 150000
#define N_EDGES 1200000
#define C 64
#define ACT 6
#define B_ROWS 25000   // N/ACT
#define GLOB 256
#define GOUT 10
#define H 32

#define NPAD 150016            // N rounded up (alignment)
#define SCAN_CHUNK 1024
#define NSCAN 147              // ceil(150000/1024)
#define MLP_BLOCKS 1563        // ceil(150000/96)

typedef short bf16x8 __attribute__((ext_vector_type(8)));
typedef float f32x4v __attribute__((ext_vector_type(4)));

// ---- bf16 helpers ----
__device__ __forceinline__ unsigned short f2bf(float f) {
    unsigned int u = __builtin_bit_cast(unsigned int, f);
    unsigned int r = (u + 0x7fffu + ((u >> 16) & 1u)) >> 16;   // RTNE
    return (unsigned short)r;
}
__device__ __forceinline__ unsigned int pack2bf(float a, float b) {
    return (unsigned int)f2bf(a) | ((unsigned int)f2bf(b) << 16);
}
__device__ __forceinline__ float bflo(unsigned int u) {
    return __builtin_bit_cast(float, u << 16);
}
__device__ __forceinline__ float bfhi(unsigned int u) {
    return __builtin_bit_cast(float, u & 0xffff0000u);
}
__device__ __forceinline__ float bf1(unsigned short us) {
    return __builtin_bit_cast(float, ((unsigned int)us) << 16);
}

// ---------------- degree histogram + per-edge rank ----------------
__global__ void degree_kernel(const int* __restrict__ dst, int* __restrict__ counts,
                              int* __restrict__ rank, int E) {
    int e = blockIdx.x * blockDim.x + threadIdx.x;
    if (e < E) rank[e] = atomicAdd(&counts[dst[e]], 1);
}

// ---------------- prefix scan (3 kernels) ----------------
__global__ void scan_block(const int* __restrict__ counts, int* __restrict__ rowptr,
                           int* __restrict__ bsum, int n) {
    __shared__ int lds[256];
    int base = blockIdx.x * SCAN_CHUNK;
    int t = threadIdx.x;
    int v[4]; int s = 0;
    #pragma unroll
    for (int i = 0; i < 4; ++i) {
        int idx = base + t * 4 + i;
        v[i] = (idx < n) ? counts[idx] : 0;
        s += v[i];
    }
    lds[t] = s; __syncthreads();
    for (int off = 1; off < 256; off <<= 1) {
        int x = (t >= off) ? lds[t - off] : 0;
        __syncthreads();
        lds[t] += x;
        __syncthreads();
    }
    int excl = lds[t] - s;
    if (t == 255) bsum[blockIdx.x] = lds[255];
    int run = excl;
    #pragma unroll
    for (int i = 0; i < 4; ++i) {
        int idx = base + t * 4 + i;
        if (idx < n) rowptr[idx] = run;
        run += v[i];
    }
}

__global__ void scan_sums(int* __restrict__ bsum, int nb) {
    __shared__ int lds[256];
    int t = threadIdx.x;
    int v = (t < nb) ? bsum[t] : 0;
    lds[t] = v; __syncthreads();
    for (int off = 1; off < 256; off <<= 1) {
        int x = (t >= off) ? lds[t - off] : 0;
        __syncthreads();
        lds[t] += x;
        __syncthreads();
    }
    if (t < nb) bsum[t] = lds[t] - v;   // exclusive
}

__global__ void scan_add(int* __restrict__ rowptr, const int* __restrict__ bsum,
                         const int* __restrict__ counts, float* __restrict__ dinv,
                         int n, int E) {
    int i = blockIdx.x * blockDim.x + threadIdx.x;
    if (i < n) {
        rowptr[i] += bsum[i >> 10];
        dinv[i] = rsqrtf((float)counts[i] + 1.0f);
    }
    if (i == n) rowptr[n] = E;
}

// ---------------- CSR fill (atomic-free: rank precomputed) ----------------
__global__ void fill_csr(const int* __restrict__ src, const int* __restrict__ dst,
                         const int* __restrict__ rowptr, const int* __restrict__ rank,
                         int* __restrict__ csr, int E) {
    int e = blockIdx.x * blockDim.x + threadIdx.x;
    if (e >= E) return;
    int d = dst[e];
    csr[rowptr[d] + rank[e]] = src[e];
}

// ---------------- prep: cast state + all weights to bf16 ----------------
#define NSTATE_V8 1200000      // 9.6M / 8
__global__ void prep_cast(const float* __restrict__ state, const float* __restrict__ convW,
                          const float* __restrict__ gW1, const float* __restrict__ l1W,
                          const float* __restrict__ l2W,
                          unsigned short* __restrict__ sb,    // [N*64]
                          unsigned short* __restrict__ wcb,   // [64*64]
                          unsigned short* __restrict__ w1b,   // [256*384]
                          unsigned short* __restrict__ w1p,   // [32*96] zero-padded
                          unsigned short* __restrict__ w2p) { // [32*32]
    int i = blockIdx.x * blockDim.x + threadIdx.x;
    if (i < NSTATE_V8) {
        const float4* p = (const float4*)(state + (size_t)i * 8);
        float4 a = p[0], b = p[1];
        uint4 o = make_uint4(pack2bf(a.x, a.y), pack2bf(a.z, a.w),
                             pack2bf(b.x, b.y), pack2bf(b.z, b.w));
        *(uint4*)(sb + (size_t)i * 8) = o;
        return;
    }
    int j = i - NSTATE_V8;
    if (j < 4096) {
        wcb[j] = f2bf(convW[j]);
    } else if (j < 4096 + 98304) {
        int k = j - 4096;
        w1b[k] = f2bf(gW1[k]);
    } else if (j < 4096 + 98304 + 3072) {
        int k = j - 4096 - 98304;
        int r = k / 96, c = k - r * 96;
        w1p[k] = (c < 74) ? f2bf(l1W[r * 74 + c]) : 0;
    } else if (j < 4096 + 98304 + 3072 + 1024) {
        int k = j - 4096 - 98304 - 3072;
        w2p[k] = f2bf(l2W[k]);
    }
}

// ---------------- conv via MFMA: hb = bf16((sb @ Wc^T) * dinv), one wave = 16 rows ----------------
__global__ __launch_bounds__(256) void conv_mfma(
        const unsigned short* __restrict__ sb,    // [N][64] bf16
        const unsigned short* __restrict__ wcb,   // [64][64] bf16
        const float* __restrict__ dinv,
        unsigned short* __restrict__ hb, int n) {
    int wid  = threadIdx.x >> 6;
    int lane = threadIdx.x & 63;
    int quad = lane >> 4;
    int lm   = lane & 15;
    int row0 = (blockIdx.x * 4 + wid) * 16;
    if (row0 >= n) return;                        // n = 150000 = 16*9375: no partial waves

    const unsigned short* ap = sb + (size_t)(row0 + lm) * 64 + quad * 8;
    bf16x8 a0 = *(const bf16x8*)ap;
    bf16x8 a1 = *(const bf16x8*)(ap + 32);

    f32x4v acc[4];
    #pragma unroll
    for (int t = 0; t < 4; ++t) acc[t] = (f32x4v){0.f, 0.f, 0.f, 0.f};
    #pragma unroll
    for (int t = 0; t < 4; ++t) {
        const unsigned short* bp = wcb + (size_t)(t * 16 + lm) * 64 + quad * 8;
        bf16x8 b0 = *(const bf16x8*)bp;
        bf16x8 b1 = *(const bf16x8*)(bp + 32);
        acc[t] = __builtin_amdgcn_mfma_f32_16x16x32_bf16(a0, b0, acc[t], 0, 0, 0);
        acc[t] = __builtin_amdgcn_mfma_f32_16x16x32_bf16(a1, b1, acc[t], 0, 0, 0);
    }

    float dv[4];
    #pragma unroll
    for (int r = 0; r < 4; ++r) dv[r] = dinv[row0 + quad * 4 + r];
    #pragma unroll
    for (int t = 0; t < 4; ++t) {
        #pragma unroll
        for (int r = 0; r < 4; ++r) {
            int m = row0 + quad * 4 + r;
            hb[(size_t)m * 64 + t * 16 + lm] = f2bf(acc[t][r] * dv[r]);
        }
    }
}

// ---------------- gather: 8 nodes/wave, 8 lanes/node, no cross-lane reduction ----------------
__global__ void gather_fused(const int* __restrict__ rowptr, const int* __restrict__ csr,
                             const unsigned short* __restrict__ hb, const float* __restrict__ dinv,
                             const float* __restrict__ convb, const unsigned short* __restrict__ sb,
                             unsigned short* __restrict__ xb, int n, int E) {
    int wid  = threadIdx.x >> 6;
    int lane = threadIdx.x & 63;
    int g = lane >> 3;        // node slot within wave (0..7)
    int l = lane & 7;         // channel octet (8 bf16 per lane)
    int node = (blockIdx.x * 4 + wid) * 8 + g;
    bool valid = node < n;
    int nodec = valid ? node : (n - 1);
    int beg = rowptr[nodec], end = rowptr[nodec + 1];
    int deg = valid ? (end - beg) : 0;

    float acc[8] = {0.f, 0.f, 0.f, 0.f, 0.f, 0.f, 0.f, 0.f};
    int pidx = beg + l; if (pidx > E - 1) pidx = E - 1;
    int eid = csr[pidx];                        // prefetch up to 8 edge ids per node
    for (int i = 0; i < deg; ++i) {
        if ((i & 7) == 0 && i != 0) {
            int q = beg + i + l; if (q > E - 1) q = E - 1;
            eid = csr[q];
        }
        int s = __shfl(eid, (g << 3) + (i & 7), 64);   // broadcast within group
        uint4 u = *(const uint4*)(hb + (size_t)s * 64 + l * 8);
        acc[0] += bflo(u.x); acc[1] += bfhi(u.x);
        acc[2] += bflo(u.y); acc[3] += bfhi(u.y);
        acc[4] += bflo(u.z); acc[5] += bfhi(u.z);
        acc[6] += bflo(u.w); acc[7] += bfhi(u.w);
    }

    if (valid) {
        float dd = dinv[node];
        uint4 us = *(const uint4*)(hb + (size_t)node * 64 + l * 8);
        uint4 uv = *(const uint4*)(sb + (size_t)node * 64 + l * 8);
        float4 c0 = *(const float4*)(convb + l * 8);
        float4 c1 = *(const float4*)(convb + l * 8 + 4);
        float sf[8] = {bflo(us.x), bfhi(us.x), bflo(us.y), bfhi(us.y),
                       bflo(us.z), bfhi(us.z), bflo(us.w), bfhi(us.w)};
        float sv[8] = {bflo(uv.x), bfhi(uv.x), bflo(uv.y), bfhi(uv.y),
                       bflo(uv.z), bfhi(uv.z), bflo(uv.w), bfhi(uv.w)};
        float cb[8] = {c0.x, c0.y, c0.z, c0.w, c1.x, c1.y, c1.z, c1.w};
        float o[8];
        #pragma unroll
        for (int j = 0; j < 8; ++j) {
            float v = dd * (acc[j] + sf[j]) + cb[j];
            v = (v > 0.f) ? v : 0.f;
            o[j] = v + sv[j];
        }
        uint2 p0 = make_uint2(pack2bf(o[0], o[1]), pack2bf(o[2], o[3]));
        uint2 p1 = make_uint2(pack2bf(o[4], o[5]), pack2bf(o[6], o[7]));
        unsigned short* xp = xb + (size_t)node * 64 + l * 8;
        *(uint2*)xp       = p0;
        *(uint2*)(xp + 4) = p1;
    }
}

// ---------------- global branch layer 1 (MFMA bf16, LDS-staged B panel) ----------------
// block = 512 threads (8 waves) = 128 rows x 64 cols. B quarter [64][384] staged in LDS
// with padded row stride 392 shorts (784 B = 49*16B: lm lanes land 4 banks apart, <=2-way).
#define B_STRIDE 392
__global__ __launch_bounds__(512) void global_gemm1_mfma(
        const unsigned short* __restrict__ Ab,   // [25000][384] bf16
        const unsigned short* __restrict__ Wb,   // [256][384] bf16
        const float* __restrict__ bias,          // gb1
        unsigned short* __restrict__ y1b, int M) {
    __shared__ unsigned short Blds[64 * B_STRIDE];   // 50176 B

    int tid  = threadIdx.x;
    int mb   = blockIdx.x >> 2;              // 0..195
    int q    = blockIdx.x & 3;               // col quarter
    int col0 = q * 64;

    // stage B quarter: 64 rows x 384 shorts = 3072 segments of 8 shorts (16 B), 6 per thread
    #pragma unroll
    for (int i = 0; i < 6; ++i) {
        int seg = i * 512 + tid;
        int row = seg / 48;
        int off = (seg - row * 48) * 8;      // shorts
        uint4 v = *(const uint4*)(Wb + (size_t)(col0 + row) * 384 + off);   // 16 B
        *(uint4*)(&Blds[row * B_STRIDE + off]) = v;
    }
    __syncthreads();

    int wave = tid >> 6;
    int lane = tid & 63;
    int quad = lane >> 4;
    int lm   = lane & 15;
    int row0 = mb * 128 + wave * 16;

    int arow = row0 + lm;
    if (arow >= M) arow = M - 1;             // clamp; stores predicated
    const unsigned short* ap = Ab + (size_t)arow * 384 + quad * 8;

    // burst-load all 12 A fragments (independent)
    bf16x8 af[12];
    #pragma unroll
    for (int ks = 0; ks < 12; ++ks) af[ks] = *(const bf16x8*)(ap + ks * 32);

    f32x4v acc[4];
    #pragma unroll
    for (int t = 0; t < 4; ++t) acc[t] = (f32x4v){0.f, 0.f, 0.f, 0.f};

    #pragma unroll
    for (int ks = 0; ks < 12; ++ks) {
        #pragma unroll
        for (int t = 0; t < 4; ++t) {
            bf16x8 bfr = *(const bf16x8*)(&Blds[(t * 16 + lm) * B_STRIDE + ks * 32 + quad * 8]);
            acc[t] = __builtin_amdgcn_mfma_f32_16x16x32_bf16(af[ks], bfr, acc[t], 0, 0, 0);
        }
    }

    #pragma unroll
    for (int t = 0; t < 4; ++t) {
        int nn = col0 + t * 16 + lm;
        float bv = bias[nn];
        #pragma unroll
        for (int r = 0; r < 4; ++r) {
            int m = row0 + quad * 4 + r;
            if (m < M) {
                float v = acc[t][r] + bv;
                v = (v > 0.f) ? v : 0.01f * v;
                y1b[(size_t)m * 256 + nn] = f2bf(v);
            }
        }
    }
}

// ---------------- global branch layer 2: xgb = bf16 [B][16] (zero-padded) ----------------
__global__ void global_gemm2(const unsigned short* __restrict__ y1b, const float* __restrict__ W2,
                             const float* __restrict__ b2, unsigned short* __restrict__ xgb, int B) {
    int wave = (blockIdx.x * blockDim.x + threadIdx.x) >> 6;
    int lane = threadIdx.x & 63;
    if (wave >= B) return;
    const unsigned short* yr = y1b + (size_t)wave * 256;
    float yv[4];
    #pragma unroll
    for (int j = 0; j < 4; ++j) yv[j] = bf1(yr[lane + 64 * j]);
    float res[10];
    #pragma unroll
    for (int o = 0; o < 10; ++o) {
        const float* w = W2 + o * 256;
        float p = 0.f;
        #pragma unroll
        for (int j = 0; j < 4; ++j) p += yv[j] * w[lane + 64 * j];
        #pragma unroll
        for (int off = 32; off > 0; off >>= 1) p += __shfl_down(p, off, 64);
        res[o] = p;
    }
    if (lane == 0) {
        float v[10];
        #pragma unroll
        for (int o = 0; o < 10; ++o) {
            float t = res[o] + b2[o];
            v[o] = (t > 0.f) ? t : 0.01f * t;
        }
        uint4 pa = make_uint4(pack2bf(v[0], v[1]), pack2bf(v[2], v[3]),
                              pack2bf(v[4], v[5]), pack2bf(v[6], v[7]));
        uint4 pb = make_uint4(pack2bf(v[8], v[9]), 0u, 0u, 0u);
        unsigned short* xp = xgb + (size_t)wave * 16;
        *(uint4*)xp       = pa;
        *(uint4*)(xp + 8) = pb;
    }
}

// ---------------- final MLP via MFMA: 6 waves/block, 1 tile (16 nodes) per wave ----------------
#define Y1_STRIDE 40
__global__ __launch_bounds__(384) void mlp_mfma(
        const unsigned short* __restrict__ xb,    // [N][64] bf16
        const unsigned short* __restrict__ xgb,   // [B][16] bf16 zero-padded
        const unsigned short* __restrict__ w1p,   // [32][96] bf16 zero-padded
        const unsigned short* __restrict__ w2p,   // [32][32] bf16
        const float* __restrict__ l1b, const float* __restrict__ l2b,
        const float* __restrict__ l3W, const float* __restrict__ l3b,
        float* __restrict__ out, float* __restrict__ partial, int n) {
    __shared__ unsigned short y1L[6][16 * Y1_STRIDE];
    __shared__ float conc[96];
    __shared__ float wsum[6];

    int wid  = threadIdx.x >> 6;
    int lane = threadIdx.x & 63;
    int quad = lane >> 4;
    int lm   = lane & 15;
    int nbase = blockIdx.x * 96;
    int node  = nbase + wid * 16 + lm;
    int nodec = (node < n) ? node : (n - 1);      // clamp loads; stores predicated

    bf16x8 b1[2][3];
    #pragma unroll
    for (int t2 = 0; t2 < 2; ++t2)
        #pragma unroll
        for (int ks = 0; ks < 3; ++ks)
            b1[t2][ks] = *(const bf16x8*)(w1p + (t2 * 16 + lm) * 96 + ks * 32 + quad * 8);
    bf16x8 b2f[2];
    #pragma unroll
    for (int t2 = 0; t2 < 2; ++t2)
        b2f[t2] = *(const bf16x8*)(w2p + (t2 * 16 + lm) * 32 + quad * 8);

    float bias1a = l1b[lm],      bias1b = l1b[16 + lm];
    float bias2a = l2b[lm],      bias2b = l2b[16 + lm];
    float w3a    = l3W[lm],      w3b    = l3W[16 + lm];
    float b3     = l3b[0];

    bf16x8 a0 = *(const bf16x8*)(xb + (size_t)nodec * 64 + quad * 8);
    bf16x8 a1 = *(const bf16x8*)(xb + (size_t)nodec * 64 + 32 + quad * 8);
    bf16x8 a2 = (bf16x8){0, 0, 0, 0, 0, 0, 0, 0};
    if (quad < 2) a2 = *(const bf16x8*)(xgb + (size_t)(nodec / 6) * 16 + quad * 8);

    f32x4v acc0 = (f32x4v){0.f, 0.f, 0.f, 0.f};
    f32x4v acc1 = acc0;
    acc0 = __builtin_amdgcn_mfma_f32_16x16x32_bf16(a0, b1[0][0], acc0, 0, 0, 0);
    acc1 = __builtin_amdgcn_mfma_f32_16x16x32_bf16(a0, b1[1][0], acc1, 0, 0, 0);
    acc0 = __builtin_amdgcn_mfma_f32_16x16x32_bf16(a1, b1[0][1], acc0, 0, 0, 0);
    acc1 = __builtin_amdgcn_mfma_f32_16x16x32_bf16(a1, b1[1][1], acc1, 0, 0, 0);
    acc0 = __builtin_amdgcn_mfma_f32_16x16x32_bf16(a2, b1[0][2], acc0, 0, 0, 0);
    acc1 = __builtin_amdgcn_mfma_f32_16x16x32_bf16(a2, b1[1][2], acc1, 0, 0, 0);

    unsigned short* myY = y1L[wid];
    #pragma unroll
    for (int r = 0; r < 4; ++r) {
        float v0 = acc0[r] + bias1a;
        float v1 = acc1[r] + bias1b;
        v0 = (v0 > 0.f) ? v0 : 0.01f * v0;
        v1 = (v1 > 0.f) ? v1 : 0.01f * v1;
        myY[(quad * 4 + r) * Y1_STRIDE + lm]      = f2bf(v0);
        myY[(quad * 4 + r) * Y1_STRIDE + 16 + lm] = f2bf(v1);
    }
    bf16x8 a2f = *(const bf16x8*)(myY + lm * Y1_STRIDE + quad * 8);
    f32x4v acc20 = (f32x4v){0.f, 0.f, 0.f, 0.f};
    f32x4v acc21 = acc20;
    acc20 = __builtin_amdgcn_mfma_f32_16x16x32_bf16(a2f, b2f[0], acc20, 0, 0, 0);
    acc21 = __builtin_amdgcn_mfma_f32_16x16x32_bf16(a2f, b2f[1], acc21, 0, 0, 0);

    float part[4];
    #pragma unroll
    for (int r = 0; r < 4; ++r) {
        float y2a = acc20[r] + bias2a;
        float y2b = acc21[r] + bias2b;
        y2a = (y2a > 0.f) ? y2a : 0.01f * y2a;
        y2b = (y2b > 0.f) ? y2b : 0.01f * y2b;
        part[r] = y2a * w3a + y2b * w3b;
    }
    #pragma unroll
    for (int st = 1; st < 16; st <<= 1) {
        #pragma unroll
        for (int r = 0; r < 4; ++r) part[r] += __shfl_xor(part[r], st, 64);
    }
    if (lm == 0) {
        #pragma unroll
        for (int r = 0; r < 4; ++r) {
            float a3 = part[r] + b3;
            conc[wid * 16 + quad * 4 + r] = (a3 > 20.f) ? a3 : log1pf(expf(a3));
        }
    }
    __syncthreads();

    int tid = threadIdx.x;
    float myabs = 0.f;
    if (tid < 96) {
        int gnode = nbase + tid;
        if (gnode < n) {
            int g0 = (tid / 6) * 6;
            float s = 0.f;
            #pragma unroll
            for (int i = 0; i < 6; ++i) s += conc[g0 + i];
            float c = conc[tid];
            out[gnode] = c / (s + 1e-20f);
            myabs = fabsf(c);
        }
    }
    #pragma unroll
    for (int off = 32; off > 0; off >>= 1) myabs += __shfl_down(myabs, off, 64);
    if (lane == 0) wsum[wid] = myabs;
    __syncthreads();
    if (tid == 0)
        partial[blockIdx.x] = wsum[0] + wsum[1] + wsum[2] + wsum[3] + wsum[4] + wsum[5];
}

// ---------------- final reduction of per-block partials ----------------
__global__ void reduce_reg(const float* __restrict__ partial, float* __restrict__ regptr, int nb) {
    __shared__ float wsum[4];
    int tid = threadIdx.x;
    float s = 0.f;
    for (int i = tid; i < nb; i += 256) s += partial[i];
    #pragma unroll
    for (int off = 32; off > 0; off >>= 1) s += __shfl_down(s, off, 64);
    if ((tid & 63) == 0) wsum[tid >> 6] = s;
    __syncthreads();
    if (tid == 0)
        *regptr = (wsum[0] + wsum[1] + wsum[2] + wsum[3]) * (1.0f / (float)N_NODES);
}

extern "C" void kernel_launch(void* const* d_in, const int* in_sizes, int n_in,
                              void* d_out, int out_size, void* d_ws, size_t ws_size,
                              hipStream_t stream) {
    const float* state = (const float*)d_in[0];
    const int*   ei    = (const int*)d_in[1];
    const float* convW = (const float*)d_in[2];
    const float* convb = (const float*)d_in[3];
    const float* gW1   = (const float*)d_in[4];
    const float* gb1   = (const float*)d_in[5];
    const float* gW2   = (const float*)d_in[6];
    const float* gb2   = (const float*)d_in[7];
    const float* l1W   = (const float*)d_in[8];
    const float* l1b   = (const float*)d_in[9];
    const float* l2W   = (const float*)d_in[10];
    const float* l2b   = (const float*)d_in[11];
    const float* l3W   = (const float*)d_in[12];
    const float* l3b   = (const float*)d_in[13];

    const int n = N_NODES, E = N_EDGES, B = B_ROWS;
    const int* src = ei;
    const int* dst = ei + E;

    // ---- workspace layout ----
    char* w = (char*)d_ws;
    int*   counts = (int*)w;                 w += NPAD * 4;
    int*   rank   = (int*)w;                 w += (size_t)E * 4;
    int*   rowptr = (int*)w;                 w += NPAD * 4;
    int*   bsum   = (int*)w;                 w += 256 * 4;
    float* dinv   = (float*)w;               w += NPAD * 4;
    int*   csr    = (int*)w;                 w += (size_t)E * 4;
    float* hregion= (float*)w;               w += (size_t)n * 64 * 4; // 38.4 MB
    unsigned short* xb = (unsigned short*)w; w += (size_t)n * 64 * 2; // 19.2 MB
    unsigned short* w1b = (unsigned short*)w; w += 98304 * 2;
    unsigned short* w1p = (unsigned short*)w; w += 3072 * 2;
    unsigned short* w2p = (unsigned short*)w; w += 1024 * 2;
    unsigned short* wcb = (unsigned short*)w; w += 4096 * 2;
    float* partial = (float*)w;              w += MLP_BLOCKS * 4;
    // hregion phases:
    //   phase 1: hb = [0..19.2MB) bf16 h*dinv ; sb = [19.2..38.4MB) bf16 state
    //   phase 2: y1b = [0..12.8MB) bf16 y1 (hb dead) ; xgb = [12.8..13.6MB) bf16 [B][16]
    unsigned short* hb  = (unsigned short*)hregion;
    unsigned short* sb  = (unsigned short*)(hregion + 4800000);
    unsigned short* y1b = (unsigned short*)hregion;
    unsigned short* xgb = (unsigned short*)(hregion + 3200000);

    float* out    = (float*)d_out;
    float* regptr = out + n;

    hipMemsetAsync(counts, 0, NPAD * 4, stream);

    degree_kernel<<<(E + 255) / 256, 256, 0, stream>>>(dst, counts, rank, E);
    scan_block<<<NSCAN, 256, 0, stream>>>(counts, rowptr, bsum, n);
    scan_sums<<<1, 256, 0, stream>>>(bsum, NSCAN);
    scan_add<<<(n + 256) / 256, 256, 0, stream>>>(rowptr, bsum, counts, dinv, n, E);
    fill_csr<<<(E + 255) / 256, 256, 0, stream>>>(src, dst, rowptr, rank, csr, E);
    prep_cast<<<(NSTATE_V8 + 106496 + 255) / 256, 256, 0, stream>>>(
        state, convW, gW1, l1W, l2W, sb, wcb, w1b, w1p, w2p);
    conv_mfma<<<(9375 + 3) / 4, 256, 0, stream>>>(sb, wcb, dinv, hb, n);
    gather_fused<<<(n + 31) / 32, 256, 0, stream>>>(rowptr, csr, hb, dinv, convb, sb, xb, n, E);
    global_gemm1_mfma<<<196 * 4, 512, 0, stream>>>(sb, w1b, gb1, y1b, B);
    global_gemm2<<<(B * 64 + 255) / 256, 256, 0, stream>>>(y1b, gW2, gb2, xgb, B);
    mlp_mfma<<<MLP_BLOCKS, 384, 0, stream>>>(xb, xgb, w1p, w2p, l1b, l2b, l3W, l3b,
                                             out, partial, n);
    reduce_reg<<<1, 256, 0, stream>>>(partial, regptr, MLP_BLOCKS);
}